// Round 1
// baseline (1053.983 us; speedup 1.0000x reference)
//
#include <hip/hip_runtime.h>
#include <math.h>

#define NAG 3
#define BATCH 32768
#define HD 128
#define SD 18
#define AD 2
#define TB 16
#define EPSV 1e-5f

// ws float-offsets
#define WS_STATS 0            // [3][20][2] mean,istd
#define WS_ACCUM 1024         // [3][20][2] sum,sumsq (memset to 0 each launch)
#define WS_F0 2048            // [128][128]  F0[h1][h2] = sum_d asel0[h1][d]*akey0[h2][d]
#define WS_F1 (WS_F0 + HD*HD)
#define WS_M  (WS_F1 + HD*HD)
#define WS_TOTAL_FLOATS (WS_M + HD*HD)

__device__ __forceinline__ float lrelu(float x){ return x >= 0.0f ? x : 0.01f * x; }

// ---------------------------------------------------------------- stats ----
__global__ void stats_partial_kernel(const float* __restrict__ s,
                                     const float* __restrict__ a,
                                     float* __restrict__ accum){
  const int n = blockIdx.x >> 4;       // 48 blocks: 16 chunks per agent
  const int chunk = blockIdx.x & 15;
  const int t = threadIdx.x;
  const int rows = BATCH / 16;
  const int b0 = chunk * rows;
  float sum[20], sq[20];
  #pragma unroll
  for (int c = 0; c < 20; ++c){ sum[c] = 0.f; sq[c] = 0.f; }
  for (int b = b0 + t; b < b0 + rows; b += 256){
    const float* row = s + ((size_t)n * BATCH + b) * SD;
    #pragma unroll
    for (int c = 0; c < SD; ++c){ float v = row[c]; sum[c] += v; sq[c] += v * v; }
    const float* ra = a + ((size_t)n * BATCH + b) * AD;
    #pragma unroll
    for (int c = 0; c < AD; ++c){ float v = ra[c]; sum[SD + c] += v; sq[SD + c] += v * v; }
  }
  __shared__ float red[256];
  for (int c = 0; c < 20; ++c){
    red[t] = sum[c]; __syncthreads();
    for (int off = 128; off > 0; off >>= 1){ if (t < off) red[t] += red[t + off]; __syncthreads(); }
    if (t == 0) atomicAdd(&accum[(n * 20 + c) * 2 + 0], red[0]);
    __syncthreads();
    red[t] = sq[c]; __syncthreads();
    for (int off = 128; off > 0; off >>= 1){ if (t < off) red[t] += red[t + off]; __syncthreads(); }
    if (t == 0) atomicAdd(&accum[(n * 20 + c) * 2 + 1], red[0]);
    __syncthreads();
  }
}

__global__ void stats_final_kernel(const float* __restrict__ accum,
                                   float* __restrict__ stats){
  int i = threadIdx.x;
  if (i < 60){
    float S = accum[i * 2 + 0], SQ = accum[i * 2 + 1];
    float mean = S / (float)BATCH;
    float var = SQ / (float)BATCH - mean * mean;
    stats[i * 2 + 0] = mean;
    stats[i * 2 + 1] = 1.0f / sqrtf(var + EPSV);
  }
}

// ----------------------------------------------------- fused sel@key^T ----
// F_m[h1][h2] = sum_d selW[h1][d] * keyW[h2][d]
__global__ void fuse_mats_kernel(const float* __restrict__ asel, const float* __restrict__ akey,
                                 const float* __restrict__ csel, const float* __restrict__ ckey,
                                 float* __restrict__ ws){
  const int h1 = blockIdx.x;
  const int m  = blockIdx.y;
  const int h2 = threadIdx.x;
  const float* A; const float* Bm; float* out;
  if (m == 0){ A = asel;          Bm = akey;          out = ws + WS_F0; }
  else if (m == 1){ A = asel + HD*HD; Bm = akey + HD*HD; out = ws + WS_F1; }
  else { A = csel; Bm = ckey; out = ws + WS_M; }
  const float* arow = A + h1 * HD;
  const float* brow = Bm + h2 * HD;
  float acc = 0.f;
  #pragma unroll 4
  for (int d = 0; d < HD; ++d) acc = fmaf(arow[d], brow[d], acc);
  out[h1 * HD + h2] = acc;
}

// ------------------------------------------------------------- helpers ----
// Y-tile GEMM accumulate: acc[r] += sum_k X[b0t+r][k] * W[k*HD + d]
__device__ __forceinline__ void gemm_acc128(float* acc, const float* __restrict__ W,
                                            const float (*X)[HD], const int b0t, const int d){
  for (int k = 0; k < HD; k += 4){
    float w0 = W[(k + 0) * HD + d];
    float w1 = W[(k + 1) * HD + d];
    float w2 = W[(k + 2) * HD + d];
    float w3 = W[(k + 3) * HD + d];
    #pragma unroll
    for (int r = 0; r < 8; ++r){
      const float4 x4 = *reinterpret_cast<const float4*>(&X[b0t + r][k]);
      acc[r] = fmaf(x4.x, w0, acc[r]);
      acc[r] = fmaf(x4.y, w1, acc[r]);
      acc[r] = fmaf(x4.z, w2, acc[r]);
      acc[r] = fmaf(x4.w, w3, acc[r]);
    }
  }
}

// per-row dot over HD, 16 lanes per b row, lane0 writes dst[b] = dot*scale
__device__ __forceinline__ void rowdot16(const float (*A)[HD], const float (*Bv)[HD],
                                         float* dst, const float scale, const int t){
  const int b = t >> 4;
  const int i = t & 15;
  float p = 0.f;
  #pragma unroll
  for (int sstep = 0; sstep < 8; ++sstep){
    int hh = i + (sstep << 4);
    p = fmaf(A[b][hh], Bv[b][hh], p);
  }
  #pragma unroll
  for (int m = 8; m >= 1; m >>= 1) p += __shfl_xor(p, m, 16);
  if (i == 0) dst[b] = p * scale;
}

// ------------------------------------------------------------ main -------
__global__ __launch_bounds__(256, 2) void fused_main_kernel(
    const float* __restrict__ s, const float* __restrict__ a,
    const float* __restrict__ en_W, const float* __restrict__ en_b,
    const float* __restrict__ oa_W, const float* __restrict__ oa_b,
    const float* __restrict__ goal_W, const float* __restrict__ goal_b,
    const float* __restrict__ aval_W, const float* __restrict__ aval_b,
    const float* __restrict__ merge_W, const float* __restrict__ merge_b,
    const float* __restrict__ senc_W, const float* __restrict__ senc_b,
    const float* __restrict__ cval_W, const float* __restrict__ cval_b,
    const float* __restrict__ cW1, const float* __restrict__ cb1,
    const float* __restrict__ cW2, const float* __restrict__ cb2,
    const float* __restrict__ ws, float* __restrict__ out)
{
  __shared__ float xs[NAG][TB][SD];
  __shared__ float xa[NAG][TB][AD];
  __shared__ float sa[NAG][TB][HD];
  __shared__ float bufA[TB][HD], bufB[TB][HD], bufC[TB][HD];
  __shared__ float bufD[TB][HD], bufE[TB][HD], bufF[TB][HD];
  __shared__ float watt[5][TB];        // actor attention weights: [0..1]=oa, [2..4]=goal
  __shared__ float wcrit[NAG][NAG][TB];

  const int t = threadIdx.x;
  const int d = t & (HD - 1);
  const int bg = t >> 7;              // 0 or 1
  const int b0t = bg * 8;
  const int gb0 = blockIdx.x * TB;
  const float scale = 0.088388347648318447f;   // 1/sqrt(128)
  const float* stats = ws + WS_STATS;
  const float* F0 = ws + WS_F0;
  const float* F1 = ws + WS_F1;
  const float* Mm = ws + WS_M;

  // ---- stage normalized inputs (all agents) ----
  for (int row = t; row < NAG * TB; row += 256){
    const int n = row / TB, b = row % TB;
    const size_t gb = (size_t)gb0 + b;
    const float* srow = s + ((size_t)n * BATCH + gb) * SD;
    const float* st = stats + n * 40;
    #pragma unroll
    for (int c = 0; c < SD; ++c) xs[n][b][c] = (srow[c] - st[c * 2]) * st[c * 2 + 1];
    const float* arow = a + ((size_t)n * BATCH + gb) * AD;
    #pragma unroll
    for (int c = 0; c < AD; ++c) xa[n][b][c] = (arow[c] - st[(SD + c) * 2]) * st[(SD + c) * 2 + 1];
  }
  __syncthreads();

  // ======================= ACTOR (per agent) =======================
  for (int n = 0; n < NAG; ++n){
    // Phase A: en_enc -> bufA, oa_enc0 -> bufC, oa_enc1 -> bufD
    {
      const float* W = en_W + n * 6 * HD;
      const float bb = en_b[n * HD + d];
      float acc[8];
      #pragma unroll
      for (int r = 0; r < 8; ++r) acc[r] = bb;
      #pragma unroll
      for (int k = 0; k < 6; ++k){
        float w = W[k * HD + d];
        #pragma unroll
        for (int r = 0; r < 8; ++r){
          float xv = (k < 4) ? xs[n][b0t + r][k] : xa[n][b0t + r][k - 4];
          acc[r] = fmaf(xv, w, acc[r]);
        }
      }
      #pragma unroll
      for (int r = 0; r < 8; ++r) bufA[b0t + r][d] = lrelu(acc[r]);
    }
    #pragma unroll
    for (int j = 0; j < 2; ++j){
      const float* W = oa_W + n * 4 * HD;
      const float bb = oa_b[n * HD + d];
      float acc[8];
      #pragma unroll
      for (int r = 0; r < 8; ++r) acc[r] = bb;
      #pragma unroll
      for (int k = 0; k < 4; ++k){
        float w = W[k * HD + d];
        #pragma unroll
        for (int r = 0; r < 8; ++r) acc[r] = fmaf(xs[n][b0t + r][4 + 4 * j + k], w, acc[r]);
      }
      float (*dst)[HD] = (j == 0) ? bufC : bufD;
      #pragma unroll
      for (int r = 0; r < 8; ++r) dst[b0t + r][d] = lrelu(acc[r]);
    }
    __syncthreads();   // S1

    { // selk0 = en_enc @ F0 -> bufB
      float acc[8];
      #pragma unroll
      for (int r = 0; r < 8; ++r) acc[r] = 0.f;
      gemm_acc128(acc, F0, bufA, b0t, d);
      #pragma unroll
      for (int r = 0; r < 8; ++r) bufB[b0t + r][d] = acc[r];
    }
    __syncthreads();   // S2

    rowdot16(bufB, bufC, &watt[0][0], scale, t);
    rowdot16(bufB, bufD, &watt[1][0], scale, t);
    __syncthreads();   // S3

    if (t < TB){
      float l0 = watt[0][t], l1 = watt[1][t];
      float m = fmaxf(l0, l1);
      float e0 = __expf(l0 - m), e1 = __expf(l1 - m);
      float inv = 1.f / (e0 + e1);
      watt[0][t] = e0 * inv; watt[1][t] = e1 * inv;
    }
    __syncthreads();   // S4

    { // ov0 -> bufB (selk0 consumed); selk1 = en_enc @ F1 -> bufF
      float ov[8];
      #pragma unroll
      for (int r = 0; r < 8; ++r) ov[r] = 0.f;
      const float vb = aval_b[d];     // m=0
      #pragma unroll
      for (int j = 0; j < 2; ++j){
        float acc[8];
        #pragma unroll
        for (int r = 0; r < 8; ++r) acc[r] = vb;
        gemm_acc128(acc, aval_W, (j == 0) ? bufC : bufD, b0t, d);
        #pragma unroll
        for (int r = 0; r < 8; ++r) ov[r] = fmaf(watt[j][b0t + r], lrelu(acc[r]), ov[r]);
      }
      float acc2[8];
      #pragma unroll
      for (int r = 0; r < 8; ++r) acc2[r] = 0.f;
      gemm_acc128(acc2, F1, bufA, b0t, d);
      #pragma unroll
      for (int r = 0; r < 8; ++r){ bufB[b0t + r][d] = ov[r]; bufF[b0t + r][d] = acc2[r]; }
    }
    __syncthreads();   // S5

    { // g_enc0..2 -> bufC, bufD, bufE
      const float* W = goal_W + n * 2 * HD;
      const float bb = goal_b[n * HD + d];
      #pragma unroll
      for (int j = 0; j < 3; ++j){
        float acc[8];
        #pragma unroll
        for (int r = 0; r < 8; ++r) acc[r] = bb;
        #pragma unroll
        for (int k = 0; k < 2; ++k){
          float w = W[k * HD + d];
          #pragma unroll
          for (int r = 0; r < 8; ++r) acc[r] = fmaf(xs[n][b0t + r][12 + 2 * j + k], w, acc[r]);
        }
        float (*dst)[HD] = (j == 0) ? bufC : (j == 1) ? bufD : bufE;
        #pragma unroll
        for (int r = 0; r < 8; ++r) dst[b0t + r][d] = lrelu(acc[r]);
      }
    }
    __syncthreads();   // S6

    rowdot16(bufF, bufC, &watt[2][0], scale, t);
    rowdot16(bufF, bufD, &watt[3][0], scale, t);
    rowdot16(bufF, bufE, &watt[4][0], scale, t);
    __syncthreads();   // S7

    if (t < TB){
      float l0 = watt[2][t], l1 = watt[3][t], l2 = watt[4][t];
      float m = fmaxf(fmaxf(l0, l1), l2);
      float e0 = __expf(l0 - m), e1 = __expf(l1 - m), e2 = __expf(l2 - m);
      float inv = 1.f / (e0 + e1 + e2);
      watt[2][t] = e0 * inv; watt[3][t] = e1 * inv; watt[4][t] = e2 * inv;
    }
    __syncthreads();   // S8

    { // ov1 -> bufF (selk1 consumed)
      float ov[8];
      #pragma unroll
      for (int r = 0; r < 8; ++r) ov[r] = 0.f;
      const float vb = aval_b[HD + d];  // m=1
      #pragma unroll
      for (int j = 0; j < 3; ++j){
        float acc[8];
        #pragma unroll
        for (int r = 0; r < 8; ++r) acc[r] = vb;
        gemm_acc128(acc, aval_W + HD * HD, (j == 0) ? bufC : (j == 1) ? bufD : bufE, b0t, d);
        #pragma unroll
        for (int r = 0; r < 8; ++r) ov[r] = fmaf(watt[2 + j][b0t + r], lrelu(acc[r]), ov[r]);
      }
      #pragma unroll
      for (int r = 0; r < 8; ++r) bufF[b0t + r][d] = ov[r];
    }
    __syncthreads();   // S9

    { // merge: sa[n] = lrelu([en|ov0|ov1] @ merge_W + b)
      const float* Wm = merge_W + (size_t)n * 384 * HD;
      const float bb = merge_b[n * HD + d];
      float acc[8];
      #pragma unroll
      for (int r = 0; r < 8; ++r) acc[r] = bb;
      gemm_acc128(acc, Wm,              bufA, b0t, d);
      gemm_acc128(acc, Wm + 128 * HD,   bufB, b0t, d);
      gemm_acc128(acc, Wm + 256 * HD,   bufF, b0t, d);
      #pragma unroll
      for (int r = 0; r < 8; ++r) sa[n][b0t + r][d] = lrelu(acc[r]);
    }
    __syncthreads();   // S10
  }

  // ======================= CRITIC =======================
  // C1: logits for each agent i
  for (int i = 0; i < NAG; ++i){
    { // s_enc_i -> bufE
      const float* W = senc_W + i * SD * HD;
      const float bb = senc_b[i * HD + d];
      float acc[8];
      #pragma unroll
      for (int r = 0; r < 8; ++r) acc[r] = bb;
      #pragma unroll
      for (int k = 0; k < SD; ++k){
        float w = W[k * HD + d];
        #pragma unroll
        for (int r = 0; r < 8; ++r) acc[r] = fmaf(xs[i][b0t + r][k], w, acc[r]);
      }
      #pragma unroll
      for (int r = 0; r < 8; ++r) bufE[b0t + r][d] = lrelu(acc[r]);
    }
    __syncthreads();  // T1
    { // selsM = s_enc @ M -> bufD
      float acc[8];
      #pragma unroll
      for (int r = 0; r < 8; ++r) acc[r] = 0.f;
      gemm_acc128(acc, Mm, bufE, b0t, d);
      #pragma unroll
      for (int r = 0; r < 8; ++r) bufD[b0t + r][d] = acc[r];
    }
    __syncthreads();  // T2
    for (int j = 0; j < NAG; ++j)
      if (j != i) rowdot16(bufD, sa[j], &wcrit[i][j][0], scale, t);
    __syncthreads();  // T3
  }

  // softmax over j != i, and zero ov accumulators
  if (t < NAG * TB){
    const int i = t / TB, b = t % TB;
    const int j0 = (i == 0) ? 1 : 0;
    const int j1 = (i == 2) ? 1 : 2;
    float l0 = wcrit[i][j0][b], l1 = wcrit[i][j1][b];
    float m = fmaxf(l0, l1);
    float e0 = __expf(l0 - m), e1 = __expf(l1 - m);
    float inv = 1.f / (e0 + e1);
    wcrit[i][j0][b] = e0 * inv; wcrit[i][j1][b] = e1 * inv;
  }
  #pragma unroll
  for (int r = 0; r < 8; ++r){
    bufA[b0t + r][d] = 0.f; bufB[b0t + r][d] = 0.f; bufC[b0t + r][d] = 0.f;
  }
  __syncthreads();  // T4

  // C2: vals_j from sa[j], accumulate into ov_i (bufA/B/C) for i != j
  for (int j = 0; j < NAG; ++j){
    float acc[8];
    const float vb = cval_b[d];
    #pragma unroll
    for (int r = 0; r < 8; ++r) acc[r] = vb;
    gemm_acc128(acc, cval_W, sa[j], b0t, d);
    float v[8];
    #pragma unroll
    for (int r = 0; r < 8; ++r) v[r] = lrelu(acc[r]);
    for (int i = 0; i < NAG; ++i){
      if (i == j) continue;
      float (*ov)[HD] = (i == 0) ? bufA : (i == 1) ? bufB : bufC;
      #pragma unroll
      for (int r = 0; r < 8; ++r) ov[b0t + r][d] += wcrit[i][j][b0t + r] * v[r];
    }
  }
  __syncthreads();  // T5

  // C3: h and q per agent
  for (int i = 0; i < NAG; ++i){
    { // s_enc_i -> bufE (recompute)
      const float* W = senc_W + i * SD * HD;
      const float bb = senc_b[i * HD + d];
      float acc[8];
      #pragma unroll
      for (int r = 0; r < 8; ++r) acc[r] = bb;
      #pragma unroll
      for (int k = 0; k < SD; ++k){
        float w = W[k * HD + d];
        #pragma unroll
        for (int r = 0; r < 8; ++r) acc[r] = fmaf(xs[i][b0t + r][k], w, acc[r]);
      }
      #pragma unroll
      for (int r = 0; r < 8; ++r) bufE[b0t + r][d] = lrelu(acc[r]);
    }
    __syncthreads();  // T6
    { // h = lrelu([s_enc | ov_i] @ cW1 + cb1) -> bufF
      const float* W1 = cW1 + (size_t)i * 256 * HD;
      const float bb = cb1[i * HD + d];
      float acc[8];
      #pragma unroll
      for (int r = 0; r < 8; ++r) acc[r] = bb;
      gemm_acc128(acc, W1, bufE, b0t, d);
      float (*ov)[HD] = (i == 0) ? bufA : (i == 1) ? bufB : bufC;
      gemm_acc128(acc, W1 + 128 * HD, ov, b0t, d);
      #pragma unroll
      for (int r = 0; r < 8; ++r) bufF[b0t + r][d] = lrelu(acc[r]);
    }
    __syncthreads();  // T7
    { // q = h @ cW2 + cb2
      const int b = t >> 4;
      const int lane = t & 15;
      float p0 = 0.f, p1 = 0.f;
      #pragma unroll
      for (int sstep = 0; sstep < 8; ++sstep){
        int dd = lane + (sstep << 4);
        float hv = bufF[b][dd];
        p0 = fmaf(hv, cW2[(i * HD + dd) * 2 + 0], p0);
        p1 = fmaf(hv, cW2[(i * HD + dd) * 2 + 1], p1);
      }
      #pragma unroll
      for (int m = 8; m >= 1; m >>= 1){
        p0 += __shfl_xor(p0, m, 16);
        p1 += __shfl_xor(p1, m, 16);
      }
      if (lane == 0){
        const size_t gb = (size_t)gb0 + b;
        out[((size_t)i * BATCH + gb) * 2 + 0] = p0 + cb2[i * 2 + 0];
        out[((size_t)i * BATCH + gb) * 2 + 1] = p1 + cb2[i * 2 + 1];
      }
    }
    __syncthreads();  // T8
  }
}

// ------------------------------------------------------------ launch -----
extern "C" void kernel_launch(void* const* d_in, const int* in_sizes, int n_in,
                              void* d_out, int out_size, void* d_ws, size_t ws_size,
                              hipStream_t stream) {
  const float* s       = (const float*)d_in[0];
  const float* a       = (const float*)d_in[1];
  const float* en_W    = (const float*)d_in[2];
  const float* en_b    = (const float*)d_in[3];
  const float* oa_W    = (const float*)d_in[4];
  const float* oa_b    = (const float*)d_in[5];
  const float* goal_W  = (const float*)d_in[6];
  const float* goal_b  = (const float*)d_in[7];
  const float* akey_W  = (const float*)d_in[8];
  const float* asel_W  = (const float*)d_in[9];
  const float* aval_W  = (const float*)d_in[10];
  const float* aval_b  = (const float*)d_in[11];
  const float* merge_W = (const float*)d_in[12];
  const float* merge_b = (const float*)d_in[13];
  const float* senc_W  = (const float*)d_in[14];
  const float* senc_b  = (const float*)d_in[15];
  const float* ckey_W  = (const float*)d_in[16];
  const float* csel_W  = (const float*)d_in[17];
  const float* cval_W  = (const float*)d_in[18];
  const float* cval_b  = (const float*)d_in[19];
  const float* cW1     = (const float*)d_in[20];
  const float* cb1     = (const float*)d_in[21];
  const float* cW2     = (const float*)d_in[22];
  const float* cb2     = (const float*)d_in[23];
  float* ws = (float*)d_ws;
  float* out = (float*)d_out;

  // zero stat accumulators (atomicAdd targets)
  hipMemsetAsync((char*)d_ws + WS_ACCUM * sizeof(float), 0, 120 * sizeof(float), stream);

  stats_partial_kernel<<<48, 256, 0, stream>>>(s, a, ws + WS_ACCUM);
  stats_final_kernel<<<1, 64, 0, stream>>>(ws + WS_ACCUM, ws + WS_STATS);
  fuse_mats_kernel<<<dim3(HD, 3), HD, 0, stream>>>(asel_W, akey_W, csel_W, ckey_W, ws);
  fused_main_kernel<<<BATCH / TB, 256, 0, stream>>>(
      s, a, en_W, en_b, oa_W, oa_b, goal_W, goal_b, aval_W, aval_b,
      merge_W, merge_b, senc_W, senc_b, cval_W, cval_b, cW1, cb1, cW2, cb2,
      ws, out);
}

// Round 2
// 572.402 us; speedup vs baseline: 1.8413x; 1.8413x over previous
//
#include <hip/hip_runtime.h>

#define NAG 3
#define BATCH 32768
#define HD 128
#define SD 18
#define TB 32
#define EPSV 1e-5f
#define SCALE 0.08838834764831845f

typedef __attribute__((ext_vector_type(8))) short short8;
typedef __attribute__((ext_vector_type(4))) float f32x4;

// ---------------- ws byte layout ----------------
#define WSB_STATS 0          // 480B f32  [3][20][2] mean,istd
#define WSB_ACCUM 512        // 480B f32  sum,sumsq
#define WSB_F     1024       // 3*16384 f32 scratch (F0,F1,M)
#define WSB_W     197632     // bf16 weight area (ushort units below)
// ushort offsets within weight area (h blob, l blob = h + elems)
#define OFF_FT0 0            // 16384, l +16384
#define OFF_FT1 32768
#define OFF_MT  65536
#define OFF_AV0 98304
#define OFF_AV1 131072
#define OFF_CV  163840
#define OFF_MG(n) (196608 + (n)*98304)   // 49152, l +49152
#define OFF_C1(n) (491520 + (n)*65536)   // 32768, l +32768
#define OFF_C2(n) (688128 + (n)*4096)    // 2048,  l +2048
#define OFF_SW(n) (700416 + (n)*57344)   // 28672, l +28672

// ---------------- LDS byte layout (113024 total) ----------------
#define XN_O    0        // 3 agents x (h[32][32]bf16 2048 | l 2048)
#define EN_O    12288    // h[32][128]bf16 8192 | l 8192
#define SLICE_O 28672
#define OV0_O   45056
#define SA_O    61440    // 3 x 16384
#define PART_O  110592   // [8][32] f32
#define EP_O    111616   // [32] f32
#define ESUM_O  111744   // [32] f32
#define LW_O    111872   // [3][3][32] f32
#define SM_TOTAL 113024

__device__ __forceinline__ float lrelu(float x){ return x >= 0.0f ? x : 0.01f * x; }
__device__ __forceinline__ f32x4 lrelu4(f32x4 v){
  f32x4 r; r[0]=lrelu(v[0]); r[1]=lrelu(v[1]); r[2]=lrelu(v[2]); r[3]=lrelu(v[3]); return r;
}
__device__ __forceinline__ f32x4 binit(float b){ f32x4 c; c[0]=b;c[1]=b;c[2]=b;c[3]=b; return c; }
__device__ __forceinline__ unsigned short f2bf(float f){
  unsigned int u = __float_as_uint(f);
  unsigned int r = (u + 0x7FFFu + ((u >> 16) & 1u)) >> 16;
  return (unsigned short)r;
}
__device__ __forceinline__ float bf2f(unsigned short h){
  return __uint_as_float(((unsigned int)h) << 16);
}

// ---------------- prep: batch stats ----------------
__global__ void stats_partial_kernel(const float* __restrict__ s,
                                     const float* __restrict__ a,
                                     float* __restrict__ accum){
  const int n = blockIdx.x >> 4;
  const int chunk = blockIdx.x & 15;
  const int t = threadIdx.x;
  const int rows = BATCH / 16;
  const int b0 = chunk * rows;
  float sum[20], sq[20];
  #pragma unroll
  for (int c = 0; c < 20; ++c){ sum[c] = 0.f; sq[c] = 0.f; }
  for (int b = b0 + t; b < b0 + rows; b += 256){
    const float* row = s + ((size_t)n * BATCH + b) * SD;
    #pragma unroll
    for (int c = 0; c < SD; ++c){ float v = row[c]; sum[c] += v; sq[c] += v * v; }
    const float* ra = a + ((size_t)n * BATCH + b) * 2;
    #pragma unroll
    for (int c = 0; c < 2; ++c){ float v = ra[c]; sum[SD + c] += v; sq[SD + c] += v * v; }
  }
  __shared__ float red[256];
  for (int c = 0; c < 20; ++c){
    red[t] = sum[c]; __syncthreads();
    for (int off = 128; off > 0; off >>= 1){ if (t < off) red[t] += red[t + off]; __syncthreads(); }
    if (t == 0) atomicAdd(&accum[(n * 20 + c) * 2 + 0], red[0]);
    __syncthreads();
    red[t] = sq[c]; __syncthreads();
    for (int off = 128; off > 0; off >>= 1){ if (t < off) red[t] += red[t + off]; __syncthreads(); }
    if (t == 0) atomicAdd(&accum[(n * 20 + c) * 2 + 1], red[0]);
    __syncthreads();
  }
}

__global__ void stats_final_kernel(const float* __restrict__ accum,
                                   float* __restrict__ stats){
  int i = threadIdx.x;
  if (i < 60){
    float S = accum[i * 2 + 0], SQ = accum[i * 2 + 1];
    float mean = S / (float)BATCH;
    float var = SQ / (float)BATCH - mean * mean;
    stats[i * 2 + 0] = mean;
    stats[i * 2 + 1] = 1.0f / sqrtf(var + EPSV);
  }
}

// ---------------- prep: F_m = sel @ key^T (f32) ----------------
__global__ void fuse_mats_kernel(const float* __restrict__ asel, const float* __restrict__ akey,
                                 const float* __restrict__ csel, const float* __restrict__ ckey,
                                 float* __restrict__ F){
  const int h1 = blockIdx.x;
  const int m  = blockIdx.y;
  const int h2 = threadIdx.x;
  const float* A; const float* Bm;
  if (m == 0){ A = asel;            Bm = akey; }
  else if (m == 1){ A = asel + HD*HD; Bm = akey + HD*HD; }
  else { A = csel; Bm = ckey; }
  const float* arow = A + h1 * HD;
  const float* brow = Bm + h2 * HD;
  float acc = 0.f;
  #pragma unroll 4
  for (int d = 0; d < HD; ++d) acc = fmaf(arow[d], brow[d], acc);
  F[m * HD * HD + h1 * HD + h2] = acc;
}

// ---------------- prep: split-bf16 transpose  dst[c][k] = src[k][c] ----------------
__global__ void splitT_kernel(const float* __restrict__ src, unsigned short* __restrict__ dh,
                              unsigned short* __restrict__ dl, int K, int Csrc, int Cdst){
  int idx = blockIdx.x * 256 + threadIdx.x;
  if (idx >= K * Cdst) return;
  int k = idx / Cdst, c = idx - k * Cdst;
  float v = (c < Csrc) ? src[(size_t)k * Csrc + c] : 0.f;
  unsigned short hi = f2bf(v);
  float lo = v - bf2f(hi);
  dh[(size_t)c * K + k] = hi;
  dl[(size_t)c * K + k] = f2bf(lo);
}

// ---------------- prep: packed small-encoder weights [896 cols][32 k] per agent ----------------
__global__ void smallpack_kernel(const float* __restrict__ en_W, const float* __restrict__ oa_W,
                                 const float* __restrict__ goal_W, const float* __restrict__ senc_W,
                                 unsigned short* __restrict__ wsu){
  int idx = blockIdx.x * 256 + threadIdx.x;
  if (idx >= 3 * 896 * 32) return;
  int k = idx & 31; int c = (idx >> 5) % 896; int n = idx / (896 * 32);
  int tt = c >> 7, cc = c & 127;
  float v = 0.f;
  if (tt == 0){
    if (k < 4) v = en_W[(size_t)(n*6 + k)*128 + cc];
    else if (k == 18 || k == 19) v = en_W[(size_t)(n*6 + 4 + (k-18))*128 + cc];
  } else if (tt <= 2){
    int j = tt - 1; int kk = k - (4 + 4*j);
    if (kk >= 0 && kk < 4) v = oa_W[(size_t)(n*4 + kk)*128 + cc];
  } else if (tt <= 5){
    int j = tt - 3; int kk = k - (12 + 2*j);
    if (kk >= 0 && kk < 2) v = goal_W[(size_t)(n*2 + kk)*128 + cc];
  } else {
    if (k < 18) v = senc_W[(size_t)(n*18 + k)*128 + cc];
  }
  unsigned short hi = f2bf(v); float lo = v - bf2f(hi);
  unsigned short* dh = wsu + OFF_SW(n);
  dh[c * 32 + k] = hi;
  dh[28672 + c * 32 + k] = f2bf(lo);
}

// ---------------- MFMA helpers ----------------
// A-frag from split tile (row stride 256B, hi at base, lo at base+8192), XOR-swizzled
__device__ __forceinline__ void ldA(const unsigned char* sm, int base, int mi, int ks, int lane,
                                    short8& h, short8& l){
  int row = mi * 16 + (lane & 15);
  int bc  = ks * 64 + ((lane >> 4) << 4);
  int off = base + row * 256 + (bc ^ ((row & 7) << 4));
  h = *(const short8*)(sm + off);
  l = *(const short8*)(sm + off + 8192);
}
// A-frag from K=32 split tile (row stride 64B, lo at +2048)
__device__ __forceinline__ void ldA32(const unsigned char* sm, int base, int mi, int lane,
                                      short8& h, short8& l){
  int row = mi * 16 + (lane & 15);
  int bc  = (lane >> 4) << 4;
  int off = base + row * 64 + (bc ^ ((row & 3) << 4));
  h = *(const short8*)(sm + off);
  l = *(const short8*)(sm + off + 2048);
}

#define MM3(acc, ah, al, bh, bl) \
  acc = __builtin_amdgcn_mfma_f32_16x16x32_bf16(ah, bh, acc, 0, 0, 0); \
  acc = __builtin_amdgcn_mfma_f32_16x16x32_bf16(ah, bl, acc, 0, 0, 0); \
  acc = __builtin_amdgcn_mfma_f32_16x16x32_bf16(al, bh, acc, 0, 0, 0);

// K=128 GEMM segment: 4 ksteps, both m-tiles, weights Wt[c][k] row-stride K
__device__ __forceinline__ void gemmA(f32x4& c0, f32x4& c1, const unsigned char* sm, int abase,
                                      const unsigned short* wh, const unsigned short* wl,
                                      int K, int bcol, int kBaseB, int lane){
  const size_t bb = (size_t)bcol * K + kBaseB + ((lane >> 4) << 3);
  #pragma unroll
  for (int ks = 0; ks < 4; ++ks){
    short8 ah0, al0, ah1, al1;
    ldA(sm, abase, 0, ks, lane, ah0, al0);
    ldA(sm, abase, 1, ks, lane, ah1, al1);
    const short8 bh = *(const short8*)(wh + bb + ks * 32);
    const short8 bl = *(const short8*)(wl + bb + ks * 32);
    MM3(c0, ah0, al0, bh, bl);
    MM3(c1, ah1, al1, bh, bl);
  }
}
// K=32 GEMM (packed small encoders)
__device__ __forceinline__ void gemmS(f32x4& c0, f32x4& c1, const unsigned char* sm, int abase,
                                      const unsigned short* wh, const unsigned short* wl,
                                      int bcol, int lane){
  const size_t bb = (size_t)bcol * 32 + ((lane >> 4) << 3);
  short8 ah0, al0, ah1, al1;
  ldA32(sm, abase, 0, lane, ah0, al0);
  ldA32(sm, abase, 1, lane, ah1, al1);
  const short8 bh = *(const short8*)(wh + bb);
  const short8 bl = *(const short8*)(wl + bb);
  MM3(c0, ah0, al0, bh, bl);
  MM3(c1, ah1, al1, bh, bl);
}

// D-frag -> split tile write (row stride 256B)
__device__ __forceinline__ void stTile(unsigned char* sm, int base, int mi, int lane, int col, f32x4 v){
  #pragma unroll
  for (int r = 0; r < 4; ++r){
    int row = mi * 16 + ((lane >> 4) << 2) + r;
    int bc  = col * 2;
    int off = base + row * 256 + (bc ^ ((row & 7) << 4));
    unsigned short hi = f2bf(v[r]);
    *(unsigned short*)(sm + off) = hi;
    *(unsigned short*)(sm + off + 8192) = f2bf(v[r] - bf2f(hi));
  }
}

// per-row dot of D-frag regs with split tile; partials to PART[wave][32]
__device__ __forceinline__ void dotTile(unsigned char* sm, int tbase, const f32x4 d0, const f32x4 d1,
                                        int lane, int wave, int col){
  float* part = (float*)(sm + PART_O);
  #pragma unroll
  for (int mi = 0; mi < 2; ++mi){
    #pragma unroll
    for (int r = 0; r < 4; ++r){
      int row = mi * 16 + ((lane >> 4) << 2) + r;
      int bc  = col * 2;
      int off = tbase + row * 256 + (bc ^ ((row & 7) << 4));
      float v = bf2f(*(const unsigned short*)(sm + off)) +
                bf2f(*(const unsigned short*)(sm + off + 8192));
      float p = (mi ? d1[r] : d0[r]) * v;
      p += __shfl_xor(p, 1, 16);
      p += __shfl_xor(p, 2, 16);
      p += __shfl_xor(p, 4, 16);
      p += __shfl_xor(p, 8, 16);
      if ((lane & 15) == 0) part[wave * 32 + row] = p;
    }
  }
}

// ---------------- main fused kernel ----------------
__global__ __launch_bounds__(512, 2) void fused_kernel(
    const float* __restrict__ s, const float* __restrict__ a,
    const float* __restrict__ en_b, const float* __restrict__ oa_b,
    const float* __restrict__ goal_b, const float* __restrict__ aval_b,
    const float* __restrict__ merge_b, const float* __restrict__ senc_b,
    const float* __restrict__ cval_b, const float* __restrict__ cb1,
    const float* __restrict__ cb2, const unsigned char* __restrict__ wsc,
    float* __restrict__ out)
{
  __shared__ __align__(16) unsigned char SM[SM_TOTAL];
  unsigned char* sm = SM;
  const int t = threadIdx.x;
  const int lane = t & 63;
  const int wave = t >> 6;
  const int col = wave * 16 + (lane & 15);
  const int gb0 = blockIdx.x * TB;
  const float* stats = (const float*)(wsc + WSB_STATS);
  const unsigned short* wsu = (const unsigned short*)(wsc + WSB_W);
  const f32x4 Z = binit(0.f);

  // ---- stage normalized inputs as split-bf16 K=32 tiles ----
  if (t < 96){
    int n = t >> 5, row = t & 31;
    size_t gb = (size_t)gb0 + row;
    const float* st = stats + n * 40;
    const float* srow = s + ((size_t)n * BATCH + gb) * SD;
    const float* arow = a + ((size_t)n * BATCH + gb) * 2;
    #pragma unroll
    for (int c = 0; c < 32; ++c){
      float v = 0.f;
      if (c < 18) v = (srow[c] - st[c*2]) * st[c*2+1];
      else if (c < 20) v = (arow[c-18] - st[c*2]) * st[c*2+1];
      unsigned short hi = f2bf(v);
      int off = XN_O + n * 4096 + row * 64 + ((c * 2) ^ ((row & 3) << 4));
      *(unsigned short*)(sm + off) = hi;
      *(unsigned short*)(sm + off + 2048) = f2bf(v - bf2f(hi));
    }
  }
  __syncthreads();

  // ======================= ACTOR =======================
  #pragma unroll 1
  for (int n = 0; n < NAG; ++n){
    const unsigned short* swh = wsu + OFF_SW(n);
    const unsigned short* swl = swh + 28672;
    // en_enc -> EN
    {
      f32x4 v0 = binit(en_b[n*HD + col]), v1 = v0;
      gemmS(v0, v1, sm, XN_O + n*4096, swh, swl, 0 + col, lane);
      stTile(sm, EN_O, 0, lane, col, lrelu4(v0));
      stTile(sm, EN_O, 1, lane, col, lrelu4(v1));
    }
    __syncthreads();
    // selk0 = en@F0, selk1 = en@F1 (regs)
    f32x4 sk0a = Z, sk0b = Z, sk1a = Z, sk1b = Z;
    gemmA(sk0a, sk0b, sm, EN_O, wsu + OFF_FT0, wsu + OFF_FT0 + 16384, 128, col, 0, lane);
    gemmA(sk1a, sk1b, sm, EN_O, wsu + OFF_FT1, wsu + OFF_FT1 + 16384, 128, col, 0, lane);

    // ---- oa attention (m=0, 2 slices), exp without max-sub ----
    f32x4 ov0a = Z, ov0b = Z;
    #pragma unroll 1
    for (int j = 0; j < 2; ++j){
      __syncthreads();                      // protect SLICE vs previous readers
      f32x4 v0 = binit(oa_b[n*HD + col]), v1 = v0;
      gemmS(v0, v1, sm, XN_O + n*4096, swh, swl, 128*(1+j) + col, lane);
      stTile(sm, SLICE_O, 0, lane, col, lrelu4(v0));
      stTile(sm, SLICE_O, 1, lane, col, lrelu4(v1));
      __syncthreads();
      dotTile(sm, SLICE_O, sk0a, sk0b, lane, wave, col);
      __syncthreads();
      if (t < TB){
        const float* part = (const float*)(sm + PART_O);
        float tot = 0.f;
        #pragma unroll
        for (int w2 = 0; w2 < 8; ++w2) tot += part[w2*32 + t];
        float e = __expf(tot * SCALE);
        ((float*)(sm + EP_O))[t] = e;
        float* es = (float*)(sm + ESUM_O);
        es[t] = (j == 0) ? e : es[t] + e;
      }
      __syncthreads();
      f32x4 w0 = binit(aval_b[col]), w1 = w0;
      gemmA(w0, w1, sm, SLICE_O, wsu + OFF_AV0, wsu + OFF_AV0 + 16384, 128, col, 0, lane);
      const float* eP = (const float*)(sm + EP_O);
      #pragma unroll
      for (int r = 0; r < 4; ++r){
        int row0 = ((lane >> 4) << 2) + r;
        ov0a[r] += eP[row0]      * lrelu(w0[r]);
        ov0b[r] += eP[row0 + 16] * lrelu(w1[r]);
      }
    }
    // ov0 = acc/esum -> OV0
    {
      const float* es = (const float*)(sm + ESUM_O);
      f32x4 o0, o1;
      #pragma unroll
      for (int r = 0; r < 4; ++r){
        int row0 = ((lane >> 4) << 2) + r;
        o0[r] = ov0a[r] / es[row0];
        o1[r] = ov0b[r] / es[row0 + 16];
      }
      stTile(sm, OV0_O, 0, lane, col, o0);
      stTile(sm, OV0_O, 1, lane, col, o1);
    }

    // ---- goal attention (m=1, 3 slices) ----
    f32x4 ov1a = Z, ov1b = Z;
    #pragma unroll 1
    for (int j = 0; j < 3; ++j){
      __syncthreads();
      f32x4 v0 = binit(goal_b[n*HD + col]), v1 = v0;
      gemmS(v0, v1, sm, XN_O + n*4096, swh, swl, 128*(3+j) + col, lane);
      stTile(sm, SLICE_O, 0, lane, col, lrelu4(v0));
      stTile(sm, SLICE_O, 1, lane, col, lrelu4(v1));
      __syncthreads();
      dotTile(sm, SLICE_O, sk1a, sk1b, lane, wave, col);
      __syncthreads();
      if (t < TB){
        const float* part = (const float*)(sm + PART_O);
        float tot = 0.f;
        #pragma unroll
        for (int w2 = 0; w2 < 8; ++w2) tot += part[w2*32 + t];
        float e = __expf(tot * SCALE);
        ((float*)(sm + EP_O))[t] = e;
        float* es = (float*)(sm + ESUM_O);
        es[t] = (j == 0) ? e : es[t] + e;
      }
      __syncthreads();
      f32x4 w0 = binit(aval_b[HD + col]), w1 = w0;
      gemmA(w0, w1, sm, SLICE_O, wsu + OFF_AV1, wsu + OFF_AV1 + 16384, 128, col, 0, lane);
      const float* eP = (const float*)(sm + EP_O);
      #pragma unroll
      for (int r = 0; r < 4; ++r){
        int row0 = ((lane >> 4) << 2) + r;
        ov1a[r] += eP[row0]      * lrelu(w0[r]);
        ov1b[r] += eP[row0 + 16] * lrelu(w1[r]);
      }
    }
    __syncthreads();                        // all vals reads of SLICE done
    // ov1 -> SLICE
    {
      const float* es = (const float*)(sm + ESUM_O);
      f32x4 o0, o1;
      #pragma unroll
      for (int r = 0; r < 4; ++r){
        int row0 = ((lane >> 4) << 2) + r;
        o0[r] = ov1a[r] / es[row0];
        o1[r] = ov1b[r] / es[row0 + 16];
      }
      stTile(sm, SLICE_O, 0, lane, col, o0);
      stTile(sm, SLICE_O, 1, lane, col, o1);
    }
    __syncthreads();
    // merge: sa[n] = lrelu([en|ov0|ov1] @ merge_W + b)
    {
      const unsigned short* mh = wsu + OFF_MG(n);
      const unsigned short* ml = mh + 49152;
      f32x4 m0 = binit(merge_b[n*HD + col]), m1 = m0;
      gemmA(m0, m1, sm, EN_O,    mh, ml, 384, col, 0,   lane);
      gemmA(m0, m1, sm, OV0_O,   mh, ml, 384, col, 128, lane);
      gemmA(m0, m1, sm, SLICE_O, mh, ml, 384, col, 256, lane);
      stTile(sm, SA_O + n*16384, 0, lane, col, lrelu4(m0));
      stTile(sm, SA_O + n*16384, 1, lane, col, lrelu4(m1));
    }
    __syncthreads();                        // sa[n] ready; protect EN/OV0/SLICE reuse
  }

  // ======================= CRITIC =======================
  // Q1/Q2: per i: s_enc_i, selsM_i = s_enc@M, raw logits vs sa_j
  #pragma unroll 1
  for (int i = 0; i < NAG; ++i){
    const unsigned short* swh = wsu + OFF_SW(i);
    const unsigned short* swl = swh + 28672;
    f32x4 e0 = binit(senc_b[i*HD + col]), e1 = e0;
    gemmS(e0, e1, sm, XN_O + i*4096, swh, swl, 768 + col, lane);
    stTile(sm, EN_O, 0, lane, col, lrelu4(e0));
    stTile(sm, EN_O, 1, lane, col, lrelu4(e1));
    __syncthreads();
    f32x4 sm0 = Z, sm1 = Z;
    gemmA(sm0, sm1, sm, EN_O, wsu + OFF_MT, wsu + OFF_MT + 16384, 128, col, 0, lane);
    #pragma unroll 1
    for (int j = 0; j < NAG; ++j){
      if (j == i) continue;
      dotTile(sm, SA_O + j*16384, sm0, sm1, lane, wave, col);
      __syncthreads();
      if (t < TB){
        const float* part = (const float*)(sm + PART_O);
        float tot = 0.f;
        #pragma unroll
        for (int w2 = 0; w2 < 8; ++w2) tot += part[w2*32 + t];
        ((float*)(sm + LW_O))[(i*3 + j)*32 + t] = tot;
      }
      __syncthreads();
    }
  }
  // Q3: softmax over j != i (in place in LW)
  if (t < TB){
    float* LW = (float*)(sm + LW_O);
    #pragma unroll
    for (int i = 0; i < NAG; ++i){
      int j0 = (i == 0) ? 1 : 0;
      int j1 = (i == 2) ? 1 : 2;
      float l0 = LW[(i*3 + j0)*32 + t] * SCALE;
      float l1 = LW[(i*3 + j1)*32 + t] * SCALE;
      float q0 = __expf(l0), q1 = __expf(l1);
      float inv = 1.f / (q0 + q1);
      LW[(i*3 + j0)*32 + t] = q0 * inv;
      LW[(i*3 + j1)*32 + t] = q1 * inv;
    }
  }
  __syncthreads();
  // Q4: vals_j once, accumulate ov_i (regs)
  f32x4 oc00 = Z, oc01 = Z, oc10 = Z, oc11 = Z, oc20 = Z, oc21 = Z;
  {
    const float* LW = (const float*)(sm + LW_O);
    #pragma unroll 1
    for (int j = 0; j < NAG; ++j){
      f32x4 v0 = binit(cval_b[col]), v1 = v0;
      gemmA(v0, v1, sm, SA_O + j*16384, wsu + OFF_CV, wsu + OFF_CV + 16384, 128, col, 0, lane);
      v0 = lrelu4(v0); v1 = lrelu4(v1);
      #pragma unroll
      for (int i = 0; i < NAG; ++i){
        if (i == j) continue;
        f32x4& o0 = (i == 0) ? oc00 : ((i == 1) ? oc10 : oc20);
        f32x4& o1 = (i == 0) ? oc01 : ((i == 1) ? oc11 : oc21);
        #pragma unroll
        for (int r = 0; r < 4; ++r){
          int row0 = ((lane >> 4) << 2) + r;
          o0[r] += LW[(i*3 + j)*32 + row0]      * v0[r];
          o1[r] += LW[(i*3 + j)*32 + row0 + 16] * v1[r];
        }
      }
    }
  }
  __syncthreads();
  // Q5: per i: h = lrelu([s_enc|ov]@cW1+b), q = h@cW2 + cb2
  #pragma unroll 1
  for (int i = 0; i < NAG; ++i){
    const unsigned short* swh = wsu + OFF_SW(i);
    const unsigned short* swl = swh + 28672;
    f32x4 se0 = binit(senc_b[i*HD + col]), se1 = se0;
    gemmS(se0, se1, sm, XN_O + i*4096, swh, swl, 768 + col, lane);
    stTile(sm, EN_O, 0, lane, col, lrelu4(se0));
    stTile(sm, EN_O, 1, lane, col, lrelu4(se1));
    {
      f32x4 o0 = (i == 0) ? oc00 : ((i == 1) ? oc10 : oc20);
      f32x4 o1 = (i == 0) ? oc01 : ((i == 1) ? oc11 : oc21);
      stTile(sm, OV0_O, 0, lane, col, o0);
      stTile(sm, OV0_O, 1, lane, col, o1);
    }
    __syncthreads();
    const unsigned short* c1h = wsu + OFF_C1(i);
    const unsigned short* c1l = c1h + 32768;
    f32x4 h0 = binit(cb1[i*HD + col]), h1 = h0;
    gemmA(h0, h1, sm, EN_O,  c1h, c1l, 256, col, 0,   lane);
    gemmA(h0, h1, sm, OV0_O, c1h, c1l, 256, col, 128, lane);
    stTile(sm, SLICE_O, 0, lane, col, lrelu4(h0));
    stTile(sm, SLICE_O, 1, lane, col, lrelu4(h1));
    __syncthreads();
    f32x4 q0 = Z, q1 = Z;
    gemmA(q0, q1, sm, SLICE_O, wsu + OFF_C2(i), wsu + OFF_C2(i) + 2048, 128, (lane & 15), 0, lane);
    if (wave == 0 && (lane & 15) < 2){
      int c2 = lane & 15;
      float bb = cb2[i*2 + c2];
      #pragma unroll
      for (int r = 0; r < 4; ++r){
        int row = ((lane >> 4) << 2) + r;
        out[((size_t)i*BATCH + gb0 + row)*2 + c2]      = q0[r] + bb;
        out[((size_t)i*BATCH + gb0 + row + 16)*2 + c2] = q1[r] + bb;
      }
    }
    __syncthreads();
  }
}

// ------------------------------------------------------------ launch -----
extern "C" void kernel_launch(void* const* d_in, const int* in_sizes, int n_in,
                              void* d_out, int out_size, void* d_ws, size_t ws_size,
                              hipStream_t stream) {
  const float* s       = (const float*)d_in[0];
  const float* a       = (const float*)d_in[1];
  const float* en_W    = (const float*)d_in[2];
  const float* en_b    = (const float*)d_in[3];
  const float* oa_W    = (const float*)d_in[4];
  const float* oa_b    = (const float*)d_in[5];
  const float* goal_W  = (const float*)d_in[6];
  const float* goal_b  = (const float*)d_in[7];
  const float* akey_W  = (const float*)d_in[8];
  const float* asel_W  = (const float*)d_in[9];
  const float* aval_W  = (const float*)d_in[10];
  const float* aval_b  = (const float*)d_in[11];
  const float* merge_W = (const float*)d_in[12];
  const float* merge_b = (const float*)d_in[13];
  const float* senc_W  = (const float*)d_in[14];
  const float* senc_b  = (const float*)d_in[15];
  const float* ckey_W  = (const float*)d_in[16];
  const float* csel_W  = (const float*)d_in[17];
  const float* cval_W  = (const float*)d_in[18];
  const float* cval_b  = (const float*)d_in[19];
  const float* cW1     = (const float*)d_in[20];
  const float* cb1     = (const float*)d_in[21];
  const float* cW2     = (const float*)d_in[22];
  const float* cb2     = (const float*)d_in[23];
  unsigned char* wsc = (unsigned char*)d_ws;
  float* F = (float*)(wsc + WSB_F);
  unsigned short* wsu = (unsigned short*)(wsc + WSB_W);
  float* out = (float*)d_out;

  hipMemsetAsync(wsc + WSB_ACCUM, 0, 480, stream);
  stats_partial_kernel<<<48, 256, 0, stream>>>(s, a, (float*)(wsc + WSB_ACCUM));
  stats_final_kernel<<<1, 64, 0, stream>>>((const float*)(wsc + WSB_ACCUM), (float*)(wsc + WSB_STATS));
  fuse_mats_kernel<<<dim3(HD, 3), HD, 0, stream>>>(asel_W, akey_W, csel_W, ckey_W, F);

  splitT_kernel<<<64, 256, 0, stream>>>(F,           wsu + OFF_FT0, wsu + OFF_FT0 + 16384, 128, 128, 128);
  splitT_kernel<<<64, 256, 0, stream>>>(F + 16384,   wsu + OFF_FT1, wsu + OFF_FT1 + 16384, 128, 128, 128);
  splitT_kernel<<<64, 256, 0, stream>>>(F + 32768,   wsu + OFF_MT,  wsu + OFF_MT  + 16384, 128, 128, 128);
  splitT_kernel<<<64, 256, 0, stream>>>(aval_W,          wsu + OFF_AV0, wsu + OFF_AV0 + 16384, 128, 128, 128);
  splitT_kernel<<<64, 256, 0, stream>>>(aval_W + 16384,  wsu + OFF_AV1, wsu + OFF_AV1 + 16384, 128, 128, 128);
  splitT_kernel<<<64, 256, 0, stream>>>(cval_W,          wsu + OFF_CV,  wsu + OFF_CV  + 16384, 128, 128, 128);
  for (int n = 0; n < 3; ++n){
    splitT_kernel<<<192, 256, 0, stream>>>(merge_W + (size_t)n*49152, wsu + OFF_MG(n), wsu + OFF_MG(n) + 49152, 384, 128, 128);
    splitT_kernel<<<128, 256, 0, stream>>>(cW1     + (size_t)n*32768, wsu + OFF_C1(n), wsu + OFF_C1(n) + 32768, 256, 128, 128);
    splitT_kernel<<<8,   256, 0, stream>>>(cW2     + (size_t)n*256,   wsu + OFF_C2(n), wsu + OFF_C2(n) + 2048,  128, 2, 16);
  }
  smallpack_kernel<<<336, 256, 0, stream>>>(en_W, oa_W, goal_W, senc_W, wsu);

  fused_kernel<<<BATCH / TB, 512, 0, stream>>>(
      s, a, en_b, oa_b, goal_b, aval_b, merge_b, senc_b, cval_b, cb1, cb2,
      (const unsigned char*)wsc, out);
}

// Round 3
// 476.509 us; speedup vs baseline: 2.2119x; 1.2012x over previous
//
#include <hip/hip_runtime.h>

#define NAG 3
#define BATCH 32768
#define HD 128
#define SD 18
#define TB 32
#define EPSV 1e-5f
#define SCALE 0.08838834764831845f

typedef __attribute__((ext_vector_type(8))) short short8;
typedef __attribute__((ext_vector_type(4))) float f32x4;

// ---------------- ws byte layout ----------------
#define WSB_STATS 0          // 480B f32  [3][20][2] mean,istd
#define WSB_ACCUM 512        // 480B f32  sum,sumsq
#define WSB_F     1024       // 3*16384 f32 scratch (F0,F1,M)
#define WSB_W     197632     // bf16 weight area (ushort units below)
#define OFF_FT0 0            // 16384, l +16384
#define OFF_FT1 32768
#define OFF_MT  65536
#define OFF_AV0 98304
#define OFF_AV1 131072
#define OFF_CV  163840
#define OFF_MG(n) (196608 + (n)*98304)   // 49152, l +49152
#define OFF_C1(n) (491520 + (n)*65536)   // 32768, l +32768
#define OFF_C2(n) (688128 + (n)*4096)    // 2048,  l +2048 (fallback only)
#define OFF_SW(n) (700416 + (n)*57344)   // 28672, l +28672
#define WSB_SA  2097152      // bf16 sa [3][32768][128] = 25165824 B (path A only)
#define SA_BYTES ((size_t)NAG * BATCH * HD * 2)

__device__ __forceinline__ float lrelu(float x){ return x >= 0.0f ? x : 0.01f * x; }
__device__ __forceinline__ f32x4 lrelu4(f32x4 v){
  f32x4 r; r[0]=lrelu(v[0]); r[1]=lrelu(v[1]); r[2]=lrelu(v[2]); r[3]=lrelu(v[3]); return r;
}
__device__ __forceinline__ f32x4 binit(float b){ f32x4 c; c[0]=b;c[1]=b;c[2]=b;c[3]=b; return c; }
__device__ __forceinline__ unsigned short f2bf(float f){
  unsigned int u = __float_as_uint(f);
  unsigned int r = (u + 0x7FFFu + ((u >> 16) & 1u)) >> 16;
  return (unsigned short)r;
}
__device__ __forceinline__ float bf2f(unsigned short h){
  return __uint_as_float(((unsigned int)h) << 16);
}

// ---------------- prep: batch stats ----------------
__global__ void stats_partial_kernel(const float* __restrict__ s,
                                     const float* __restrict__ a,
                                     float* __restrict__ accum){
  const int n = blockIdx.x >> 4;
  const int chunk = blockIdx.x & 15;
  const int t = threadIdx.x;
  const int rows = BATCH / 16;
  const int b0 = chunk * rows;
  float sum[20], sq[20];
  #pragma unroll
  for (int c = 0; c < 20; ++c){ sum[c] = 0.f; sq[c] = 0.f; }
  for (int b = b0 + t; b < b0 + rows; b += 256){
    const float* row = s + ((size_t)n * BATCH + b) * SD;
    #pragma unroll
    for (int c = 0; c < SD; ++c){ float v = row[c]; sum[c] += v; sq[c] += v * v; }
    const float* ra = a + ((size_t)n * BATCH + b) * 2;
    #pragma unroll
    for (int c = 0; c < 2; ++c){ float v = ra[c]; sum[SD + c] += v; sq[SD + c] += v * v; }
  }
  __shared__ float red[256];
  for (int c = 0; c < 20; ++c){
    red[t] = sum[c]; __syncthreads();
    for (int off = 128; off > 0; off >>= 1){ if (t < off) red[t] += red[t + off]; __syncthreads(); }
    if (t == 0) atomicAdd(&accum[(n * 20 + c) * 2 + 0], red[0]);
    __syncthreads();
    red[t] = sq[c]; __syncthreads();
    for (int off = 128; off > 0; off >>= 1){ if (t < off) red[t] += red[t + off]; __syncthreads(); }
    if (t == 0) atomicAdd(&accum[(n * 20 + c) * 2 + 1], red[0]);
    __syncthreads();
  }
}

__global__ void stats_final_kernel(const float* __restrict__ accum,
                                   float* __restrict__ stats){
  int i = threadIdx.x;
  if (i < 60){
    float S = accum[i * 2 + 0], SQ = accum[i * 2 + 1];
    float mean = S / (float)BATCH;
    float var = SQ / (float)BATCH - mean * mean;
    stats[i * 2 + 0] = mean;
    stats[i * 2 + 1] = 1.0f / sqrtf(var + EPSV);
  }
}

// ---------------- prep: F_m = sel @ key^T (f32) ----------------
__global__ void fuse_mats_kernel(const float* __restrict__ asel, const float* __restrict__ akey,
                                 const float* __restrict__ csel, const float* __restrict__ ckey,
                                 float* __restrict__ F){
  const int h1 = blockIdx.x;
  const int m  = blockIdx.y;
  const int h2 = threadIdx.x;
  const float* A; const float* Bm;
  if (m == 0){ A = asel;            Bm = akey; }
  else if (m == 1){ A = asel + HD*HD; Bm = akey + HD*HD; }
  else { A = csel; Bm = ckey; }
  const float* arow = A + h1 * HD;
  const float* brow = Bm + h2 * HD;
  float acc = 0.f;
  #pragma unroll 4
  for (int d = 0; d < HD; ++d) acc = fmaf(arow[d], brow[d], acc);
  F[m * HD * HD + h1 * HD + h2] = acc;
}

// ---------------- prep: split-bf16 transpose  dst[c][k] = src[k][c] ----------------
__global__ void splitT_kernel(const float* __restrict__ src, unsigned short* __restrict__ dh,
                              unsigned short* __restrict__ dl, int K, int Csrc, int Cdst){
  int idx = blockIdx.x * 256 + threadIdx.x;
  if (idx >= K * Cdst) return;
  int k = idx / Cdst, c = idx - k * Cdst;
  float v = (c < Csrc) ? src[(size_t)k * Csrc + c] : 0.f;
  unsigned short hi = f2bf(v);
  float lo = v - bf2f(hi);
  dh[(size_t)c * K + k] = hi;
  dl[(size_t)c * K + k] = f2bf(lo);
}

// ---------------- prep: packed small-encoder weights [896 cols][32 k] per agent ----------------
__global__ void smallpack_kernel(const float* __restrict__ en_W, const float* __restrict__ oa_W,
                                 const float* __restrict__ goal_W, const float* __restrict__ senc_W,
                                 unsigned short* __restrict__ wsu){
  int idx = blockIdx.x * 256 + threadIdx.x;
  if (idx >= 3 * 896 * 32) return;
  int k = idx & 31; int c = (idx >> 5) % 896; int n = idx / (896 * 32);
  int tt = c >> 7, cc = c & 127;
  float v = 0.f;
  if (tt == 0){
    if (k < 4) v = en_W[(size_t)(n*6 + k)*128 + cc];
    else if (k == 18 || k == 19) v = en_W[(size_t)(n*6 + 4 + (k-18))*128 + cc];
  } else if (tt <= 2){
    int j = tt - 1; int kk = k - (4 + 4*j);
    if (kk >= 0 && kk < 4) v = oa_W[(size_t)(n*4 + kk)*128 + cc];
  } else if (tt <= 5){
    int j = tt - 3; int kk = k - (12 + 2*j);
    if (kk >= 0 && kk < 2) v = goal_W[(size_t)(n*2 + kk)*128 + cc];
  } else {
    if (k < 18) v = senc_W[(size_t)(n*18 + k)*128 + cc];
  }
  unsigned short hi = f2bf(v); float lo = v - bf2f(hi);
  unsigned short* dh = wsu + OFF_SW(n);
  dh[c * 32 + k] = hi;
  dh[28672 + c * 32 + k] = f2bf(lo);
}

// ---------------- MFMA helpers ----------------
__device__ __forceinline__ void ldA(const unsigned char* sm, int base, int mi, int ks, int lane,
                                    short8& h, short8& l){
  int row = mi * 16 + (lane & 15);
  int bc  = ks * 64 + ((lane >> 4) << 4);
  int off = base + row * 256 + (bc ^ ((row & 7) << 4));
  h = *(const short8*)(sm + off);
  l = *(const short8*)(sm + off + 8192);
}
__device__ __forceinline__ short8 ldAh(const unsigned char* sm, int base, int mi, int ks, int lane){
  int row = mi * 16 + (lane & 15);
  int bc  = ks * 64 + ((lane >> 4) << 4);
  return *(const short8*)(sm + base + row * 256 + (bc ^ ((row & 7) << 4)));
}
__device__ __forceinline__ void ldA32(const unsigned char* sm, int base, int mi, int lane,
                                      short8& h, short8& l){
  int row = mi * 16 + (lane & 15);
  int bc  = (lane >> 4) << 4;
  int off = base + row * 64 + (bc ^ ((row & 3) << 4));
  h = *(const short8*)(sm + off);
  l = *(const short8*)(sm + off + 2048);
}

#define MM3(acc, ah, al, bh, bl) \
  acc = __builtin_amdgcn_mfma_f32_16x16x32_bf16(ah, bh, acc, 0, 0, 0); \
  acc = __builtin_amdgcn_mfma_f32_16x16x32_bf16(ah, bl, acc, 0, 0, 0); \
  acc = __builtin_amdgcn_mfma_f32_16x16x32_bf16(al, bh, acc, 0, 0, 0);
#define MM2(acc, ah, bh, bl) \
  acc = __builtin_amdgcn_mfma_f32_16x16x32_bf16(ah, bh, acc, 0, 0, 0); \
  acc = __builtin_amdgcn_mfma_f32_16x16x32_bf16(ah, bl, acc, 0, 0, 0);

// single-col variants (fallback kernel)
__device__ __forceinline__ void gemmA(f32x4& c0, f32x4& c1, const unsigned char* sm, int abase,
                                      const unsigned short* wh, const unsigned short* wl,
                                      int K, int bcol, int kBaseB, int lane){
  const size_t bb = (size_t)bcol * K + kBaseB + ((lane >> 4) << 3);
  #pragma unroll
  for (int ks = 0; ks < 4; ++ks){
    short8 ah0, al0, ah1, al1;
    ldA(sm, abase, 0, ks, lane, ah0, al0);
    ldA(sm, abase, 1, ks, lane, ah1, al1);
    const short8 bh = *(const short8*)(wh + bb + ks * 32);
    const short8 bl = *(const short8*)(wl + bb + ks * 32);
    MM3(c0, ah0, al0, bh, bl);
    MM3(c1, ah1, al1, bh, bl);
  }
}
__device__ __forceinline__ void gemmS(f32x4& c0, f32x4& c1, const unsigned char* sm, int abase,
                                      const unsigned short* wh, const unsigned short* wl,
                                      int bcol, int lane){
  const size_t bb = (size_t)bcol * 32 + ((lane >> 4) << 3);
  short8 ah0, al0, ah1, al1;
  ldA32(sm, abase, 0, lane, ah0, al0);
  ldA32(sm, abase, 1, lane, ah1, al1);
  const short8 bh = *(const short8*)(wh + bb);
  const short8 bl = *(const short8*)(wl + bb);
  MM3(c0, ah0, al0, bh, bl);
  MM3(c1, ah1, al1, bh, bl);
}

// 2-col-tile variants (path A)
__device__ __forceinline__ void gemmA2(f32x4& c00, f32x4& c01, f32x4& c10, f32x4& c11,
                                       const unsigned char* sm, int abase,
                                       const unsigned short* wh, const unsigned short* wl,
                                       int K, int col0, int kBase, int lane){
  const size_t bb0 = (size_t)col0 * K + kBase + ((lane >> 4) << 3);
  const size_t bb1 = bb0 + (size_t)16 * K;
  #pragma unroll
  for (int ks = 0; ks < 4; ++ks){
    short8 ah0, al0, ah1, al1;
    ldA(sm, abase, 0, ks, lane, ah0, al0);
    ldA(sm, abase, 1, ks, lane, ah1, al1);
    const short8 bh0 = *(const short8*)(wh + bb0 + ks * 32);
    const short8 bl0 = *(const short8*)(wl + bb0 + ks * 32);
    const short8 bh1 = *(const short8*)(wh + bb1 + ks * 32);
    const short8 bl1 = *(const short8*)(wl + bb1 + ks * 32);
    MM3(c00, ah0, al0, bh0, bl0); MM3(c01, ah0, al0, bh1, bl1);
    MM3(c10, ah1, al1, bh0, bl0); MM3(c11, ah1, al1, bh1, bl1);
  }
}
__device__ __forceinline__ void gemmA2h(f32x4& c00, f32x4& c01, f32x4& c10, f32x4& c11,
                                        const unsigned char* sm, int abase,
                                        const unsigned short* wh, const unsigned short* wl,
                                        int K, int col0, int kBase, int lane){
  const size_t bb0 = (size_t)col0 * K + kBase + ((lane >> 4) << 3);
  const size_t bb1 = bb0 + (size_t)16 * K;
  #pragma unroll
  for (int ks = 0; ks < 4; ++ks){
    short8 ah0 = ldAh(sm, abase, 0, ks, lane);
    short8 ah1 = ldAh(sm, abase, 1, ks, lane);
    const short8 bh0 = *(const short8*)(wh + bb0 + ks * 32);
    const short8 bl0 = *(const short8*)(wl + bb0 + ks * 32);
    const short8 bh1 = *(const short8*)(wh + bb1 + ks * 32);
    const short8 bl1 = *(const short8*)(wl + bb1 + ks * 32);
    MM2(c00, ah0, bh0, bl0); MM2(c01, ah0, bh1, bl1);
    MM2(c10, ah1, bh0, bl0); MM2(c11, ah1, bh1, bl1);
  }
}
__device__ __forceinline__ void gemmS2(f32x4& c00, f32x4& c01, f32x4& c10, f32x4& c11,
                                       const unsigned char* sm, int abase,
                                       const unsigned short* wh, const unsigned short* wl,
                                       int col0, int lane){
  const size_t bb0 = (size_t)col0 * 32 + ((lane >> 4) << 3);
  const size_t bb1 = bb0 + 16 * 32;
  short8 ah0, al0, ah1, al1;
  ldA32(sm, abase, 0, lane, ah0, al0);
  ldA32(sm, abase, 1, lane, ah1, al1);
  const short8 bh0 = *(const short8*)(wh + bb0);
  const short8 bl0 = *(const short8*)(wl + bb0);
  const short8 bh1 = *(const short8*)(wh + bb1);
  const short8 bl1 = *(const short8*)(wl + bb1);
  MM3(c00, ah0, al0, bh0, bl0); MM3(c01, ah0, al0, bh1, bl1);
  MM3(c10, ah1, al1, bh0, bl0); MM3(c11, ah1, al1, bh1, bl1);
}

__device__ __forceinline__ void stTile(unsigned char* sm, int base, int mi, int lane, int col, f32x4 v){
  #pragma unroll
  for (int r = 0; r < 4; ++r){
    int row = mi * 16 + ((lane >> 4) << 2) + r;
    int bc  = col * 2;
    int off = base + row * 256 + (bc ^ ((row & 7) << 4));
    unsigned short hi = f2bf(v[r]);
    *(unsigned short*)(sm + off) = hi;
    *(unsigned short*)(sm + off + 8192) = f2bf(v[r] - bf2f(hi));
  }
}
__device__ __forceinline__ void stSK(unsigned char* sm, int base, int mi, int lane, int col, f32x4 v){
  #pragma unroll
  for (int r = 0; r < 4; ++r){
    int row = mi * 16 + ((lane >> 4) << 2) + r;
    int off = base + row * 256 + ((col * 2) ^ ((row & 7) << 5));
    *(unsigned short*)(sm + off) = f2bf(v[r]);
  }
}
__device__ __forceinline__ float dot8(short8 x, short8 y){
  float acc = 0.f;
  #pragma unroll
  for (int e = 0; e < 8; ++e)
    acc = fmaf(bf2f((unsigned short)x[e]), bf2f((unsigned short)y[e]), acc);
  return acc;
}

// fallback helper
__device__ __forceinline__ void dotTile(unsigned char* sm, int tbase, const f32x4 d0, const f32x4 d1,
                                        int lane, int wave, int col, int part_o){
  float* part = (float*)(sm + part_o);
  #pragma unroll
  for (int mi = 0; mi < 2; ++mi){
    #pragma unroll
    for (int r = 0; r < 4; ++r){
      int row = mi * 16 + ((lane >> 4) << 2) + r;
      int bc  = col * 2;
      int off = tbase + row * 256 + (bc ^ ((row & 7) << 4));
      float v = bf2f(*(const unsigned short*)(sm + off)) +
                bf2f(*(const unsigned short*)(sm + off + 8192));
      float p = (mi ? d1[r] : d0[r]) * v;
      p += __shfl_xor(p, 1, 16);
      p += __shfl_xor(p, 2, 16);
      p += __shfl_xor(p, 4, 16);
      p += __shfl_xor(p, 8, 16);
      if ((lane & 15) == 0) part[wave * 32 + row] = p;
    }
  }
}

// ======================================================================
// PATH A: actor kernel — grid (BATCH/TB, NAG), 256 threads
// ======================================================================
__global__ __launch_bounds__(256, 2) void actor_kernel(
    const float* __restrict__ s, const float* __restrict__ a,
    const float* __restrict__ en_b, const float* __restrict__ oa_b,
    const float* __restrict__ goal_b, const float* __restrict__ aval_b,
    const float* __restrict__ merge_b, const unsigned char* __restrict__ wsc,
    unsigned short* __restrict__ sa_g)
{
  __shared__ __align__(16) unsigned char SM[69888];
  const int AXN = 0, AEN = 4096, ASL = 20480, AOV = 36864, ASK = 53248, AEP = 69632, AES = 69760;
  const int t = threadIdx.x, lane = t & 63, wave = t >> 6;
  const int col0 = wave * 32 + (lane & 15);
  const int n = blockIdx.y;
  const int gb0 = blockIdx.x * TB;
  const float* stats = (const float*)(wsc + WSB_STATS);
  const unsigned short* wsu = (const unsigned short*)(wsc + WSB_W);
  const unsigned short* swh = wsu + OFF_SW(n);
  const unsigned short* swl = swh + 28672;
  const f32x4 Z = binit(0.f);

  if (t < TB){
    int row = t;
    size_t gb = (size_t)gb0 + row;
    const float* st = stats + n * 40;
    const float* srow = s + ((size_t)n * BATCH + gb) * SD;
    const float* arow = a + ((size_t)n * BATCH + gb) * 2;
    #pragma unroll
    for (int c = 0; c < 32; ++c){
      float v = 0.f;
      if (c < 18) v = (srow[c] - st[c*2]) * st[c*2+1];
      else if (c < 20) v = (arow[c-18] - st[c*2]) * st[c*2+1];
      unsigned short hi = f2bf(v);
      int off = AXN + row * 64 + ((c * 2) ^ ((row & 3) << 4));
      *(unsigned short*)(SM + off) = hi;
      *(unsigned short*)(SM + off + 2048) = f2bf(v - bf2f(hi));
    }
  }
  __syncthreads();
  // R0: en_enc
  {
    f32x4 c00 = binit(en_b[n*HD + col0]), c01 = binit(en_b[n*HD + col0 + 16]);
    f32x4 c10 = c00, c11 = c01;
    gemmS2(c00, c01, c10, c11, SM, AXN, swh, swl, col0, lane);
    stTile(SM, AEN, 0, lane, col0, lrelu4(c00)); stTile(SM, AEN, 0, lane, col0+16, lrelu4(c01));
    stTile(SM, AEN, 1, lane, col0, lrelu4(c10)); stTile(SM, AEN, 1, lane, col0+16, lrelu4(c11));
  }
  __syncthreads();
  // R1: selk0, selk1 -> SK (bf16, 32B-swz)
  {
    f32x4 k00=Z,k01=Z,k10=Z,k11=Z;
    gemmA2(k00,k01,k10,k11, SM, AEN, wsu+OFF_FT0, wsu+OFF_FT0+16384, 128, col0, 0, lane);
    stSK(SM, ASK, 0, lane, col0, k00); stSK(SM, ASK, 0, lane, col0+16, k01);
    stSK(SM, ASK, 1, lane, col0, k10); stSK(SM, ASK, 1, lane, col0+16, k11);
    f32x4 m00=Z,m01=Z,m10=Z,m11=Z;
    gemmA2(m00,m01,m10,m11, SM, AEN, wsu+OFF_FT1, wsu+OFF_FT1+16384, 128, col0, 0, lane);
    stSK(SM, ASK+8192, 0, lane, col0, m00); stSK(SM, ASK+8192, 0, lane, col0+16, m01);
    stSK(SM, ASK+8192, 1, lane, col0, m10); stSK(SM, ASK+8192, 1, lane, col0+16, m11);
  }
  __syncthreads();

  f32x4 ov00=Z,ov01=Z,ov10=Z,ov11=Z;   // oa attention output accum
  f32x4 og00=Z,og01=Z,og10=Z,og11=Z;   // goal attention output accum
  f32x4 v00=Z,v01=Z,v10=Z,v11=Z;       // current slice vals
  #pragma unroll 1
  for (int sl = 0; sl < 6; ++sl){
    // ---- region A: accumulate previous slice; stage next slice encoding ----
    if (sl >= 1){
      const float* eP = (const float*)(SM + AEP);
      const int pm = (sl - 1) < 2 ? 0 : 1;
      #pragma unroll
      for (int r = 0; r < 4; ++r){
        int r0 = ((lane >> 4) << 2) + r;
        float e0 = eP[r0], e1 = eP[r0 + 16];
        if (pm == 0){
          ov00[r] += e0 * lrelu(v00[r]); ov01[r] += e0 * lrelu(v01[r]);
          ov10[r] += e1 * lrelu(v10[r]); ov11[r] += e1 * lrelu(v11[r]);
        } else {
          og00[r] += e0 * lrelu(v00[r]); og01[r] += e0 * lrelu(v01[r]);
          og10[r] += e1 * lrelu(v10[r]); og11[r] += e1 * lrelu(v11[r]);
        }
      }
      if (sl == 2){
        const float* es = (const float*)(SM + AES);
        f32x4 o00, o01, o10, o11;
        #pragma unroll
        for (int r = 0; r < 4; ++r){
          int r0 = ((lane >> 4) << 2) + r;
          o00[r] = ov00[r] / es[r0];      o01[r] = ov01[r] / es[r0];
          o10[r] = ov10[r] / es[r0+16];   o11[r] = ov11[r] / es[r0+16];
        }
        stTile(SM, AOV, 0, lane, col0, o00); stTile(SM, AOV, 0, lane, col0+16, o01);
        stTile(SM, AOV, 1, lane, col0, o10); stTile(SM, AOV, 1, lane, col0+16, o11);
      }
      if (sl == 5){
        const float* es = (const float*)(SM + AES);
        f32x4 o00, o01, o10, o11;
        #pragma unroll
        for (int r = 0; r < 4; ++r){
          int r0 = ((lane >> 4) << 2) + r;
          o00[r] = og00[r] / es[r0];      o01[r] = og01[r] / es[r0];
          o10[r] = og10[r] / es[r0+16];   o11[r] = og11[r] / es[r0+16];
        }
        stTile(SM, ASL, 0, lane, col0, o00); stTile(SM, ASL, 0, lane, col0+16, o01);
        stTile(SM, ASL, 1, lane, col0, o10); stTile(SM, ASL, 1, lane, col0+16, o11);
      }
    }
    if (sl < 5){
      const int wcol = (sl < 2) ? 128 * (1 + sl) : 128 * (3 + (sl - 2));
      const float* bptr = (sl < 2) ? (oa_b + n * HD) : (goal_b + n * HD);
      f32x4 c00 = binit(bptr[col0]), c01 = binit(bptr[col0 + 16]);
      f32x4 c10 = c00, c11 = c01;
      gemmS2(c00, c01, c10, c11, SM, AXN, swh, swl, wcol + col0, lane);
      stTile(SM, ASL, 0, lane, col0, lrelu4(c00)); stTile(SM, ASL, 0, lane, col0+16, lrelu4(c01));
      stTile(SM, ASL, 1, lane, col0, lrelu4(c10)); stTile(SM, ASL, 1, lane, col0+16, lrelu4(c11));
    }
    __syncthreads();
    if (sl < 5){
      // ---- region B: vals GEMM (regs) + per-row logit dot + exp ----
      const unsigned short* vwh = (sl < 2) ? (wsu + OFF_AV0) : (wsu + OFF_AV1);
      const float* avb = aval_b + ((sl < 2) ? 0 : HD);
      v00 = binit(avb[col0]); v01 = binit(avb[col0 + 16]); v10 = v00; v11 = v01;
      gemmA2(v00, v01, v10, v11, SM, ASL, vwh, vwh + 16384, 128, col0, 0, lane);
      {
        int row = wave * 8 + (lane >> 3);
        int cb = (lane & 7) * 32;
        int sw5 = (row & 7) << 5, sw4 = (row & 7) << 4;
        const unsigned char* skb = SM + ASK + ((sl < 2) ? 0 : 8192) + row * 256;
        short8 k0 = *(const short8*)(skb + (cb ^ sw5));
        short8 k1 = *(const short8*)(skb + (cb ^ sw5) + 16);
        const unsigned char* slb = SM + ASL + row * 256;
        short8 e0 = *(const short8*)(slb + (cb ^ sw4));
        short8 e1 = *(const short8*)(slb + ((cb + 16) ^ sw4));
        float p = dot8(k0, e0) + dot8(k1, e1);
        p += __shfl_xor(p, 1, 64);
        p += __shfl_xor(p, 2, 64);
        p += __shfl_xor(p, 4, 64);
        if ((lane & 7) == 0){
          float e = __expf(p * SCALE);
          ((float*)(SM + AEP))[row] = e;
          float* es = (float*)(SM + AES);
          es[row] = (sl == 0 || sl == 2) ? e : es[row] + e;
        }
      }
      __syncthreads();
    }
  }
  // merge: sa = lrelu([en|ov0|ov1] @ merge_W + b) -> global bf16
  {
    const unsigned short* mh = wsu + OFF_MG(n);
    const unsigned short* ml = mh + 49152;
    f32x4 c00 = binit(merge_b[n*HD + col0]), c01 = binit(merge_b[n*HD + col0 + 16]);
    f32x4 c10 = c00, c11 = c01;
    gemmA2(c00, c01, c10, c11, SM, AEN, mh, ml, 384, col0, 0,   lane);
    gemmA2(c00, c01, c10, c11, SM, AOV, mh, ml, 384, col0, 128, lane);
    gemmA2(c00, c01, c10, c11, SM, ASL, mh, ml, 384, col0, 256, lane);
    #pragma unroll
    for (int r = 0; r < 4; ++r){
      int r0 = ((lane >> 4) << 2) + r;
      size_t base0 = ((size_t)n * BATCH + gb0 + r0) * HD;
      sa_g[base0 + col0]        = f2bf(lrelu(c00[r]));
      sa_g[base0 + col0 + 16]   = f2bf(lrelu(c01[r]));
      size_t base1 = ((size_t)n * BATCH + gb0 + r0 + 16) * HD;
      sa_g[base1 + col0]        = f2bf(lrelu(c10[r]));
      sa_g[base1 + col0 + 16]   = f2bf(lrelu(c11[r]));
    }
  }
}

// ======================================================================
// PATH A: critic kernel — grid (BATCH/TB, NAG=i), 256 threads
// ======================================================================
__global__ __launch_bounds__(256, 2) void critic_kernel(
    const float* __restrict__ s, const float* __restrict__ a,
    const float* __restrict__ senc_b, const float* __restrict__ cval_b,
    const float* __restrict__ cb1, const float* __restrict__ cW2,
    const float* __restrict__ cb2, const unsigned char* __restrict__ wsc,
    const unsigned short* __restrict__ sa_g, float* __restrict__ out)
{
  __shared__ __align__(16) unsigned char SM[61952];
  const int CXN = 0, CEN = 4096, CSMo = 20480, CSA = 28672, COV = 45056, CH = 28672, CLW = 61440;
  const int t = threadIdx.x, lane = t & 63, wave = t >> 6;
  const int col0 = wave * 32 + (lane & 15);
  const int i = blockIdx.y;
  const int gb0 = blockIdx.x * TB;
  const int j0 = (i == 0) ? 1 : 0;
  const int j1 = (i == 2) ? 1 : 2;
  const float* stats = (const float*)(wsc + WSB_STATS);
  const unsigned short* wsu = (const unsigned short*)(wsc + WSB_W);
  const unsigned short* swh = wsu + OFF_SW(i);
  const unsigned short* swl = swh + 28672;
  const f32x4 Z = binit(0.f);

  // R0: stage XN_i + copy sa_j0/j1 -> LDS (hi-only, 16B-swz)
  if (t < TB){
    int row = t;
    size_t gb = (size_t)gb0 + row;
    const float* st = stats + i * 40;
    const float* srow = s + ((size_t)i * BATCH + gb) * SD;
    const float* arow = a + ((size_t)i * BATCH + gb) * 2;
    #pragma unroll
    for (int c = 0; c < 32; ++c){
      float v = 0.f;
      if (c < 18) v = (srow[c] - st[c*2]) * st[c*2+1];
      else if (c < 20) v = (arow[c-18] - st[c*2]) * st[c*2+1];
      unsigned short hi = f2bf(v);
      int off = CXN + row * 64 + ((c * 2) ^ ((row & 3) << 4));
      *(unsigned short*)(SM + off) = hi;
      *(unsigned short*)(SM + off + 2048) = f2bf(v - bf2f(hi));
    }
  }
  {
    int r = t >> 3, ch = (t & 7) * 32;
    int sw = (r & 7) << 4;
    const unsigned short* g0 = sa_g + ((size_t)j0 * BATCH + gb0 + r) * HD + ch / 2;
    short8 u0 = *(const short8*)g0; short8 u1 = *(const short8*)(g0 + 8);
    *(short8*)(SM + CSA + r * 256 + (ch ^ sw)) = u0;
    *(short8*)(SM + CSA + r * 256 + ((ch + 16) ^ sw)) = u1;
    const unsigned short* g1 = sa_g + ((size_t)j1 * BATCH + gb0 + r) * HD + ch / 2;
    u0 = *(const short8*)g1; u1 = *(const short8*)(g1 + 8);
    *(short8*)(SM + CSA + 8192 + r * 256 + (ch ^ sw)) = u0;
    *(short8*)(SM + CSA + 8192 + r * 256 + ((ch + 16) ^ sw)) = u1;
  }
  __syncthreads();
  // R1: s_enc
  {
    f32x4 c00 = binit(senc_b[i*HD + col0]), c01 = binit(senc_b[i*HD + col0 + 16]);
    f32x4 c10 = c00, c11 = c01;
    gemmS2(c00, c01, c10, c11, SM, CXN, swh, swl, 768 + col0, lane);
    stTile(SM, CEN, 0, lane, col0, lrelu4(c00)); stTile(SM, CEN, 0, lane, col0+16, lrelu4(c01));
    stTile(SM, CEN, 1, lane, col0, lrelu4(c10)); stTile(SM, CEN, 1, lane, col0+16, lrelu4(c11));
  }
  __syncthreads();
  // R2: selsM = s_enc @ M -> CSM (bf16, 32B-swz)
  {
    f32x4 k00=Z,k01=Z,k10=Z,k11=Z;
    gemmA2(k00,k01,k10,k11, SM, CEN, wsu+OFF_MT, wsu+OFF_MT+16384, 128, col0, 0, lane);
    stSK(SM, CSMo, 0, lane, col0, k00); stSK(SM, CSMo, 0, lane, col0+16, k01);
    stSK(SM, CSMo, 1, lane, col0, k10); stSK(SM, CSMo, 1, lane, col0+16, k11);
  }
  __syncthreads();
  // R3: vals GEMMs (hi-A) + logit dots + 2-way softmax
  f32x4 v000, v001, v010, v011, v100, v101, v110, v111;
  {
    v000 = binit(cval_b[col0]); v001 = binit(cval_b[col0 + 16]); v010 = v000; v011 = v001;
    gemmA2h(v000, v001, v010, v011, SM, CSA,        wsu+OFF_CV, wsu+OFF_CV+16384, 128, col0, 0, lane);
    v100 = binit(cval_b[col0]); v101 = binit(cval_b[col0 + 16]); v110 = v100; v111 = v101;
    gemmA2h(v100, v101, v110, v111, SM, CSA + 8192, wsu+OFF_CV, wsu+OFF_CV+16384, 128, col0, 0, lane);
    int row = wave * 8 + (lane >> 3);
    int cb = (lane & 7) * 32;
    int sw5 = (row & 7) << 5, sw4 = (row & 7) << 4;
    const unsigned char* mb = SM + CSMo + row * 256;
    short8 m0 = *(const short8*)(mb + (cb ^ sw5));
    short8 m1 = *(const short8*)(mb + (cb ^ sw5) + 16);
    const unsigned char* a0b = SM + CSA + row * 256;
    short8 a0 = *(const short8*)(a0b + (cb ^ sw4));
    short8 a1 = *(const short8*)(a0b + ((cb + 16) ^ sw4));
    const unsigned char* b0b = SM + CSA + 8192 + row * 256;
    short8 b0 = *(const short8*)(b0b + (cb ^ sw4));
    short8 b1 = *(const short8*)(b0b + ((cb + 16) ^ sw4));
    float p0 = dot8(m0, a0) + dot8(m1, a1);
    float p1 = dot8(m0, b0) + dot8(m1, b1);
    p0 += __shfl_xor(p0, 1, 64); p0 += __shfl_xor(p0, 2, 64); p0 += __shfl_xor(p0, 4, 64);
    p1 += __shfl_xor(p1, 1, 64); p1 += __shfl_xor(p1, 2, 64); p1 += __shfl_xor(p1, 4, 64);
    if ((lane & 7) == 0){
      float e0 = __expf(p0 * SCALE), e1 = __expf(p1 * SCALE);
      float inv = 1.f / (e0 + e1);
      ((float*)(SM + CLW))[row]      = e0 * inv;
      ((float*)(SM + CLW))[32 + row] = e1 * inv;
    }
  }
  __syncthreads();
  // R4: ov -> COV
  {
    const float* w0 = (const float*)(SM + CLW);
    const float* w1 = w0 + 32;
    f32x4 o00, o01, o10, o11;
    #pragma unroll
    for (int r = 0; r < 4; ++r){
      int r0 = ((lane >> 4) << 2) + r;
      o00[r] = w0[r0]      * lrelu(v000[r]) + w1[r0]      * lrelu(v100[r]);
      o01[r] = w0[r0]      * lrelu(v001[r]) + w1[r0]      * lrelu(v101[r]);
      o10[r] = w0[r0 + 16] * lrelu(v010[r]) + w1[r0 + 16] * lrelu(v110[r]);
      o11[r] = w0[r0 + 16] * lrelu(v011[r]) + w1[r0 + 16] * lrelu(v111[r]);
    }
    stTile(SM, COV, 0, lane, col0, o00); stTile(SM, COV, 0, lane, col0+16, o01);
    stTile(SM, COV, 1, lane, col0, o10); stTile(SM, COV, 1, lane, col0+16, o11);
  }
  __syncthreads();
  // R5: h = lrelu([s_enc|ov] @ cW1 + b) -> CH (overwrites CSA)
  {
    const unsigned short* c1h = wsu + OFF_C1(i);
    const unsigned short* c1l = c1h + 32768;
    f32x4 h00 = binit(cb1[i*HD + col0]), h01 = binit(cb1[i*HD + col0 + 16]);
    f32x4 h10 = h00, h11 = h01;
    gemmA2(h00, h01, h10, h11, SM, CEN, c1h, c1l, 256, col0, 0,   lane);
    gemmA2(h00, h01, h10, h11, SM, COV, c1h, c1l, 256, col0, 128, lane);
    stTile(SM, CH, 0, lane, col0, lrelu4(h00)); stTile(SM, CH, 0, lane, col0+16, lrelu4(h01));
    stTile(SM, CH, 1, lane, col0, lrelu4(h10)); stTile(SM, CH, 1, lane, col0+16, lrelu4(h11));
  }
  __syncthreads();
  // R6: q = h @ cW2 + cb2 (per-row dot)
  {
    int row = wave * 8 + (lane >> 3);
    int cb = (lane & 7) * 32;
    int sw4 = (row & 7) << 4;
    const unsigned char* hb = SM + CH + row * 256;
    short8 h0 = *(const short8*)(hb + (cb ^ sw4));
    short8 h1 = *(const short8*)(hb + ((cb + 16) ^ sw4));
    short8 l0 = *(const short8*)(hb + 8192 + (cb ^ sw4));
    short8 l1 = *(const short8*)(hb + 8192 + ((cb + 16) ^ sw4));
    float q0 = 0.f, q1 = 0.f;
    #pragma unroll
    for (int e = 0; e < 8; ++e){
      int d = (lane & 7) * 16 + e;
      float hv = bf2f((unsigned short)h0[e]) + bf2f((unsigned short)l0[e]);
      q0 = fmaf(hv, cW2[(i * HD + d) * 2 + 0], q0);
      q1 = fmaf(hv, cW2[(i * HD + d) * 2 + 1], q1);
    }
    #pragma unroll
    for (int e = 0; e < 8; ++e){
      int d = (lane & 7) * 16 + 8 + e;
      float hv = bf2f((unsigned short)h1[e]) + bf2f((unsigned short)l1[e]);
      q0 = fmaf(hv, cW2[(i * HD + d) * 2 + 0], q0);
      q1 = fmaf(hv, cW2[(i * HD + d) * 2 + 1], q1);
    }
    q0 += __shfl_xor(q0, 1, 64); q0 += __shfl_xor(q0, 2, 64); q0 += __shfl_xor(q0, 4, 64);
    q1 += __shfl_xor(q1, 1, 64); q1 += __shfl_xor(q1, 2, 64); q1 += __shfl_xor(q1, 4, 64);
    if ((lane & 7) == 0){
      out[((size_t)i * BATCH + gb0 + row) * 2 + 0] = q0 + cb2[i * 2 + 0];
      out[((size_t)i * BATCH + gb0 + row) * 2 + 1] = q1 + cb2[i * 2 + 1];
    }
  }
}

// ======================================================================
// PATH B fallback: round-2 single fused kernel (proven)
// ======================================================================
#define XN_O    0
#define EN_O    12288
#define SLICE_O 28672
#define OV0_O   45056
#define SA_O    61440
#define PART_O  110592
#define EP_O    111616
#define ESUM_O  111744
#define LW_O    111872
#define SM_TOTAL 113024

__global__ __launch_bounds__(512, 2) void fused_kernel(
    const float* __restrict__ s, const float* __restrict__ a,
    const float* __restrict__ en_b, const float* __restrict__ oa_b,
    const float* __restrict__ goal_b, const float* __restrict__ aval_b,
    const float* __restrict__ merge_b, const float* __restrict__ senc_b,
    const float* __restrict__ cval_b, const float* __restrict__ cb1,
    const float* __restrict__ cb2, const unsigned char* __restrict__ wsc,
    float* __restrict__ out)
{
  __shared__ __align__(16) unsigned char SM[SM_TOTAL];
  unsigned char* sm = SM;
  const int t = threadIdx.x;
  const int lane = t & 63;
  const int wave = t >> 6;
  const int col = wave * 16 + (lane & 15);
  const int gb0 = blockIdx.x * TB;
  const float* stats = (const float*)(wsc + WSB_STATS);
  const unsigned short* wsu = (const unsigned short*)(wsc + WSB_W);
  const f32x4 Z = binit(0.f);

  if (t < 96){
    int n = t >> 5, row = t & 31;
    size_t gb = (size_t)gb0 + row;
    const float* st = stats + n * 40;
    const float* srow = s + ((size_t)n * BATCH + gb) * SD;
    const float* arow = a + ((size_t)n * BATCH + gb) * 2;
    #pragma unroll
    for (int c = 0; c < 32; ++c){
      float v = 0.f;
      if (c < 18) v = (srow[c] - st[c*2]) * st[c*2+1];
      else if (c < 20) v = (arow[c-18] - st[c*2]) * st[c*2+1];
      unsigned short hi = f2bf(v);
      int off = XN_O + n * 4096 + row * 64 + ((c * 2) ^ ((row & 3) << 4));
      *(unsigned short*)(sm + off) = hi;
      *(unsigned short*)(sm + off + 2048) = f2bf(v - bf2f(hi));
    }
  }
  __syncthreads();

  #pragma unroll 1
  for (int n = 0; n < NAG; ++n){
    const unsigned short* swh = wsu + OFF_SW(n);
    const unsigned short* swl = swh + 28672;
    {
      f32x4 v0 = binit(en_b[n*HD + col]), v1 = v0;
      gemmS(v0, v1, sm, XN_O + n*4096, swh, swl, 0 + col, lane);
      stTile(sm, EN_O, 0, lane, col, lrelu4(v0));
      stTile(sm, EN_O, 1, lane, col, lrelu4(v1));
    }
    __syncthreads();
    f32x4 sk0a = Z, sk0b = Z, sk1a = Z, sk1b = Z;
    gemmA(sk0a, sk0b, sm, EN_O, wsu + OFF_FT0, wsu + OFF_FT0 + 16384, 128, col, 0, lane);
    gemmA(sk1a, sk1b, sm, EN_O, wsu + OFF_FT1, wsu + OFF_FT1 + 16384, 128, col, 0, lane);

    f32x4 ov0a = Z, ov0b = Z;
    #pragma unroll 1
    for (int j = 0; j < 2; ++j){
      __syncthreads();
      f32x4 v0 = binit(oa_b[n*HD + col]), v1 = v0;
      gemmS(v0, v1, sm, XN_O + n*4096, swh, swl, 128*(1+j) + col, lane);
      stTile(sm, SLICE_O, 0, lane, col, lrelu4(v0));
      stTile(sm, SLICE_O, 1, lane, col, lrelu4(v1));
      __syncthreads();
      dotTile(sm, SLICE_O, sk0a, sk0b, lane, wave, col, PART_O);
      __syncthreads();
      if (t < TB){
        const float* part = (const float*)(sm + PART_O);
        float tot = 0.f;
        #pragma unroll
        for (int w2 = 0; w2 < 8; ++w2) tot += part[w2*32 + t];
        float e = __expf(tot * SCALE);
        ((float*)(sm + EP_O))[t] = e;
        float* es = (float*)(sm + ESUM_O);
        es[t] = (j == 0) ? e : es[t] + e;
      }
      __syncthreads();
      f32x4 w0 = binit(aval_b[col]), w1 = w0;
      gemmA(w0, w1, sm, SLICE_O, wsu + OFF_AV0, wsu + OFF_AV0 + 16384, 128, col, 0, lane);
      const float* eP = (const float*)(sm + EP_O);
      #pragma unroll
      for (int r = 0; r < 4; ++r){
        int row0 = ((lane >> 4) << 2) + r;
        ov0a[r] += eP[row0]      * lrelu(w0[r]);
        ov0b[r] += eP[row0 + 16] * lrelu(w1[r]);
      }
    }
    {
      const float* es = (const float*)(sm + ESUM_O);
      f32x4 o0, o1;
      #pragma unroll
      for (int r = 0; r < 4; ++r){
        int row0 = ((lane >> 4) << 2) + r;
        o0[r] = ov0a[r] / es[row0];
        o1[r] = ov0b[r] / es[row0 + 16];
      }
      stTile(sm, OV0_O, 0, lane, col, o0);
      stTile(sm, OV0_O, 1, lane, col, o1);
    }

    f32x4 ov1a = Z, ov1b = Z;
    #pragma unroll 1
    for (int j = 0; j < 3; ++j){
      __syncthreads();
      f32x4 v0 = binit(goal_b[n*HD + col]), v1 = v0;
      gemmS(v0, v1, sm, XN_O + n*4096, swh, swl, 128*(3+j) + col, lane);
      stTile(sm, SLICE_O, 0, lane, col, lrelu4(v0));
      stTile(sm, SLICE_O, 1, lane, col, lrelu4(v1));
      __syncthreads();
      dotTile(sm, SLICE_O, sk1a, sk1b, lane, wave, col, PART_O);
      __syncthreads();
      if (t < TB){
        const float* part = (const float*)(sm + PART_O);
        float tot = 0.f;
        #pragma unroll
        for (int w2 = 0; w2 < 8; ++w2) tot += part[w2*32 + t];
        float e = __expf(tot * SCALE);
        ((float*)(sm + EP_O))[t] = e;
        float* es = (float*)(sm + ESUM_O);
        es[t] = (j == 0) ? e : es[t] + e;
      }
      __syncthreads();
      f32x4 w0 = binit(aval_b[HD + col]), w1 = w0;
      gemmA(w0, w1, sm, SLICE_O, wsu + OFF_AV1, wsu + OFF_AV1 + 16384, 128, col, 0, lane);
      const float* eP = (const float*)(sm + EP_O);
      #pragma unroll
      for (int r = 0; r < 4; ++r){
        int row0 = ((lane >> 4) << 2) + r;
        ov1a[r] += eP[row0]      * lrelu(w0[r]);
        ov1b[r] += eP[row0 + 16] * lrelu(w1[r]);
      }
    }
    __syncthreads();
    {
      const float* es = (const float*)(sm + ESUM_O);
      f32x4 o0, o1;
      #pragma unroll
      for (int r = 0; r < 4; ++r){
        int row0 = ((lane >> 4) << 2) + r;
        o0[r] = ov1a[r] / es[row0];
        o1[r] = ov1b[r] / es[row0 + 16];
      }
      stTile(sm, SLICE_O, 0, lane, col, o0);
      stTile(sm, SLICE_O, 1, lane, col, o1);
    }
    __syncthreads();
    {
      const unsigned short* mh = wsu + OFF_MG(n);
      const unsigned short* ml = mh + 49152;
      f32x4 m0 = binit(merge_b[n*HD + col]), m1 = m0;
      gemmA(m0, m1, sm, EN_O,    mh, ml, 384, col, 0,   lane);
      gemmA(m0, m1, sm, OV0_O,   mh, ml, 384, col, 128, lane);
      gemmA(m0, m1, sm, SLICE_O, mh, ml, 384, col, 256, lane);
      stTile(sm, SA_O + n*16384, 0, lane, col, lrelu4(m0));
      stTile(sm, SA_O + n*16384, 1, lane, col, lrelu4(m1));
    }
    __syncthreads();
  }

  #pragma unroll 1
  for (int i = 0; i < NAG; ++i){
    const unsigned short* swh = wsu + OFF_SW(i);
    const unsigned short* swl = swh + 28672;
    f32x4 e0 = binit(senc_b[i*HD + col]), e1 = e0;
    gemmS(e0, e1, sm, XN_O + i*4096, swh, swl, 768 + col, lane);
    stTile(sm, EN_O, 0, lane, col, lrelu4(e0));
    stTile(sm, EN_O, 1, lane, col, lrelu4(e1));
    __syncthreads();
    f32x4 sm0 = Z, sm1 = Z;
    gemmA(sm0, sm1, sm, EN_O, wsu + OFF_MT, wsu + OFF_MT + 16384, 128, col, 0, lane);
    #pragma unroll 1
    for (int j = 0; j < NAG; ++j){
      if (j == i) continue;
      dotTile(sm, SA_O + j*16384, sm0, sm1, lane, wave, col, PART_O);
      __syncthreads();
      if (t < TB){
        const float* part = (const float*)(sm + PART_O);
        float tot = 0.f;
        #pragma unroll
        for (int w2 = 0; w2 < 8; ++w2) tot += part[w2*32 + t];
        ((float*)(sm + LW_O))[(i*3 + j)*32 + t] = tot;
      }
      __syncthreads();
    }
  }
  if (t < TB){
    float* LW = (float*)(sm + LW_O);
    #pragma unroll
    for (int i = 0; i < NAG; ++i){
      int j0 = (i == 0) ? 1 : 0;
      int j1 = (i == 2) ? 1 : 2;
      float l0 = LW[(i*3 + j0)*32 + t] * SCALE;
      float l1 = LW[(i*3 + j1)*32 + t] * SCALE;
      float q0 = __expf(l0), q1 = __expf(l1);
      float inv = 1.f / (q0 + q1);
      LW[(i*3 + j0)*32 + t] = q0 * inv;
      LW[(i*3 + j1)*32 + t] = q1 * inv;
    }
  }
  __syncthreads();
  f32x4 oc00 = Z, oc01 = Z, oc10 = Z, oc11 = Z, oc20 = Z, oc21 = Z;
  {
    const float* LW = (const float*)(sm + LW_O);
    #pragma unroll 1
    for (int j = 0; j < NAG; ++j){
      f32x4 v0 = binit(cval_b[col]), v1 = v0;
      gemmA(v0, v1, sm, SA_O + j*16384, wsu + OFF_CV, wsu + OFF_CV + 16384, 128, col, 0, lane);
      v0 = lrelu4(v0); v1 = lrelu4(v1);
      #pragma unroll
      for (int i = 0; i < NAG; ++i){
        if (i == j) continue;
        f32x4& o0 = (i == 0) ? oc00 : ((i == 1) ? oc10 : oc20);
        f32x4& o1 = (i == 0) ? oc01 : ((i == 1) ? oc11 : oc21);
        #pragma unroll
        for (int r = 0; r < 4; ++r){
          int row0 = ((lane >> 4) << 2) + r;
          o0[r] += LW[(i*3 + j)*32 + row0]      * v0[r];
          o1[r] += LW[(i*3 + j)*32 + row0 + 16] * v1[r];
        }
      }
    }
  }
  __syncthreads();
  #pragma unroll 1
  for (int i = 0; i < NAG; ++i){
    const unsigned short* swh = wsu + OFF_SW(i);
    const unsigned short* swl = swh + 28672;
    f32x4 se0 = binit(senc_b[i*HD + col]), se1 = se0;
    gemmS(se0, se1, sm, XN_O + i*4096, swh, swl, 768 + col, lane);
    stTile(sm, EN_O, 0, lane, col, lrelu4(se0));
    stTile(sm, EN_O, 1, lane, col, lrelu4(se1));
    {
      f32x4 o0 = (i == 0) ? oc00 : ((i == 1) ? oc10 : oc20);
      f32x4 o1 = (i == 0) ? oc01 : ((i == 1) ? oc11 : oc21);
      stTile(sm, OV0_O, 0, lane, col, o0);
      stTile(sm, OV0_O, 1, lane, col, o1);
    }
    __syncthreads();
    const unsigned short* c1h = wsu + OFF_C1(i);
    const unsigned short* c1l = c1h + 32768;
    f32x4 h0 = binit(cb1[i*HD + col]), h1 = h0;
    gemmA(h0, h1, sm, EN_O,  c1h, c1l, 256, col, 0,   lane);
    gemmA(h0, h1, sm, OV0_O, c1h, c1l, 256, col, 128, lane);
    stTile(sm, SLICE_O, 0, lane, col, lrelu4(h0));
    stTile(sm, SLICE_O, 1, lane, col, lrelu4(h1));
    __syncthreads();
    f32x4 q0 = Z, q1 = Z;
    gemmA(q0, q1, sm, SLICE_O, wsu + OFF_C2(i), wsu + OFF_C2(i) + 2048, 128, (lane & 15), 0, lane);
    if (wave == 0 && (lane & 15) < 2){
      int c2 = lane & 15;
      float bb = cb2[i*2 + c2];
      #pragma unroll
      for (int r = 0; r < 4; ++r){
        int row = ((lane >> 4) << 2) + r;
        out[((size_t)i*BATCH + gb0 + row)*2 + c2]      = q0[r] + bb;
        out[((size_t)i*BATCH + gb0 + row + 16)*2 + c2] = q1[r] + bb;
      }
    }
    __syncthreads();
  }
}

// ------------------------------------------------------------ launch -----
extern "C" void kernel_launch(void* const* d_in, const int* in_sizes, int n_in,
                              void* d_out, int out_size, void* d_ws, size_t ws_size,
                              hipStream_t stream) {
  const float* s       = (const float*)d_in[0];
  const float* a       = (const float*)d_in[1];
  const float* en_W    = (const float*)d_in[2];
  const float* en_b    = (const float*)d_in[3];
  const float* oa_W    = (const float*)d_in[4];
  const float* oa_b    = (const float*)d_in[5];
  const float* goal_W  = (const float*)d_in[6];
  const float* goal_b  = (const float*)d_in[7];
  const float* akey_W  = (const float*)d_in[8];
  const float* asel_W  = (const float*)d_in[9];
  const float* aval_W  = (const float*)d_in[10];
  const float* aval_b  = (const float*)d_in[11];
  const float* merge_W = (const float*)d_in[12];
  const float* merge_b = (const float*)d_in[13];
  const float* senc_W  = (const float*)d_in[14];
  const float* senc_b  = (const float*)d_in[15];
  const float* ckey_W  = (const float*)d_in[16];
  const float* csel_W  = (const float*)d_in[17];
  const float* cval_W  = (const float*)d_in[18];
  const float* cval_b  = (const float*)d_in[19];
  const float* cW1     = (const float*)d_in[20];
  const float* cb1     = (const float*)d_in[21];
  const float* cW2     = (const float*)d_in[22];
  const float* cb2     = (const float*)d_in[23];
  unsigned char* wsc = (unsigned char*)d_ws;
  float* F = (float*)(wsc + WSB_F);
  unsigned short* wsu = (unsigned short*)(wsc + WSB_W);
  float* out = (float*)d_out;

  hipMemsetAsync(wsc + WSB_ACCUM, 0, 480, stream);
  stats_partial_kernel<<<48, 256, 0, stream>>>(s, a, (float*)(wsc + WSB_ACCUM));
  stats_final_kernel<<<1, 64, 0, stream>>>((const float*)(wsc + WSB_ACCUM), (float*)(wsc + WSB_STATS));
  fuse_mats_kernel<<<dim3(HD, 3), HD, 0, stream>>>(asel_W, akey_W, csel_W, ckey_W, F);

  splitT_kernel<<<64, 256, 0, stream>>>(F,           wsu + OFF_FT0, wsu + OFF_FT0 + 16384, 128, 128, 128);
  splitT_kernel<<<64, 256, 0, stream>>>(F + 16384,   wsu + OFF_FT1, wsu + OFF_FT1 + 16384, 128, 128, 128);
  splitT_kernel<<<64, 256, 0, stream>>>(F + 32768,   wsu + OFF_MT,  wsu + OFF_MT  + 16384, 128, 128, 128);
  splitT_kernel<<<64, 256, 0, stream>>>(aval_W,          wsu + OFF_AV0, wsu + OFF_AV0 + 16384, 128, 128, 128);
  splitT_kernel<<<64, 256, 0, stream>>>(aval_W + 16384,  wsu + OFF_AV1, wsu + OFF_AV1 + 16384, 128, 128, 128);
  splitT_kernel<<<64, 256, 0, stream>>>(cval_W,          wsu + OFF_CV,  wsu + OFF_CV  + 16384, 128, 128, 128);
  for (int n = 0; n < 3; ++n){
    splitT_kernel<<<192, 256, 0, stream>>>(merge_W + (size_t)n*49152, wsu + OFF_MG(n), wsu + OFF_MG(n) + 49152, 384, 128, 128);
    splitT_kernel<<<128, 256, 0, stream>>>(cW1     + (size_t)n*32768, wsu + OFF_C1(n), wsu + OFF_C1(n) + 32768, 256, 128, 128);
    splitT_kernel<<<8,   256, 0, stream>>>(cW2     + (size_t)n*256,   wsu + OFF_C2(n), wsu + OFF_C2(n) + 2048,  128, 2, 16);
  }
  smallpack_kernel<<<336, 256, 0, stream>>>(en_W, oa_W, goal_W, senc_W, wsu);

  if (ws_size >= (size_t)WSB_SA + SA_BYTES){
    unsigned short* sa_g = (unsigned short*)(wsc + WSB_SA);
    actor_kernel<<<dim3(BATCH / TB, NAG), 256, 0, stream>>>(
        s, a, en_b, oa_b, goal_b, aval_b, merge_b,
        (const unsigned char*)wsc, sa_g);
    critic_kernel<<<dim3(BATCH / TB, NAG), 256, 0, stream>>>(
        s, a, senc_b, cval_b, cb1, cW2, cb2,
        (const unsigned char*)wsc, (const unsigned short*)sa_g, out);
  } else {
    fused_kernel<<<BATCH / TB, 512, 0, stream>>>(
        s, a, en_b, oa_b, goal_b, aval_b, merge_b, senc_b, cval_b, cb1, cb2,
        (const unsigned char*)wsc, out);
  }
}

// Round 4
// 454.887 us; speedup vs baseline: 2.3170x; 1.0475x over previous
//
#include <hip/hip_runtime.h>

#define NAG 3
#define BATCH 32768
#define HD 128
#define SD 18
#define TB 32
#define EPSV 1e-5f
#define SCALE 0.08838834764831845f

typedef __attribute__((ext_vector_type(8))) short short8;
typedef __attribute__((ext_vector_type(4))) float f32x4;

// ---------------- ws byte layout ----------------
#define WSB_STATS 0          // 480B f32  [3][20][2] mean,istd
#define WSB_ACCUM 512        // 480B f32  sum,sumsq
#define WSB_F     1024       // 3*16384 f32 scratch (F0,F1,M)
#define WSB_W     197632     // bf16 weight area (ushort units below)
#define OFF_FT0 0            // 16384, l +16384
#define OFF_FT1 32768
#define OFF_MT  65536
#define OFF_AV0 98304
#define OFF_AV1 131072
#define OFF_CV  163840
#define OFF_MG(n) (196608 + (n)*98304)   // 49152, l +49152
#define OFF_C1(n) (491520 + (n)*65536)   // 32768, l +32768
#define OFF_C2(n) (688128 + (n)*4096)    // 2048,  l +2048 (fallback only)
#define OFF_SW(n) (700416 + (n)*57344)   // 28672, l +28672
#define WSB_SA  2097152      // bf16 sa [3][32768][128] = 25165824 B (path A only)
#define SA_BYTES ((size_t)NAG * BATCH * HD * 2)

__device__ __forceinline__ float lrelu(float x){ return x >= 0.0f ? x : 0.01f * x; }
__device__ __forceinline__ f32x4 lrelu4(f32x4 v){
  f32x4 r; r[0]=lrelu(v[0]); r[1]=lrelu(v[1]); r[2]=lrelu(v[2]); r[3]=lrelu(v[3]); return r;
}
__device__ __forceinline__ f32x4 binit(float b){ f32x4 c; c[0]=b;c[1]=b;c[2]=b;c[3]=b; return c; }
__device__ __forceinline__ unsigned short f2bf(float f){
  unsigned int u = __float_as_uint(f);
  unsigned int r = (u + 0x7FFFu + ((u >> 16) & 1u)) >> 16;
  return (unsigned short)r;
}
__device__ __forceinline__ float bf2f(unsigned short h){
  return __uint_as_float(((unsigned int)h) << 16);
}

// ---------------- prep: batch stats ----------------
__global__ void stats_partial_kernel(const float* __restrict__ s,
                                     const float* __restrict__ a,
                                     float* __restrict__ accum){
  const int n = blockIdx.x >> 4;
  const int chunk = blockIdx.x & 15;
  const int t = threadIdx.x;
  const int rows = BATCH / 16;
  const int b0 = chunk * rows;
  float sum[20], sq[20];
  #pragma unroll
  for (int c = 0; c < 20; ++c){ sum[c] = 0.f; sq[c] = 0.f; }
  for (int b = b0 + t; b < b0 + rows; b += 256){
    const float* row = s + ((size_t)n * BATCH + b) * SD;
    #pragma unroll
    for (int c = 0; c < SD; ++c){ float v = row[c]; sum[c] += v; sq[c] += v * v; }
    const float* ra = a + ((size_t)n * BATCH + b) * 2;
    #pragma unroll
    for (int c = 0; c < 2; ++c){ float v = ra[c]; sum[SD + c] += v; sq[SD + c] += v * v; }
  }
  __shared__ float red[256];
  for (int c = 0; c < 20; ++c){
    red[t] = sum[c]; __syncthreads();
    for (int off = 128; off > 0; off >>= 1){ if (t < off) red[t] += red[t + off]; __syncthreads(); }
    if (t == 0) atomicAdd(&accum[(n * 20 + c) * 2 + 0], red[0]);
    __syncthreads();
    red[t] = sq[c]; __syncthreads();
    for (int off = 128; off > 0; off >>= 1){ if (t < off) red[t] += red[t + off]; __syncthreads(); }
    if (t == 0) atomicAdd(&accum[(n * 20 + c) * 2 + 1], red[0]);
    __syncthreads();
  }
}

__global__ void stats_final_kernel(const float* __restrict__ accum,
                                   float* __restrict__ stats){
  int i = threadIdx.x;
  if (i < 60){
    float S = accum[i * 2 + 0], SQ = accum[i * 2 + 1];
    float mean = S / (float)BATCH;
    float var = SQ / (float)BATCH - mean * mean;
    stats[i * 2 + 0] = mean;
    stats[i * 2 + 1] = 1.0f / sqrtf(var + EPSV);
  }
}

// ---------------- prep: F_m = sel @ key^T (f32) ----------------
__global__ void fuse_mats_kernel(const float* __restrict__ asel, const float* __restrict__ akey,
                                 const float* __restrict__ csel, const float* __restrict__ ckey,
                                 float* __restrict__ F){
  const int h1 = blockIdx.x;
  const int m  = blockIdx.y;
  const int h2 = threadIdx.x;
  const float* A; const float* Bm;
  if (m == 0){ A = asel;            Bm = akey; }
  else if (m == 1){ A = asel + HD*HD; Bm = akey + HD*HD; }
  else { A = csel; Bm = ckey; }
  const float* arow = A + h1 * HD;
  const float* brow = Bm + h2 * HD;
  float acc = 0.f;
  #pragma unroll 4
  for (int d = 0; d < HD; ++d) acc = fmaf(arow[d], brow[d], acc);
  F[m * HD * HD + h1 * HD + h2] = acc;
}

// ---------------- prep: split-bf16 transpose  dst[c][k] = src[k][c] ----------------
__global__ void splitT_kernel(const float* __restrict__ src, unsigned short* __restrict__ dh,
                              unsigned short* __restrict__ dl, int K, int Csrc, int Cdst){
  int idx = blockIdx.x * 256 + threadIdx.x;
  if (idx >= K * Cdst) return;
  int k = idx / Cdst, c = idx - k * Cdst;
  float v = (c < Csrc) ? src[(size_t)k * Csrc + c] : 0.f;
  unsigned short hi = f2bf(v);
  float lo = v - bf2f(hi);
  dh[(size_t)c * K + k] = hi;
  dl[(size_t)c * K + k] = f2bf(lo);
}

// ---------------- prep: packed small-encoder weights [896 cols][32 k] per agent ----------------
__global__ void smallpack_kernel(const float* __restrict__ en_W, const float* __restrict__ oa_W,
                                 const float* __restrict__ goal_W, const float* __restrict__ senc_W,
                                 unsigned short* __restrict__ wsu){
  int idx = blockIdx.x * 256 + threadIdx.x;
  if (idx >= 3 * 896 * 32) return;
  int k = idx & 31; int c = (idx >> 5) % 896; int n = idx / (896 * 32);
  int tt = c >> 7, cc = c & 127;
  float v = 0.f;
  if (tt == 0){
    if (k < 4) v = en_W[(size_t)(n*6 + k)*128 + cc];
    else if (k == 18 || k == 19) v = en_W[(size_t)(n*6 + 4 + (k-18))*128 + cc];
  } else if (tt <= 2){
    int j = tt - 1; int kk = k - (4 + 4*j);
    if (kk >= 0 && kk < 4) v = oa_W[(size_t)(n*4 + kk)*128 + cc];
  } else if (tt <= 5){
    int j = tt - 3; int kk = k - (12 + 2*j);
    if (kk >= 0 && kk < 2) v = goal_W[(size_t)(n*2 + kk)*128 + cc];
  } else {
    if (k < 18) v = senc_W[(size_t)(n*18 + k)*128 + cc];
  }
  unsigned short hi = f2bf(v); float lo = v - bf2f(hi);
  unsigned short* dh = wsu + OFF_SW(n);
  dh[c * 32 + k] = hi;
  dh[28672 + c * 32 + k] = f2bf(lo);
}

// ---------------- MFMA helpers ----------------
__device__ __forceinline__ void ldA(const unsigned char* sm, int base, int mi, int ks, int lane,
                                    short8& h, short8& l){
  int row = mi * 16 + (lane & 15);
  int bc  = ks * 64 + ((lane >> 4) << 4);
  int off = base + row * 256 + (bc ^ ((row & 7) << 4));
  h = *(const short8*)(sm + off);
  l = *(const short8*)(sm + off + 8192);
}
__device__ __forceinline__ short8 ldAh(const unsigned char* sm, int base, int mi, int ks, int lane){
  int row = mi * 16 + (lane & 15);
  int bc  = ks * 64 + ((lane >> 4) << 4);
  return *(const short8*)(sm + base + row * 256 + (bc ^ ((row & 7) << 4)));
}
__device__ __forceinline__ void ldA32(const unsigned char* sm, int base, int mi, int lane,
                                      short8& h, short8& l){
  int row = mi * 16 + (lane & 15);
  int bc  = (lane >> 4) << 4;
  int off = base + row * 64 + (bc ^ ((row & 3) << 4));
  h = *(const short8*)(sm + off);
  l = *(const short8*)(sm + off + 2048);
}

#define MM3(acc, ah, al, bh, bl) \
  acc = __builtin_amdgcn_mfma_f32_16x16x32_bf16(ah, bh, acc, 0, 0, 0); \
  acc = __builtin_amdgcn_mfma_f32_16x16x32_bf16(ah, bl, acc, 0, 0, 0); \
  acc = __builtin_amdgcn_mfma_f32_16x16x32_bf16(al, bh, acc, 0, 0, 0);
#define MM2(acc, ah, bh, bl) \
  acc = __builtin_amdgcn_mfma_f32_16x16x32_bf16(ah, bh, acc, 0, 0, 0); \
  acc = __builtin_amdgcn_mfma_f32_16x16x32_bf16(ah, bl, acc, 0, 0, 0);

// single-col, split-A: 24 MFMA (K=128)
__device__ __forceinline__ void gemmA(f32x4& c0, f32x4& c1, const unsigned char* sm, int abase,
                                      const unsigned short* wh, const unsigned short* wl,
                                      int K, int bcol, int kBaseB, int lane){
  const size_t bb = (size_t)bcol * K + kBaseB + ((lane >> 4) << 3);
  #pragma unroll
  for (int ks = 0; ks < 4; ++ks){
    short8 ah0, al0, ah1, al1;
    ldA(sm, abase, 0, ks, lane, ah0, al0);
    ldA(sm, abase, 1, ks, lane, ah1, al1);
    const short8 bh = *(const short8*)(wh + bb + ks * 32);
    const short8 bl = *(const short8*)(wl + bb + ks * 32);
    MM3(c0, ah0, al0, bh, bl);
    MM3(c1, ah1, al1, bh, bl);
  }
}
// single-col, hi-A only: 16 MFMA (K=128)
__device__ __forceinline__ void gemmAh(f32x4& c0, f32x4& c1, const unsigned char* sm, int abase,
                                       const unsigned short* wh, const unsigned short* wl,
                                       int K, int bcol, int kBaseB, int lane){
  const size_t bb = (size_t)bcol * K + kBaseB + ((lane >> 4) << 3);
  #pragma unroll
  for (int ks = 0; ks < 4; ++ks){
    short8 ah0 = ldAh(sm, abase, 0, ks, lane);
    short8 ah1 = ldAh(sm, abase, 1, ks, lane);
    const short8 bh = *(const short8*)(wh + bb + ks * 32);
    const short8 bl = *(const short8*)(wl + bb + ks * 32);
    MM2(c0, ah0, bh, bl);
    MM2(c1, ah1, bh, bl);
  }
}
// single-col, K=32 packed small encoders: 6 MFMA
__device__ __forceinline__ void gemmS(f32x4& c0, f32x4& c1, const unsigned char* sm, int abase,
                                      const unsigned short* wh, const unsigned short* wl,
                                      int bcol, int lane){
  const size_t bb = (size_t)bcol * 32 + ((lane >> 4) << 3);
  short8 ah0, al0, ah1, al1;
  ldA32(sm, abase, 0, lane, ah0, al0);
  ldA32(sm, abase, 1, lane, ah1, al1);
  const short8 bh = *(const short8*)(wh + bb);
  const short8 bl = *(const short8*)(wl + bb);
  MM3(c0, ah0, al0, bh, bl);
  MM3(c1, ah1, al1, bh, bl);
}

__device__ __forceinline__ void stTile(unsigned char* sm, int base, int mi, int lane, int col, f32x4 v){
  #pragma unroll
  for (int r = 0; r < 4; ++r){
    int row = mi * 16 + ((lane >> 4) << 2) + r;
    int bc  = col * 2;
    int off = base + row * 256 + (bc ^ ((row & 7) << 4));
    unsigned short hi = f2bf(v[r]);
    *(unsigned short*)(sm + off) = hi;
    *(unsigned short*)(sm + off + 8192) = f2bf(v[r] - bf2f(hi));
  }
}
__device__ __forceinline__ void stSK(unsigned char* sm, int base, int mi, int lane, int col, f32x4 v){
  #pragma unroll
  for (int r = 0; r < 4; ++r){
    int row = mi * 16 + ((lane >> 4) << 2) + r;
    int off = base + row * 256 + ((col * 2) ^ ((row & 7) << 5));
    *(unsigned short*)(sm + off) = f2bf(v[r]);
  }
}
__device__ __forceinline__ float dot8(short8 x, short8 y){
  float acc = 0.f;
  #pragma unroll
  for (int e = 0; e < 8; ++e)
    acc = fmaf(bf2f((unsigned short)x[e]), bf2f((unsigned short)y[e]), acc);
  return acc;
}

// fallback helper (path B)
__device__ __forceinline__ void dotTile(unsigned char* sm, int tbase, const f32x4 d0, const f32x4 d1,
                                        int lane, int wave, int col, int part_o){
  float* part = (float*)(sm + part_o);
  #pragma unroll
  for (int mi = 0; mi < 2; ++mi){
    #pragma unroll
    for (int r = 0; r < 4; ++r){
      int row = mi * 16 + ((lane >> 4) << 2) + r;
      int bc  = col * 2;
      int off = tbase + row * 256 + (bc ^ ((row & 7) << 4));
      float v = bf2f(*(const unsigned short*)(sm + off)) +
                bf2f(*(const unsigned short*)(sm + off + 8192));
      float p = (mi ? d1[r] : d0[r]) * v;
      p += __shfl_xor(p, 1, 16);
      p += __shfl_xor(p, 2, 16);
      p += __shfl_xor(p, 4, 16);
      p += __shfl_xor(p, 8, 16);
      if ((lane & 15) == 0) part[wave * 32 + row] = p;
    }
  }
}

// ======================================================================
// PATH A: actor kernel — grid (BATCH/TB, NAG), 512 threads (8 waves x 1 col-tile)
// ======================================================================
__global__ __launch_bounds__(512, 4) void actor_kernel(
    const float* __restrict__ s, const float* __restrict__ a,
    const float* __restrict__ en_b, const float* __restrict__ oa_b,
    const float* __restrict__ goal_b, const float* __restrict__ aval_b,
    const float* __restrict__ merge_b, const unsigned char* __restrict__ wsc,
    unsigned short* __restrict__ sa_g)
{
  __shared__ __align__(16) unsigned char SM[69888];
  const int AXN = 0, AEN = 4096, ASL = 20480, AOV = 36864, ASK = 53248, AEP = 69632, AES = 69760;
  const int t = threadIdx.x, lane = t & 63, wave = t >> 6;
  const int col = wave * 16 + (lane & 15);
  const int n = blockIdx.y;
  const int gb0 = blockIdx.x * TB;
  const float* stats = (const float*)(wsc + WSB_STATS);
  const unsigned short* wsu = (const unsigned short*)(wsc + WSB_W);
  const unsigned short* swh = wsu + OFF_SW(n);
  const unsigned short* swl = swh + 28672;
  const f32x4 Z = binit(0.f);

  if (t < TB){
    int row = t;
    size_t gb = (size_t)gb0 + row;
    const float* st = stats + n * 40;
    const float* srow = s + ((size_t)n * BATCH + gb) * SD;
    const float* arow = a + ((size_t)n * BATCH + gb) * 2;
    #pragma unroll
    for (int c = 0; c < 32; ++c){
      float v = 0.f;
      if (c < 18) v = (srow[c] - st[c*2]) * st[c*2+1];
      else if (c < 20) v = (arow[c-18] - st[c*2]) * st[c*2+1];
      unsigned short hi = f2bf(v);
      int off = AXN + row * 64 + ((c * 2) ^ ((row & 3) << 4));
      *(unsigned short*)(SM + off) = hi;
      *(unsigned short*)(SM + off + 2048) = f2bf(v - bf2f(hi));
    }
  }
  __syncthreads();
  // R0: en_enc
  {
    f32x4 c0 = binit(en_b[n*HD + col]), c1 = c0;
    gemmS(c0, c1, SM, AXN, swh, swl, col, lane);
    stTile(SM, AEN, 0, lane, col, lrelu4(c0));
    stTile(SM, AEN, 1, lane, col, lrelu4(c1));
  }
  __syncthreads();
  // R1: selk0, selk1 -> SK (bf16, 32B-swz)
  {
    f32x4 k0 = Z, k1 = Z;
    gemmA(k0, k1, SM, AEN, wsu + OFF_FT0, wsu + OFF_FT0 + 16384, 128, col, 0, lane);
    stSK(SM, ASK, 0, lane, col, k0); stSK(SM, ASK, 1, lane, col, k1);
    f32x4 m0 = Z, m1 = Z;
    gemmA(m0, m1, SM, AEN, wsu + OFF_FT1, wsu + OFF_FT1 + 16384, 128, col, 0, lane);
    stSK(SM, ASK + 8192, 0, lane, col, m0); stSK(SM, ASK + 8192, 1, lane, col, m1);
  }
  __syncthreads();

  f32x4 ov0 = Z, ov1 = Z;    // oa attention output accum (m0, m1)
  f32x4 og0 = Z, og1 = Z;    // goal attention output accum
  f32x4 v0 = Z, v1 = Z;      // current slice vals
  #pragma unroll 1
  for (int sl = 0; sl < 6; ++sl){
    // ---- region A: accumulate previous slice; stage next slice encoding ----
    if (sl >= 1){
      const float* eP = (const float*)(SM + AEP);
      const int pm = (sl - 1) < 2 ? 0 : 1;
      #pragma unroll
      for (int r = 0; r < 4; ++r){
        int r0 = ((lane >> 4) << 2) + r;
        float e0 = eP[r0], e1 = eP[r0 + 16];
        if (pm == 0){ ov0[r] += e0 * lrelu(v0[r]); ov1[r] += e1 * lrelu(v1[r]); }
        else        { og0[r] += e0 * lrelu(v0[r]); og1[r] += e1 * lrelu(v1[r]); }
      }
      if (sl == 2){
        const float* es = (const float*)(SM + AES);
        f32x4 o0, o1;
        #pragma unroll
        for (int r = 0; r < 4; ++r){
          int r0 = ((lane >> 4) << 2) + r;
          o0[r] = ov0[r] / es[r0];
          o1[r] = ov1[r] / es[r0 + 16];
        }
        stTile(SM, AOV, 0, lane, col, o0);
        stTile(SM, AOV, 1, lane, col, o1);
      }
      if (sl == 5){
        const float* es = (const float*)(SM + AES);
        f32x4 o0, o1;
        #pragma unroll
        for (int r = 0; r < 4; ++r){
          int r0 = ((lane >> 4) << 2) + r;
          o0[r] = og0[r] / es[r0];
          o1[r] = og1[r] / es[r0 + 16];
        }
        stTile(SM, ASL, 0, lane, col, o0);
        stTile(SM, ASL, 1, lane, col, o1);
      }
    }
    if (sl < 5){
      const int wcol = (sl < 2) ? 128 * (1 + sl) : 128 * (3 + (sl - 2));
      const float* bptr = (sl < 2) ? (oa_b + n * HD) : (goal_b + n * HD);
      f32x4 c0 = binit(bptr[col]), c1 = c0;
      gemmS(c0, c1, SM, AXN, swh, swl, wcol + col, lane);
      stTile(SM, ASL, 0, lane, col, lrelu4(c0));
      stTile(SM, ASL, 1, lane, col, lrelu4(c1));
    }
    __syncthreads();
    if (sl < 5){
      // ---- region B: vals GEMM (regs) + per-row logit dot + exp ----
      const unsigned short* vwh = (sl < 2) ? (wsu + OFF_AV0) : (wsu + OFF_AV1);
      const float* avb = aval_b + ((sl < 2) ? 0 : HD);
      v0 = binit(avb[col]); v1 = v0;
      gemmA(v0, v1, SM, ASL, vwh, vwh + 16384, 128, col, 0, lane);
      {
        int row = wave * 4 + (lane >> 4);
        int cb = (lane & 15) * 16;
        int sw5 = (row & 7) << 5, sw4 = (row & 7) << 4;
        const unsigned char* skb = SM + ASK + ((sl < 2) ? 0 : 8192) + row * 256;
        short8 kf = *(const short8*)(skb + (cb ^ sw5));
        const unsigned char* slb = SM + ASL + row * 256;
        short8 ef = *(const short8*)(slb + (cb ^ sw4));
        float p = dot8(kf, ef);
        p += __shfl_xor(p, 1, 16);
        p += __shfl_xor(p, 2, 16);
        p += __shfl_xor(p, 4, 16);
        p += __shfl_xor(p, 8, 16);
        if ((lane & 15) == 0){
          float e = __expf(p * SCALE);
          ((float*)(SM + AEP))[row] = e;
          float* es = (float*)(SM + AES);
          es[row] = (sl == 0 || sl == 2) ? e : es[row] + e;
        }
      }
      __syncthreads();
    }
  }
  // merge: sa = lrelu([en|ov0|ov1] @ merge_W + b) -> global bf16
  {
    const unsigned short* mh = wsu + OFF_MG(n);
    const unsigned short* ml = mh + 49152;
    f32x4 c0 = binit(merge_b[n*HD + col]), c1 = c0;
    gemmA(c0, c1, SM, AEN, mh, ml, 384, col, 0,   lane);
    gemmA(c0, c1, SM, AOV, mh, ml, 384, col, 128, lane);
    gemmA(c0, c1, SM, ASL, mh, ml, 384, col, 256, lane);
    #pragma unroll
    for (int r = 0; r < 4; ++r){
      int r0 = ((lane >> 4) << 2) + r;
      sa_g[((size_t)n * BATCH + gb0 + r0) * HD + col]      = f2bf(lrelu(c0[r]));
      sa_g[((size_t)n * BATCH + gb0 + r0 + 16) * HD + col] = f2bf(lrelu(c1[r]));
    }
  }
}

// ======================================================================
// PATH A: critic kernel — grid (BATCH/TB, NAG=i), 512 threads
// ======================================================================
__global__ __launch_bounds__(512, 4) void critic_kernel(
    const float* __restrict__ s, const float* __restrict__ a,
    const float* __restrict__ senc_b, const float* __restrict__ cval_b,
    const float* __restrict__ cb1, const float* __restrict__ cW2,
    const float* __restrict__ cb2, const unsigned char* __restrict__ wsc,
    const unsigned short* __restrict__ sa_g, float* __restrict__ out)
{
  __shared__ __align__(16) unsigned char SM[61952];
  const int CXN = 0, CEN = 4096, CSMo = 20480, CSA = 28672, COV = 45056, CH = 28672, CLW = 61440;
  const int t = threadIdx.x, lane = t & 63, wave = t >> 6;
  const int col = wave * 16 + (lane & 15);
  const int i = blockIdx.y;
  const int gb0 = blockIdx.x * TB;
  const int j0 = (i == 0) ? 1 : 0;
  const int j1 = (i == 2) ? 1 : 2;
  const float* stats = (const float*)(wsc + WSB_STATS);
  const unsigned short* wsu = (const unsigned short*)(wsc + WSB_W);
  const unsigned short* swh = wsu + OFF_SW(i);
  const unsigned short* swl = swh + 28672;
  const f32x4 Z = binit(0.f);

  // R0: stage XN_i + copy sa_j0/j1 -> LDS (hi-only, 16B-swz)
  if (t < TB){
    int row = t;
    size_t gb = (size_t)gb0 + row;
    const float* st = stats + i * 40;
    const float* srow = s + ((size_t)i * BATCH + gb) * SD;
    const float* arow = a + ((size_t)i * BATCH + gb) * 2;
    #pragma unroll
    for (int c = 0; c < 32; ++c){
      float v = 0.f;
      if (c < 18) v = (srow[c] - st[c*2]) * st[c*2+1];
      else if (c < 20) v = (arow[c-18] - st[c*2]) * st[c*2+1];
      unsigned short hi = f2bf(v);
      int off = CXN + row * 64 + ((c * 2) ^ ((row & 3) << 4));
      *(unsigned short*)(SM + off) = hi;
      *(unsigned short*)(SM + off + 2048) = f2bf(v - bf2f(hi));
    }
  }
  {
    int r = t >> 4, ch = (t & 15) * 16;
    int sw = (r & 7) << 4;
    short8 u0 = *(const short8*)(sa_g + ((size_t)j0 * BATCH + gb0 + r) * HD + (ch >> 1));
    *(short8*)(SM + CSA + r * 256 + (ch ^ sw)) = u0;
    short8 u1 = *(const short8*)(sa_g + ((size_t)j1 * BATCH + gb0 + r) * HD + (ch >> 1));
    *(short8*)(SM + CSA + 8192 + r * 256 + (ch ^ sw)) = u1;
  }
  __syncthreads();
  // R1: s_enc
  {
    f32x4 c0 = binit(senc_b[i*HD + col]), c1 = c0;
    gemmS(c0, c1, SM, CXN, swh, swl, 768 + col, lane);
    stTile(SM, CEN, 0, lane, col, lrelu4(c0));
    stTile(SM, CEN, 1, lane, col, lrelu4(c1));
  }
  __syncthreads();
  // R2: selsM = s_enc @ M -> CSM (bf16, 32B-swz)
  {
    f32x4 k0 = Z, k1 = Z;
    gemmA(k0, k1, SM, CEN, wsu + OFF_MT, wsu + OFF_MT + 16384, 128, col, 0, lane);
    stSK(SM, CSMo, 0, lane, col, k0);
    stSK(SM, CSMo, 1, lane, col, k1);
  }
  __syncthreads();
  // R3: vals GEMMs (hi-A) + logit dots + 2-way softmax
  f32x4 v00, v01, v10, v11;
  {
    v00 = binit(cval_b[col]); v01 = v00;
    gemmAh(v00, v01, SM, CSA,        wsu + OFF_CV, wsu + OFF_CV + 16384, 128, col, 0, lane);
    v10 = binit(cval_b[col]); v11 = v10;
    gemmAh(v10, v11, SM, CSA + 8192, wsu + OFF_CV, wsu + OFF_CV + 16384, 128, col, 0, lane);
    int row = wave * 4 + (lane >> 4);
    int cb = (lane & 15) * 16;
    int sw5 = (row & 7) << 5, sw4 = (row & 7) << 4;
    short8 m0 = *(const short8*)(SM + CSMo + row * 256 + (cb ^ sw5));
    short8 a0 = *(const short8*)(SM + CSA + row * 256 + (cb ^ sw4));
    short8 b0 = *(const short8*)(SM + CSA + 8192 + row * 256 + (cb ^ sw4));
    float p0 = dot8(m0, a0);
    float p1 = dot8(m0, b0);
    p0 += __shfl_xor(p0, 1, 16); p0 += __shfl_xor(p0, 2, 16);
    p0 += __shfl_xor(p0, 4, 16); p0 += __shfl_xor(p0, 8, 16);
    p1 += __shfl_xor(p1, 1, 16); p1 += __shfl_xor(p1, 2, 16);
    p1 += __shfl_xor(p1, 4, 16); p1 += __shfl_xor(p1, 8, 16);
    if ((lane & 15) == 0){
      float e0 = __expf(p0 * SCALE), e1 = __expf(p1 * SCALE);
      float inv = 1.f / (e0 + e1);
      ((float*)(SM + CLW))[row]      = e0 * inv;
      ((float*)(SM + CLW))[32 + row] = e1 * inv;
    }
  }
  __syncthreads();
  // R4: ov -> COV
  {
    const float* w0 = (const float*)(SM + CLW);
    const float* w1 = w0 + 32;
    f32x4 o0, o1;
    #pragma unroll
    for (int r = 0; r < 4; ++r){
      int r0 = ((lane >> 4) << 2) + r;
      o0[r] = w0[r0]      * lrelu(v00[r]) + w1[r0]      * lrelu(v10[r]);
      o1[r] = w0[r0 + 16] * lrelu(v01[r]) + w1[r0 + 16] * lrelu(v11[r]);
    }
    stTile(SM, COV, 0, lane, col, o0);
    stTile(SM, COV, 1, lane, col, o1);
  }
  __syncthreads();
  // R5: h = lrelu([s_enc|ov] @ cW1 + b) -> CH (overwrites CSA)
  {
    const unsigned short* c1h = wsu + OFF_C1(i);
    const unsigned short* c1l = c1h + 32768;
    f32x4 h0 = binit(cb1[i*HD + col]), h1 = h0;
    gemmA(h0, h1, SM, CEN, c1h, c1l, 256, col, 0,   lane);
    gemmA(h0, h1, SM, COV, c1h, c1l, 256, col, 128, lane);
    stTile(SM, CH, 0, lane, col, lrelu4(h0));
    stTile(SM, CH, 1, lane, col, lrelu4(h1));
  }
  __syncthreads();
  // R6: q = h @ cW2 + cb2 (per-row dot)
  {
    int row = wave * 4 + (lane >> 4);
    int cb = (lane & 15) * 16;
    int sw4 = (row & 7) << 4;
    const unsigned char* hb = SM + CH + row * 256;
    short8 h0 = *(const short8*)(hb + (cb ^ sw4));
    short8 l0 = *(const short8*)(hb + 8192 + (cb ^ sw4));
    float q0 = 0.f, q1 = 0.f;
    #pragma unroll
    for (int e = 0; e < 8; ++e){
      int d = (lane & 15) * 8 + e;
      float hv = bf2f((unsigned short)h0[e]) + bf2f((unsigned short)l0[e]);
      q0 = fmaf(hv, cW2[(i * HD + d) * 2 + 0], q0);
      q1 = fmaf(hv, cW2[(i * HD + d) * 2 + 1], q1);
    }
    q0 += __shfl_xor(q0, 1, 16); q0 += __shfl_xor(q0, 2, 16);
    q0 += __shfl_xor(q0, 4, 16); q0 += __shfl_xor(q0, 8, 16);
    q1 += __shfl_xor(q1, 1, 16); q1 += __shfl_xor(q1, 2, 16);
    q1 += __shfl_xor(q1, 4, 16); q1 += __shfl_xor(q1, 8, 16);
    if ((lane & 15) == 0){
      out[((size_t)i * BATCH + gb0 + row) * 2 + 0] = q0 + cb2[i * 2 + 0];
      out[((size_t)i * BATCH + gb0 + row) * 2 + 1] = q1 + cb2[i * 2 + 1];
    }
  }
}

// ======================================================================
// PATH B fallback: round-2 single fused kernel (proven)
// ======================================================================
#define XN_O    0
#define EN_O    12288
#define SLICE_O 28672
#define OV0_O   45056
#define SA_O    61440
#define PART_O  110592
#define EP_O    111616
#define ESUM_O  111744
#define LW_O    111872
#define SM_TOTAL 113024

__global__ __launch_bounds__(512, 2) void fused_kernel(
    const float* __restrict__ s, const float* __restrict__ a,
    const float* __restrict__ en_b, const float* __restrict__ oa_b,
    const float* __restrict__ goal_b, const float* __restrict__ aval_b,
    const float* __restrict__ merge_b, const float* __restrict__ senc_b,
    const float* __restrict__ cval_b, const float* __restrict__ cb1,
    const float* __restrict__ cb2, const unsigned char* __restrict__ wsc,
    float* __restrict__ out)
{
  __shared__ __align__(16) unsigned char SM[SM_TOTAL];
  unsigned char* sm = SM;
  const int t = threadIdx.x;
  const int lane = t & 63;
  const int wave = t >> 6;
  const int col = wave * 16 + (lane & 15);
  const int gb0 = blockIdx.x * TB;
  const float* stats = (const float*)(wsc + WSB_STATS);
  const unsigned short* wsu = (const unsigned short*)(wsc + WSB_W);
  const f32x4 Z = binit(0.f);

  if (t < 96){
    int n = t >> 5, row = t & 31;
    size_t gb = (size_t)gb0 + row;
    const float* st = stats + n * 40;
    const float* srow = s + ((size_t)n * BATCH + gb) * SD;
    const float* arow = a + ((size_t)n * BATCH + gb) * 2;
    #pragma unroll
    for (int c = 0; c < 32; ++c){
      float v = 0.f;
      if (c < 18) v = (srow[c] - st[c*2]) * st[c*2+1];
      else if (c < 20) v = (arow[c-18] - st[c*2]) * st[c*2+1];
      unsigned short hi = f2bf(v);
      int off = XN_O + n * 4096 + row * 64 + ((c * 2) ^ ((row & 3) << 4));
      *(unsigned short*)(sm + off) = hi;
      *(unsigned short*)(sm + off + 2048) = f2bf(v - bf2f(hi));
    }
  }
  __syncthreads();

  #pragma unroll 1
  for (int n = 0; n < NAG; ++n){
    const unsigned short* swh = wsu + OFF_SW(n);
    const unsigned short* swl = swh + 28672;
    {
      f32x4 v0 = binit(en_b[n*HD + col]), v1 = v0;
      gemmS(v0, v1, sm, XN_O + n*4096, swh, swl, 0 + col, lane);
      stTile(sm, EN_O, 0, lane, col, lrelu4(v0));
      stTile(sm, EN_O, 1, lane, col, lrelu4(v1));
    }
    __syncthreads();
    f32x4 sk0a = Z, sk0b = Z, sk1a = Z, sk1b = Z;
    gemmA(sk0a, sk0b, sm, EN_O, wsu + OFF_FT0, wsu + OFF_FT0 + 16384, 128, col, 0, lane);
    gemmA(sk1a, sk1b, sm, EN_O, wsu + OFF_FT1, wsu + OFF_FT1 + 16384, 128, col, 0, lane);

    f32x4 ov0a = Z, ov0b = Z;
    #pragma unroll 1
    for (int j = 0; j < 2; ++j){
      __syncthreads();
      f32x4 v0 = binit(oa_b[n*HD + col]), v1 = v0;
      gemmS(v0, v1, sm, XN_O + n*4096, swh, swl, 128*(1+j) + col, lane);
      stTile(sm, SLICE_O, 0, lane, col, lrelu4(v0));
      stTile(sm, SLICE_O, 1, lane, col, lrelu4(v1));
      __syncthreads();
      dotTile(sm, SLICE_O, sk0a, sk0b, lane, wave, col, PART_O);
      __syncthreads();
      if (t < TB){
        const float* part = (const float*)(sm + PART_O);
        float tot = 0.f;
        #pragma unroll
        for (int w2 = 0; w2 < 8; ++w2) tot += part[w2*32 + t];
        float e = __expf(tot * SCALE);
        ((float*)(sm + EP_O))[t] = e;
        float* es = (float*)(sm + ESUM_O);
        es[t] = (j == 0) ? e : es[t] + e;
      }
      __syncthreads();
      f32x4 w0 = binit(aval_b[col]), w1 = w0;
      gemmA(w0, w1, sm, SLICE_O, wsu + OFF_AV0, wsu + OFF_AV0 + 16384, 128, col, 0, lane);
      const float* eP = (const float*)(sm + EP_O);
      #pragma unroll
      for (int r = 0; r < 4; ++r){
        int row0 = ((lane >> 4) << 2) + r;
        ov0a[r] += eP[row0]      * lrelu(w0[r]);
        ov0b[r] += eP[row0 + 16] * lrelu(w1[r]);
      }
    }
    {
      const float* es = (const float*)(sm + ESUM_O);
      f32x4 o0, o1;
      #pragma unroll
      for (int r = 0; r < 4; ++r){
        int row0 = ((lane >> 4) << 2) + r;
        o0[r] = ov0a[r] / es[row0];
        o1[r] = ov0b[r] / es[row0 + 16];
      }
      stTile(sm, OV0_O, 0, lane, col, o0);
      stTile(sm, OV0_O, 1, lane, col, o1);
    }

    f32x4 ov1a = Z, ov1b = Z;
    #pragma unroll 1
    for (int j = 0; j < 3; ++j){
      __syncthreads();
      f32x4 v0 = binit(goal_b[n*HD + col]), v1 = v0;
      gemmS(v0, v1, sm, XN_O + n*4096, swh, swl, 128*(3+j) + col, lane);
      stTile(sm, SLICE_O, 0, lane, col, lrelu4(v0));
      stTile(sm, SLICE_O, 1, lane, col, lrelu4(v1));
      __syncthreads();
      dotTile(sm, SLICE_O, sk1a, sk1b, lane, wave, col, PART_O);
      __syncthreads();
      if (t < TB){
        const float* part = (const float*)(sm + PART_O);
        float tot = 0.f;
        #pragma unroll
        for (int w2 = 0; w2 < 8; ++w2) tot += part[w2*32 + t];
        float e = __expf(tot * SCALE);
        ((float*)(sm + EP_O))[t] = e;
        float* es = (float*)(sm + ESUM_O);
        es[t] = (j == 0) ? e : es[t] + e;
      }
      __syncthreads();
      f32x4 w0 = binit(aval_b[HD + col]), w1 = w0;
      gemmA(w0, w1, sm, SLICE_O, wsu + OFF_AV1, wsu + OFF_AV1 + 16384, 128, col, 0, lane);
      const float* eP = (const float*)(sm + EP_O);
      #pragma unroll
      for (int r = 0; r < 4; ++r){
        int row0 = ((lane >> 4) << 2) + r;
        ov1a[r] += eP[row0]      * lrelu(w0[r]);
        ov1b[r] += eP[row0 + 16] * lrelu(w1[r]);
      }
    }
    __syncthreads();
    {
      const float* es = (const float*)(sm + ESUM_O);
      f32x4 o0, o1;
      #pragma unroll
      for (int r = 0; r < 4; ++r){
        int row0 = ((lane >> 4) << 2) + r;
        o0[r] = ov1a[r] / es[row0];
        o1[r] = ov1b[r] / es[row0 + 16];
      }
      stTile(sm, SLICE_O, 0, lane, col, o0);
      stTile(sm, SLICE_O, 1, lane, col, o1);
    }
    __syncthreads();
    {
      const unsigned short* mh = wsu + OFF_MG(n);
      const unsigned short* ml = mh + 49152;
      f32x4 m0 = binit(merge_b[n*HD + col]), m1 = m0;
      gemmA(m0, m1, sm, EN_O,    mh, ml, 384, col, 0,   lane);
      gemmA(m0, m1, sm, OV0_O,   mh, ml, 384, col, 128, lane);
      gemmA(m0, m1, sm, SLICE_O, mh, ml, 384, col, 256, lane);
      stTile(sm, SA_O + n*16384, 0, lane, col, lrelu4(m0));
      stTile(sm, SA_O + n*16384, 1, lane, col, lrelu4(m1));
    }
    __syncthreads();
  }

  #pragma unroll 1
  for (int i = 0; i < NAG; ++i){
    const unsigned short* swh = wsu + OFF_SW(i);
    const unsigned short* swl = swh + 28672;
    f32x4 e0 = binit(senc_b[i*HD + col]), e1 = e0;
    gemmS(e0, e1, sm, XN_O + i*4096, swh, swl, 768 + col, lane);
    stTile(sm, EN_O, 0, lane, col, lrelu4(e0));
    stTile(sm, EN_O, 1, lane, col, lrelu4(e1));
    __syncthreads();
    f32x4 sm0 = Z, sm1 = Z;
    gemmA(sm0, sm1, sm, EN_O, wsu + OFF_MT, wsu + OFF_MT + 16384, 128, col, 0, lane);
    #pragma unroll 1
    for (int j = 0; j < NAG; ++j){
      if (j == i) continue;
      dotTile(sm, SA_O + j*16384, sm0, sm1, lane, wave, col, PART_O);
      __syncthreads();
      if (t < TB){
        const float* part = (const float*)(sm + PART_O);
        float tot = 0.f;
        #pragma unroll
        for (int w2 = 0; w2 < 8; ++w2) tot += part[w2*32 + t];
        ((float*)(sm + LW_O))[(i*3 + j)*32 + t] = tot;
      }
      __syncthreads();
    }
  }
  if (t < TB){
    float* LW = (float*)(sm + LW_O);
    #pragma unroll
    for (int i = 0; i < NAG; ++i){
      int j0 = (i == 0) ? 1 : 0;
      int j1 = (i == 2) ? 1 : 2;
      float l0 = LW[(i*3 + j0)*32 + t] * SCALE;
      float l1 = LW[(i*3 + j1)*32 + t] * SCALE;
      float q0 = __expf(l0), q1 = __expf(l1);
      float inv = 1.f / (q0 + q1);
      LW[(i*3 + j0)*32 + t] = q0 * inv;
      LW[(i*3 + j1)*32 + t] = q1 * inv;
    }
  }
  __syncthreads();
  f32x4 oc00 = Z, oc01 = Z, oc10 = Z, oc11 = Z, oc20 = Z, oc21 = Z;
  {
    const float* LW = (const float*)(sm + LW_O);
    #pragma unroll 1
    for (int j = 0; j < NAG; ++j){
      f32x4 v0 = binit(cval_b[col]), v1 = v0;
      gemmA(v0, v1, sm, SA_O + j*16384, wsu + OFF_CV, wsu + OFF_CV + 16384, 128, col, 0, lane);
      v0 = lrelu4(v0); v1 = lrelu4(v1);
      #pragma unroll
      for (int i = 0; i < NAG; ++i){
        if (i == j) continue;
        f32x4& o0 = (i == 0) ? oc00 : ((i == 1) ? oc10 : oc20);
        f32x4& o1 = (i == 0) ? oc01 : ((i == 1) ? oc11 : oc21);
        #pragma unroll
        for (int r = 0; r < 4; ++r){
          int row0 = ((lane >> 4) << 2) + r;
          o0[r] += LW[(i*3 + j)*32 + row0]      * v0[r];
          o1[r] += LW[(i*3 + j)*32 + row0 + 16] * v1[r];
        }
      }
    }
  }
  __syncthreads();
  #pragma unroll 1
  for (int i = 0; i < NAG; ++i){
    const unsigned short* swh = wsu + OFF_SW(i);
    const unsigned short* swl = swh + 28672;
    f32x4 se0 = binit(senc_b[i*HD + col]), se1 = se0;
    gemmS(se0, se1, sm, XN_O + i*4096, swh, swl, 768 + col, lane);
    stTile(sm, EN_O, 0, lane, col, lrelu4(se0));
    stTile(sm, EN_O, 1, lane, col, lrelu4(se1));
    {
      f32x4 o0 = (i == 0) ? oc00 : ((i == 1) ? oc10 : oc20);
      f32x4 o1 = (i == 0) ? oc01 : ((i == 1) ? oc11 : oc21);
      stTile(sm, OV0_O, 0, lane, col, o0);
      stTile(sm, OV0_O, 1, lane, col, o1);
    }
    __syncthreads();
    const unsigned short* c1h = wsu + OFF_C1(i);
    const unsigned short* c1l = c1h + 32768;
    f32x4 h0 = binit(cb1[i*HD + col]), h1 = h0;
    gemmA(h0, h1, sm, EN_O,  c1h, c1l, 256, col, 0,   lane);
    gemmA(h0, h1, sm, OV0_O, c1h, c1l, 256, col, 128, lane);
    stTile(sm, SLICE_O, 0, lane, col, lrelu4(h0));
    stTile(sm, SLICE_O, 1, lane, col, lrelu4(h1));
    __syncthreads();
    f32x4 q0 = Z, q1 = Z;
    gemmA(q0, q1, sm, SLICE_O, wsu + OFF_C2(i), wsu + OFF_C2(i) + 2048, 128, (lane & 15), 0, lane);
    if (wave == 0 && (lane & 15) < 2){
      int c2 = lane & 15;
      float bb = cb2[i*2 + c2];
      #pragma unroll
      for (int r = 0; r < 4; ++r){
        int row = ((lane >> 4) << 2) + r;
        out[((size_t)i*BATCH + gb0 + row)*2 + c2]      = q0[r] + bb;
        out[((size_t)i*BATCH + gb0 + row + 16)*2 + c2] = q1[r] + bb;
      }
    }
    __syncthreads();
  }
}

// ------------------------------------------------------------ launch -----
extern "C" void kernel_launch(void* const* d_in, const int* in_sizes, int n_in,
                              void* d_out, int out_size, void* d_ws, size_t ws_size,
                              hipStream_t stream) {
  const float* s       = (const float*)d_in[0];
  const float* a       = (const float*)d_in[1];
  const float* en_W    = (const float*)d_in[2];
  const float* en_b    = (const float*)d_in[3];
  const float* oa_W    = (const float*)d_in[4];
  const float* oa_b    = (const float*)d_in[5];
  const float* goal_W  = (const float*)d_in[6];
  const float* goal_b  = (const float*)d_in[7];
  const float* akey_W  = (const float*)d_in[8];
  const float* asel_W  = (const float*)d_in[9];
  const float* aval_W  = (const float*)d_in[10];
  const float* aval_b  = (const float*)d_in[11];
  const float* merge_W = (const float*)d_in[12];
  const float* merge_b = (const float*)d_in[13];
  const float* senc_W  = (const float*)d_in[14];
  const float* senc_b  = (const float*)d_in[15];
  const float* ckey_W  = (const float*)d_in[16];
  const float* csel_W  = (const float*)d_in[17];
  const float* cval_W  = (const float*)d_in[18];
  const float* cval_b  = (const float*)d_in[19];
  const float* cW1     = (const float*)d_in[20];
  const float* cb1     = (const float*)d_in[21];
  const float* cW2     = (const float*)d_in[22];
  const float* cb2     = (const float*)d_in[23];
  unsigned char* wsc = (unsigned char*)d_ws;
  float* F = (float*)(wsc + WSB_F);
  unsigned short* wsu = (unsigned short*)(wsc + WSB_W);
  float* out = (float*)d_out;

  hipMemsetAsync(wsc + WSB_ACCUM, 0, 480, stream);
  stats_partial_kernel<<<48, 256, 0, stream>>>(s, a, (float*)(wsc + WSB_ACCUM));
  stats_final_kernel<<<1, 64, 0, stream>>>((const float*)(wsc + WSB_ACCUM), (float*)(wsc + WSB_STATS));
  fuse_mats_kernel<<<dim3(HD, 3), HD, 0, stream>>>(asel_W, akey_W, csel_W, ckey_W, F);

  splitT_kernel<<<64, 256, 0, stream>>>(F,           wsu + OFF_FT0, wsu + OFF_FT0 + 16384, 128, 128, 128);
  splitT_kernel<<<64, 256, 0, stream>>>(F + 16384,   wsu + OFF_FT1, wsu + OFF_FT1 + 16384, 128, 128, 128);
  splitT_kernel<<<64, 256, 0, stream>>>(F + 32768,   wsu + OFF_MT,  wsu + OFF_MT  + 16384, 128, 128, 128);
  splitT_kernel<<<64, 256, 0, stream>>>(aval_W,          wsu + OFF_AV0, wsu + OFF_AV0 + 16384, 128, 128, 128);
  splitT_kernel<<<64, 256, 0, stream>>>(aval_W + 16384,  wsu + OFF_AV1, wsu + OFF_AV1 + 16384, 128, 128, 128);
  splitT_kernel<<<64, 256, 0, stream>>>(cval_W,          wsu + OFF_CV,  wsu + OFF_CV  + 16384, 128, 128, 128);
  for (int n = 0; n < 3; ++n){
    splitT_kernel<<<192, 256, 0, stream>>>(merge_W + (size_t)n*49152, wsu + OFF_MG(n), wsu + OFF_MG(n) + 49152, 384, 128, 128);
    splitT_kernel<<<128, 256, 0, stream>>>(cW1     + (size_t)n*32768, wsu + OFF_C1(n), wsu + OFF_C1(n) + 32768, 256, 128, 128);
    splitT_kernel<<<8,   256, 0, stream>>>(cW2     + (size_t)n*256,   wsu + OFF_C2(n), wsu + OFF_C2(n) + 2048,  128, 2, 16);
  }
  smallpack_kernel<<<336, 256, 0, stream>>>(en_W, oa_W, goal_W, senc_W, wsu);

  if (ws_size >= (size_t)WSB_SA + SA_BYTES){
    unsigned short* sa_g = (unsigned short*)(wsc + WSB_SA);
    actor_kernel<<<dim3(BATCH / TB, NAG), 512, 0, stream>>>(
        s, a, en_b, oa_b, goal_b, aval_b, merge_b,
        (const unsigned char*)wsc, sa_g);
    critic_kernel<<<dim3(BATCH / TB, NAG), 512, 0, stream>>>(
        s, a, senc_b, cval_b, cb1, cW2, cb2,
        (const unsigned char*)wsc, (const unsigned short*)sa_g, out);
  } else {
    fused_kernel<<<BATCH / TB, 512, 0, stream>>>(
        s, a, en_b, oa_b, goal_b, aval_b, merge_b, senc_b, cval_b, cb1, cb2,
        (const unsigned char*)wsc, out);
  }
}

// Round 5
// 441.763 us; speedup vs baseline: 2.3859x; 1.0297x over previous
//
#include <hip/hip_runtime.h>

#define NAG 3
#define BATCH 32768
#define HD 128
#define SD 18
#define TB 32
#define EPSV 1e-5f
#define SCALE 0.08838834764831845f

typedef __attribute__((ext_vector_type(8))) short short8;
typedef __attribute__((ext_vector_type(4))) float f32x4;

// ---------------- ws byte layout ----------------
#define WSB_STATS 0          // 480B f32  [3][20][2] mean,istd
#define WSB_ACCUM 512        // 480B f32  sum,sumsq
#define WSB_F     1024       // 3*16384 f32 scratch (F0,F1,M)
#define WSB_W     197632     // bf16 weight area (ushort units below)
#define OFF_FT0 0            // 16384, l +16384
#define OFF_FT1 32768
#define OFF_MT  65536
#define OFF_AV0 98304
#define OFF_AV1 131072
#define OFF_CV  163840
#define OFF_MG(n) (196608 + (n)*98304)   // 49152, l +49152
#define OFF_C1(n) (491520 + (n)*65536)   // 32768, l +32768
#define OFF_C2(n) (688128 + (n)*4096)    // 2048,  l +2048 (fallback only)
#define OFF_SW(n) (700416 + (n)*57344)   // 28672, l +28672
#define WSB_SA  2097152      // bf16 sa [3][32768][128] = 25165824 B (path A only)
#define SA_BYTES ((size_t)NAG * BATCH * HD * 2)

__device__ __forceinline__ float lrelu(float x){ return x >= 0.0f ? x : 0.01f * x; }
__device__ __forceinline__ f32x4 lrelu4(f32x4 v){
  f32x4 r; r[0]=lrelu(v[0]); r[1]=lrelu(v[1]); r[2]=lrelu(v[2]); r[3]=lrelu(v[3]); return r;
}
__device__ __forceinline__ f32x4 binit(float b){ f32x4 c; c[0]=b;c[1]=b;c[2]=b;c[3]=b; return c; }
__device__ __forceinline__ unsigned short f2bf(float f){
  unsigned int u = __float_as_uint(f);
  unsigned int r = (u + 0x7FFFu + ((u >> 16) & 1u)) >> 16;
  return (unsigned short)r;
}
__device__ __forceinline__ float bf2f(unsigned short h){
  return __uint_as_float(((unsigned int)h) << 16);
}

// ---------------- prep: batch stats ----------------
__global__ void stats_partial_kernel(const float* __restrict__ s,
                                     const float* __restrict__ a,
                                     float* __restrict__ accum){
  const int n = blockIdx.x >> 4;
  const int chunk = blockIdx.x & 15;
  const int t = threadIdx.x;
  const int rows = BATCH / 16;
  const int b0 = chunk * rows;
  float sum[20], sq[20];
  #pragma unroll
  for (int c = 0; c < 20; ++c){ sum[c] = 0.f; sq[c] = 0.f; }
  for (int b = b0 + t; b < b0 + rows; b += 256){
    const float* row = s + ((size_t)n * BATCH + b) * SD;
    #pragma unroll
    for (int c = 0; c < SD; ++c){ float v = row[c]; sum[c] += v; sq[c] += v * v; }
    const float* ra = a + ((size_t)n * BATCH + b) * 2;
    #pragma unroll
    for (int c = 0; c < 2; ++c){ float v = ra[c]; sum[SD + c] += v; sq[SD + c] += v * v; }
  }
  __shared__ float red[256];
  for (int c = 0; c < 20; ++c){
    red[t] = sum[c]; __syncthreads();
    for (int off = 128; off > 0; off >>= 1){ if (t < off) red[t] += red[t + off]; __syncthreads(); }
    if (t == 0) atomicAdd(&accum[(n * 20 + c) * 2 + 0], red[0]);
    __syncthreads();
    red[t] = sq[c]; __syncthreads();
    for (int off = 128; off > 0; off >>= 1){ if (t < off) red[t] += red[t + off]; __syncthreads(); }
    if (t == 0) atomicAdd(&accum[(n * 20 + c) * 2 + 1], red[0]);
    __syncthreads();
  }
}

__global__ void stats_final_kernel(const float* __restrict__ accum,
                                   float* __restrict__ stats){
  int i = threadIdx.x;
  if (i < 60){
    float S = accum[i * 2 + 0], SQ = accum[i * 2 + 1];
    float mean = S / (float)BATCH;
    float var = SQ / (float)BATCH - mean * mean;
    stats[i * 2 + 0] = mean;
    stats[i * 2 + 1] = 1.0f / sqrtf(var + EPSV);
  }
}

// ---------------- prep: F_m = sel @ key^T (f32) ----------------
__global__ void fuse_mats_kernel(const float* __restrict__ asel, const float* __restrict__ akey,
                                 const float* __restrict__ csel, const float* __restrict__ ckey,
                                 float* __restrict__ F){
  const int h1 = blockIdx.x;
  const int m  = blockIdx.y;
  const int h2 = threadIdx.x;
  const float* A; const float* Bm;
  if (m == 0){ A = asel;            Bm = akey; }
  else if (m == 1){ A = asel + HD*HD; Bm = akey + HD*HD; }
  else { A = csel; Bm = ckey; }
  const float* arow = A + h1 * HD;
  const float* brow = Bm + h2 * HD;
  float acc = 0.f;
  #pragma unroll 4
  for (int d = 0; d < HD; ++d) acc = fmaf(arow[d], brow[d], acc);
  F[m * HD * HD + h1 * HD + h2] = acc;
}

// ---------------- prep: split-bf16 transpose  dst[c][k] = src[k][c] ----------------
__global__ void splitT_kernel(const float* __restrict__ src, unsigned short* __restrict__ dh,
                              unsigned short* __restrict__ dl, int K, int Csrc, int Cdst){
  int idx = blockIdx.x * 256 + threadIdx.x;
  if (idx >= K * Cdst) return;
  int k = idx / Cdst, c = idx - k * Cdst;
  float v = (c < Csrc) ? src[(size_t)k * Csrc + c] : 0.f;
  unsigned short hi = f2bf(v);
  float lo = v - bf2f(hi);
  dh[(size_t)c * K + k] = hi;
  dl[(size_t)c * K + k] = f2bf(lo);
}

// ---------------- prep: packed small-encoder weights [896 cols][32 k] per agent ----------------
__global__ void smallpack_kernel(const float* __restrict__ en_W, const float* __restrict__ oa_W,
                                 const float* __restrict__ goal_W, const float* __restrict__ senc_W,
                                 unsigned short* __restrict__ wsu){
  int idx = blockIdx.x * 256 + threadIdx.x;
  if (idx >= 3 * 896 * 32) return;
  int k = idx & 31; int c = (idx >> 5) % 896; int n = idx / (896 * 32);
  int tt = c >> 7, cc = c & 127;
  float v = 0.f;
  if (tt == 0){
    if (k < 4) v = en_W[(size_t)(n*6 + k)*128 + cc];
    else if (k == 18 || k == 19) v = en_W[(size_t)(n*6 + 4 + (k-18))*128 + cc];
  } else if (tt <= 2){
    int j = tt - 1; int kk = k - (4 + 4*j);
    if (kk >= 0 && kk < 4) v = oa_W[(size_t)(n*4 + kk)*128 + cc];
  } else if (tt <= 5){
    int j = tt - 3; int kk = k - (12 + 2*j);
    if (kk >= 0 && kk < 2) v = goal_W[(size_t)(n*2 + kk)*128 + cc];
  } else {
    if (k < 18) v = senc_W[(size_t)(n*18 + k)*128 + cc];
  }
  unsigned short hi = f2bf(v); float lo = v - bf2f(hi);
  unsigned short* dh = wsu + OFF_SW(n);
  dh[c * 32 + k] = hi;
  dh[28672 + c * 32 + k] = f2bf(lo);
}

// ---------------- MFMA helpers ----------------
__device__ __forceinline__ void ldA(const unsigned char* sm, int base, int mi, int ks, int lane,
                                    short8& h, short8& l){
  int row = mi * 16 + (lane & 15);
  int bc  = ks * 64 + ((lane >> 4) << 4);
  int off = base + row * 256 + (bc ^ ((row & 7) << 4));
  h = *(const short8*)(sm + off);
  l = *(const short8*)(sm + off + 8192);
}
__device__ __forceinline__ short8 ldAh(const unsigned char* sm, int base, int mi, int ks, int lane){
  int row = mi * 16 + (lane & 15);
  int bc  = ks * 64 + ((lane >> 4) << 4);
  return *(const short8*)(sm + base + row * 256 + (bc ^ ((row & 7) << 4)));
}
__device__ __forceinline__ void ldA32(const unsigned char* sm, int base, int mi, int lane,
                                      short8& h, short8& l){
  int row = mi * 16 + (lane & 15);
  int bc  = (lane >> 4) << 4;
  int off = base + row * 64 + (bc ^ ((row & 3) << 4));
  h = *(const short8*)(sm + off);
  l = *(const short8*)(sm + off + 2048);
}

#define MM3(acc, ah, al, bh, bl) \
  acc = __builtin_amdgcn_mfma_f32_16x16x32_bf16(ah, bh, acc, 0, 0, 0); \
  acc = __builtin_amdgcn_mfma_f32_16x16x32_bf16(ah, bl, acc, 0, 0, 0); \
  acc = __builtin_amdgcn_mfma_f32_16x16x32_bf16(al, bh, acc, 0, 0, 0);
#define MM2(acc, ah, bh, bl) \
  acc = __builtin_amdgcn_mfma_f32_16x16x32_bf16(ah, bh, acc, 0, 0, 0); \
  acc = __builtin_amdgcn_mfma_f32_16x16x32_bf16(ah, bl, acc, 0, 0, 0);

// split-A, split-B: 24 MFMA (fallback kernel)
__device__ __forceinline__ void gemmA(f32x4& c0, f32x4& c1, const unsigned char* sm, int abase,
                                      const unsigned short* wh, const unsigned short* wl,
                                      int K, int bcol, int kBaseB, int lane){
  const size_t bb = (size_t)bcol * K + kBaseB + ((lane >> 4) << 3);
  #pragma unroll
  for (int ks = 0; ks < 4; ++ks){
    short8 ah0, al0, ah1, al1;
    ldA(sm, abase, 0, ks, lane, ah0, al0);
    ldA(sm, abase, 1, ks, lane, ah1, al1);
    const short8 bh = *(const short8*)(wh + bb + ks * 32);
    const short8 bl = *(const short8*)(wl + bb + ks * 32);
    MM3(c0, ah0, al0, bh, bl);
    MM3(c1, ah1, al1, bh, bl);
  }
}
// hi-A, split-B: 16 MFMA, 8 LDS reads (path A workhorse)
__device__ __forceinline__ void gemmAh(f32x4& c0, f32x4& c1, const unsigned char* sm, int abase,
                                       const unsigned short* wh, const unsigned short* wl,
                                       int K, int bcol, int kBaseB, int lane){
  const size_t bb = (size_t)bcol * K + kBaseB + ((lane >> 4) << 3);
  #pragma unroll
  for (int ks = 0; ks < 4; ++ks){
    short8 ah0 = ldAh(sm, abase, 0, ks, lane);
    short8 ah1 = ldAh(sm, abase, 1, ks, lane);
    const short8 bh = *(const short8*)(wh + bb + ks * 32);
    const short8 bl = *(const short8*)(wl + bb + ks * 32);
    MM2(c0, ah0, bh, bl);
    MM2(c1, ah1, bh, bl);
  }
}
// hi-A shared across TWO split-B matrices: 32 MFMA, 8 LDS reads
__device__ __forceinline__ void gemmAW2(f32x4& c0, f32x4& c1, f32x4& d0, f32x4& d1,
                                        const unsigned char* sm, int abase,
                                        const unsigned short* wh0, const unsigned short* wl0,
                                        const unsigned short* wh1, const unsigned short* wl1,
                                        int K, int bcol, int lane){
  const size_t bb = (size_t)bcol * K + ((lane >> 4) << 3);
  #pragma unroll
  for (int ks = 0; ks < 4; ++ks){
    short8 ah0 = ldAh(sm, abase, 0, ks, lane);
    short8 ah1 = ldAh(sm, abase, 1, ks, lane);
    const short8 b0h = *(const short8*)(wh0 + bb + ks * 32);
    const short8 b0l = *(const short8*)(wl0 + bb + ks * 32);
    const short8 b1h = *(const short8*)(wh1 + bb + ks * 32);
    const short8 b1l = *(const short8*)(wl1 + bb + ks * 32);
    MM2(c0, ah0, b0h, b0l); MM2(c1, ah1, b0h, b0l);
    MM2(d0, ah0, b1h, b1l); MM2(d1, ah1, b1h, b1l);
  }
}
// split-A (XN K=32), split-B: 6 MFMA
__device__ __forceinline__ void gemmS(f32x4& c0, f32x4& c1, const unsigned char* sm, int abase,
                                      const unsigned short* wh, const unsigned short* wl,
                                      int bcol, int lane){
  const size_t bb = (size_t)bcol * 32 + ((lane >> 4) << 3);
  short8 ah0, al0, ah1, al1;
  ldA32(sm, abase, 0, lane, ah0, al0);
  ldA32(sm, abase, 1, lane, ah1, al1);
  const short8 bh = *(const short8*)(wh + bb);
  const short8 bl = *(const short8*)(wl + bb);
  MM3(c0, ah0, al0, bh, bl);
  MM3(c1, ah1, al1, bh, bl);
}

// split store (16KB tile: hi + lo at +8192)
__device__ __forceinline__ void stTile(unsigned char* sm, int base, int mi, int lane, int col, f32x4 v){
  #pragma unroll
  for (int r = 0; r < 4; ++r){
    int row = mi * 16 + ((lane >> 4) << 2) + r;
    int bc  = col * 2;
    int off = base + row * 256 + (bc ^ ((row & 7) << 4));
    unsigned short hi = f2bf(v[r]);
    *(unsigned short*)(sm + off) = hi;
    *(unsigned short*)(sm + off + 8192) = f2bf(v[r] - bf2f(hi));
  }
}
// hi-only store (8KB tile)
__device__ __forceinline__ void stH(unsigned char* sm, int base, int mi, int lane, int col, f32x4 v){
  #pragma unroll
  for (int r = 0; r < 4; ++r){
    int row = mi * 16 + ((lane >> 4) << 2) + r;
    int off = base + row * 256 + ((col * 2) ^ ((row & 7) << 4));
    *(unsigned short*)(sm + off) = f2bf(v[r]);
  }
}
__device__ __forceinline__ void stSK(unsigned char* sm, int base, int mi, int lane, int col, f32x4 v){
  #pragma unroll
  for (int r = 0; r < 4; ++r){
    int row = mi * 16 + ((lane >> 4) << 2) + r;
    int off = base + row * 256 + ((col * 2) ^ ((row & 7) << 5));
    *(unsigned short*)(sm + off) = f2bf(v[r]);
  }
}
__device__ __forceinline__ float dot8(short8 x, short8 y){
  float acc = 0.f;
  #pragma unroll
  for (int e = 0; e < 8; ++e)
    acc = fmaf(bf2f((unsigned short)x[e]), bf2f((unsigned short)y[e]), acc);
  return acc;
}

// fallback helper (path B)
__device__ __forceinline__ void dotTile(unsigned char* sm, int tbase, const f32x4 d0, const f32x4 d1,
                                        int lane, int wave, int col, int part_o){
  float* part = (float*)(sm + part_o);
  #pragma unroll
  for (int mi = 0; mi < 2; ++mi){
    #pragma unroll
    for (int r = 0; r < 4; ++r){
      int row = mi * 16 + ((lane >> 4) << 2) + r;
      int bc  = col * 2;
      int off = tbase + row * 256 + (bc ^ ((row & 7) << 4));
      float v = bf2f(*(const unsigned short*)(sm + off)) +
                bf2f(*(const unsigned short*)(sm + off + 8192));
      float p = (mi ? d1[r] : d0[r]) * v;
      p += __shfl_xor(p, 1, 16);
      p += __shfl_xor(p, 2, 16);
      p += __shfl_xor(p, 4, 16);
      p += __shfl_xor(p, 8, 16);
      if ((lane & 15) == 0) part[wave * 32 + row] = p;
    }
  }
}

// ======================================================================
// PATH A: actor kernel — grid (BATCH/TB, NAG), 512 threads, ~45KB LDS
// ======================================================================
__global__ __launch_bounds__(512, 6) void actor_kernel(
    const float* __restrict__ s, const float* __restrict__ a,
    const float* __restrict__ en_b, const float* __restrict__ oa_b,
    const float* __restrict__ goal_b, const float* __restrict__ aval_b,
    const float* __restrict__ merge_b, const unsigned char* __restrict__ wsc,
    unsigned short* __restrict__ sa_g)
{
  __shared__ __align__(16) unsigned char SM[45312];
  const int AXN = 0, AEN = 4096, ASL = 12288, AOV = 20480, ASK = 28672, AEP = 45056, AES = 45184;
  const int t = threadIdx.x, lane = t & 63, wave = t >> 6;
  const int col = wave * 16 + (lane & 15);
  const int n = blockIdx.y;
  const int gb0 = blockIdx.x * TB;
  const float* stats = (const float*)(wsc + WSB_STATS);
  const unsigned short* wsu = (const unsigned short*)(wsc + WSB_W);
  const unsigned short* swh = wsu + OFF_SW(n);
  const unsigned short* swl = swh + 28672;
  const f32x4 Z = binit(0.f);

  if (t < TB){
    int row = t;
    size_t gb = (size_t)gb0 + row;
    const float* st = stats + n * 40;
    const float* srow = s + ((size_t)n * BATCH + gb) * SD;
    const float* arow = a + ((size_t)n * BATCH + gb) * 2;
    #pragma unroll
    for (int c = 0; c < 32; ++c){
      float v = 0.f;
      if (c < 18) v = (srow[c] - st[c*2]) * st[c*2+1];
      else if (c < 20) v = (arow[c-18] - st[c*2]) * st[c*2+1];
      unsigned short hi = f2bf(v);
      int off = AXN + row * 64 + ((c * 2) ^ ((row & 3) << 4));
      *(unsigned short*)(SM + off) = hi;
      *(unsigned short*)(SM + off + 2048) = f2bf(v - bf2f(hi));
    }
  }
  __syncthreads();
  // R0: en_enc -> AEN (hi)
  {
    f32x4 c0 = binit(en_b[n*HD + col]), c1 = c0;
    gemmS(c0, c1, SM, AXN, swh, swl, col, lane);
    stH(SM, AEN, 0, lane, col, lrelu4(c0));
    stH(SM, AEN, 1, lane, col, lrelu4(c1));
  }
  __syncthreads();
  // R1: selk0 & selk1 in one A-pass -> SK tiles (bf16, 32B-swz)
  {
    f32x4 k0 = Z, k1 = Z, m0 = Z, m1 = Z;
    gemmAW2(k0, k1, m0, m1, SM, AEN,
            wsu + OFF_FT0, wsu + OFF_FT0 + 16384,
            wsu + OFF_FT1, wsu + OFF_FT1 + 16384, 128, col, lane);
    stSK(SM, ASK, 0, lane, col, k0); stSK(SM, ASK, 1, lane, col, k1);
    stSK(SM, ASK + 8192, 0, lane, col, m0); stSK(SM, ASK + 8192, 1, lane, col, m1);
  }
  __syncthreads();

  f32x4 ov0 = Z, ov1 = Z;    // oa attention output accum
  f32x4 og0 = Z, og1 = Z;    // goal attention output accum
  f32x4 v0 = Z, v1 = Z;      // current slice vals
  #pragma unroll 1
  for (int sl = 0; sl < 6; ++sl){
    // ---- region A: accumulate previous slice; stage next slice encoding ----
    if (sl >= 1){
      const float* eP = (const float*)(SM + AEP);
      const int pm = (sl - 1) < 2 ? 0 : 1;
      #pragma unroll
      for (int r = 0; r < 4; ++r){
        int r0 = ((lane >> 4) << 2) + r;
        float e0 = eP[r0], e1 = eP[r0 + 16];
        if (pm == 0){ ov0[r] += e0 * lrelu(v0[r]); ov1[r] += e1 * lrelu(v1[r]); }
        else        { og0[r] += e0 * lrelu(v0[r]); og1[r] += e1 * lrelu(v1[r]); }
      }
      if (sl == 2){
        const float* es = (const float*)(SM + AES);
        f32x4 o0, o1;
        #pragma unroll
        for (int r = 0; r < 4; ++r){
          int r0 = ((lane >> 4) << 2) + r;
          o0[r] = ov0[r] / es[r0];
          o1[r] = ov1[r] / es[r0 + 16];
        }
        stH(SM, AOV, 0, lane, col, o0);
        stH(SM, AOV, 1, lane, col, o1);
      }
      if (sl == 5){
        const float* es = (const float*)(SM + AES);
        f32x4 o0, o1;
        #pragma unroll
        for (int r = 0; r < 4; ++r){
          int r0 = ((lane >> 4) << 2) + r;
          o0[r] = og0[r] / es[r0];
          o1[r] = og1[r] / es[r0 + 16];
        }
        stH(SM, ASL, 0, lane, col, o0);
        stH(SM, ASL, 1, lane, col, o1);
      }
    }
    if (sl < 5){
      const int wcol = (sl < 2) ? 128 * (1 + sl) : 128 * (3 + (sl - 2));
      const float* bptr = (sl < 2) ? (oa_b + n * HD) : (goal_b + n * HD);
      f32x4 c0 = binit(bptr[col]), c1 = c0;
      gemmS(c0, c1, SM, AXN, swh, swl, wcol + col, lane);
      stH(SM, ASL, 0, lane, col, lrelu4(c0));
      stH(SM, ASL, 1, lane, col, lrelu4(c1));
    }
    __syncthreads();
    if (sl < 5){
      // ---- region B: vals GEMM (regs) + per-row logit dot + exp ----
      const unsigned short* vwh = (sl < 2) ? (wsu + OFF_AV0) : (wsu + OFF_AV1);
      const float* avb = aval_b + ((sl < 2) ? 0 : HD);
      v0 = binit(avb[col]); v1 = v0;
      gemmAh(v0, v1, SM, ASL, vwh, vwh + 16384, 128, col, 0, lane);
      {
        int row = wave * 4 + (lane >> 4);
        int cb = (lane & 15) * 16;
        int sw5 = (row & 7) << 5, sw4 = (row & 7) << 4;
        const unsigned char* skb = SM + ASK + ((sl < 2) ? 0 : 8192) + row * 256;
        short8 kf = *(const short8*)(skb + (cb ^ sw5));
        const unsigned char* slb = SM + ASL + row * 256;
        short8 ef = *(const short8*)(slb + (cb ^ sw4));
        float p = dot8(kf, ef);
        p += __shfl_xor(p, 1, 16);
        p += __shfl_xor(p, 2, 16);
        p += __shfl_xor(p, 4, 16);
        p += __shfl_xor(p, 8, 16);
        if ((lane & 15) == 0){
          float e = __expf(p * SCALE);
          ((float*)(SM + AEP))[row] = e;
          float* es = (float*)(SM + AES);
          es[row] = (sl == 0 || sl == 2) ? e : es[row] + e;
        }
      }
      __syncthreads();
    }
  }
  // merge: sa = lrelu([en|ov0|ov1] @ merge_W + b) -> global bf16
  {
    const unsigned short* mh = wsu + OFF_MG(n);
    const unsigned short* ml = mh + 49152;
    f32x4 c0 = binit(merge_b[n*HD + col]), c1 = c0;
    gemmAh(c0, c1, SM, AEN, mh, ml, 384, col, 0,   lane);
    gemmAh(c0, c1, SM, AOV, mh, ml, 384, col, 128, lane);
    gemmAh(c0, c1, SM, ASL, mh, ml, 384, col, 256, lane);
    #pragma unroll
    for (int r = 0; r < 4; ++r){
      int r0 = ((lane >> 4) << 2) + r;
      sa_g[((size_t)n * BATCH + gb0 + r0) * HD + col]      = f2bf(lrelu(c0[r]));
      sa_g[((size_t)n * BATCH + gb0 + r0 + 16) * HD + col] = f2bf(lrelu(c1[r]));
    }
  }
}

// ======================================================================
// PATH A: critic kernel — grid (BATCH/TB, NAG=i), 512 threads, ~45KB LDS
// ======================================================================
__global__ __launch_bounds__(512, 6) void critic_kernel(
    const float* __restrict__ s, const float* __restrict__ a,
    const float* __restrict__ senc_b, const float* __restrict__ cval_b,
    const float* __restrict__ cb1, const float* __restrict__ cW2,
    const float* __restrict__ cb2, const unsigned char* __restrict__ wsc,
    const unsigned short* __restrict__ sa_g, float* __restrict__ out)
{
  __shared__ __align__(16) unsigned char SM[45312];
  const int CXN = 0, CEN = 4096, CSMo = 12288, CSA = 20480, COV = 36864, CH = 20480, CLW = 45056;
  const int t = threadIdx.x, lane = t & 63, wave = t >> 6;
  const int col = wave * 16 + (lane & 15);
  const int i = blockIdx.y;
  const int gb0 = blockIdx.x * TB;
  const int j0 = (i == 0) ? 1 : 0;
  const int j1 = (i == 2) ? 1 : 2;
  const float* stats = (const float*)(wsc + WSB_STATS);
  const unsigned short* wsu = (const unsigned short*)(wsc + WSB_W);
  const unsigned short* swh = wsu + OFF_SW(i);
  const unsigned short* swl = swh + 28672;
  const f32x4 Z = binit(0.f);

  // R0: stage XN_i (split) + copy sa_j0/j1 -> LDS (hi, 16B-swz)
  if (t < TB){
    int row = t;
    size_t gb = (size_t)gb0 + row;
    const float* st = stats + i * 40;
    const float* srow = s + ((size_t)i * BATCH + gb) * SD;
    const float* arow = a + ((size_t)i * BATCH + gb) * 2;
    #pragma unroll
    for (int c = 0; c < 32; ++c){
      float v = 0.f;
      if (c < 18) v = (srow[c] - st[c*2]) * st[c*2+1];
      else if (c < 20) v = (arow[c-18] - st[c*2]) * st[c*2+1];
      unsigned short hi = f2bf(v);
      int off = CXN + row * 64 + ((c * 2) ^ ((row & 3) << 4));
      *(unsigned short*)(SM + off) = hi;
      *(unsigned short*)(SM + off + 2048) = f2bf(v - bf2f(hi));
    }
  }
  {
    int r = t >> 4, ch = (t & 15) * 16;
    int sw = (r & 7) << 4;
    short8 u0 = *(const short8*)(sa_g + ((size_t)j0 * BATCH + gb0 + r) * HD + (ch >> 1));
    *(short8*)(SM + CSA + r * 256 + (ch ^ sw)) = u0;
    short8 u1 = *(const short8*)(sa_g + ((size_t)j1 * BATCH + gb0 + r) * HD + (ch >> 1));
    *(short8*)(SM + CSA + 8192 + r * 256 + (ch ^ sw)) = u1;
  }
  __syncthreads();
  // R1: s_enc -> CEN (hi)
  {
    f32x4 c0 = binit(senc_b[i*HD + col]), c1 = c0;
    gemmS(c0, c1, SM, CXN, swh, swl, 768 + col, lane);
    stH(SM, CEN, 0, lane, col, lrelu4(c0));
    stH(SM, CEN, 1, lane, col, lrelu4(c1));
  }
  __syncthreads();
  // R2: selsM = s_enc @ M -> CSM (bf16, 32B-swz)
  {
    f32x4 k0 = Z, k1 = Z;
    gemmAh(k0, k1, SM, CEN, wsu + OFF_MT, wsu + OFF_MT + 16384, 128, col, 0, lane);
    stSK(SM, CSMo, 0, lane, col, k0);
    stSK(SM, CSMo, 1, lane, col, k1);
  }
  __syncthreads();
  // R3: vals GEMMs (hi-A) + logit dots + 2-way softmax
  f32x4 v00, v01, v10, v11;
  {
    v00 = binit(cval_b[col]); v01 = v00;
    gemmAh(v00, v01, SM, CSA,        wsu + OFF_CV, wsu + OFF_CV + 16384, 128, col, 0, lane);
    v10 = binit(cval_b[col]); v11 = v10;
    gemmAh(v10, v11, SM, CSA + 8192, wsu + OFF_CV, wsu + OFF_CV + 16384, 128, col, 0, lane);
    int row = wave * 4 + (lane >> 4);
    int cb = (lane & 15) * 16;
    int sw5 = (row & 7) << 5, sw4 = (row & 7) << 4;
    short8 m0 = *(const short8*)(SM + CSMo + row * 256 + (cb ^ sw5));
    short8 a0 = *(const short8*)(SM + CSA + row * 256 + (cb ^ sw4));
    short8 b0 = *(const short8*)(SM + CSA + 8192 + row * 256 + (cb ^ sw4));
    float p0 = dot8(m0, a0);
    float p1 = dot8(m0, b0);
    p0 += __shfl_xor(p0, 1, 16); p0 += __shfl_xor(p0, 2, 16);
    p0 += __shfl_xor(p0, 4, 16); p0 += __shfl_xor(p0, 8, 16);
    p1 += __shfl_xor(p1, 1, 16); p1 += __shfl_xor(p1, 2, 16);
    p1 += __shfl_xor(p1, 4, 16); p1 += __shfl_xor(p1, 8, 16);
    if ((lane & 15) == 0){
      float e0 = __expf(p0 * SCALE), e1 = __expf(p1 * SCALE);
      float inv = 1.f / (e0 + e1);
      ((float*)(SM + CLW))[row]      = e0 * inv;
      ((float*)(SM + CLW))[32 + row] = e1 * inv;
    }
  }
  __syncthreads();
  // R4: ov -> COV (hi)
  {
    const float* w0 = (const float*)(SM + CLW);
    const float* w1 = w0 + 32;
    f32x4 o0, o1;
    #pragma unroll
    for (int r = 0; r < 4; ++r){
      int r0 = ((lane >> 4) << 2) + r;
      o0[r] = w0[r0]      * lrelu(v00[r]) + w1[r0]      * lrelu(v10[r]);
      o1[r] = w0[r0 + 16] * lrelu(v01[r]) + w1[r0 + 16] * lrelu(v11[r]);
    }
    stH(SM, COV, 0, lane, col, o0);
    stH(SM, COV, 1, lane, col, o1);
  }
  __syncthreads();
  // R5: h = lrelu([s_enc|ov] @ cW1 + b) -> CH (split; overwrites CSA tiles)
  {
    const unsigned short* c1h = wsu + OFF_C1(i);
    const unsigned short* c1l = c1h + 32768;
    f32x4 h0 = binit(cb1[i*HD + col]), h1 = h0;
    gemmAh(h0, h1, SM, CEN, c1h, c1l, 256, col, 0,   lane);
    gemmAh(h0, h1, SM, COV, c1h, c1l, 256, col, 128, lane);
    stTile(SM, CH, 0, lane, col, lrelu4(h0));
    stTile(SM, CH, 1, lane, col, lrelu4(h1));
  }
  __syncthreads();
  // R6: q = h @ cW2 + cb2 (per-row dot, split h)
  {
    int row = wave * 4 + (lane >> 4);
    int cb = (lane & 15) * 16;
    int sw4 = (row & 7) << 4;
    const unsigned char* hb = SM + CH + row * 256;
    short8 h0 = *(const short8*)(hb + (cb ^ sw4));
    short8 l0 = *(const short8*)(hb + 8192 + (cb ^ sw4));
    float q0 = 0.f, q1 = 0.f;
    #pragma unroll
    for (int e = 0; e < 8; ++e){
      int d = (lane & 15) * 8 + e;
      float hv = bf2f((unsigned short)h0[e]) + bf2f((unsigned short)l0[e]);
      q0 = fmaf(hv, cW2[(i * HD + d) * 2 + 0], q0);
      q1 = fmaf(hv, cW2[(i * HD + d) * 2 + 1], q1);
    }
    q0 += __shfl_xor(q0, 1, 16); q0 += __shfl_xor(q0, 2, 16);
    q0 += __shfl_xor(q0, 4, 16); q0 += __shfl_xor(q0, 8, 16);
    q1 += __shfl_xor(q1, 1, 16); q1 += __shfl_xor(q1, 2, 16);
    q1 += __shfl_xor(q1, 4, 16); q1 += __shfl_xor(q1, 8, 16);
    if ((lane & 15) == 0){
      out[((size_t)i * BATCH + gb0 + row) * 2 + 0] = q0 + cb2[i * 2 + 0];
      out[((size_t)i * BATCH + gb0 + row) * 2 + 1] = q1 + cb2[i * 2 + 1];
    }
  }
}

// ======================================================================
// PATH B fallback: round-2 single fused kernel (proven)
// ======================================================================
#define XN_O    0
#define EN_O    12288
#define SLICE_O 28672
#define OV0_O   45056
#define SA_O    61440
#define PART_O  110592
#define EP_O    111616
#define ESUM_O  111744
#define LW_O    111872
#define SM_TOTAL 113024

__global__ __launch_bounds__(512, 2) void fused_kernel(
    const float* __restrict__ s, const float* __restrict__ a,
    const float* __restrict__ en_b, const float* __restrict__ oa_b,
    const float* __restrict__ goal_b, const float* __restrict__ aval_b,
    const float* __restrict__ merge_b, const float* __restrict__ senc_b,
    const float* __restrict__ cval_b, const float* __restrict__ cb1,
    const float* __restrict__ cb2, const unsigned char* __restrict__ wsc,
    float* __restrict__ out)
{
  __shared__ __align__(16) unsigned char SM[SM_TOTAL];
  unsigned char* sm = SM;
  const int t = threadIdx.x;
  const int lane = t & 63;
  const int wave = t >> 6;
  const int col = wave * 16 + (lane & 15);
  const int gb0 = blockIdx.x * TB;
  const float* stats = (const float*)(wsc + WSB_STATS);
  const unsigned short* wsu = (const unsigned short*)(wsc + WSB_W);
  const f32x4 Z = binit(0.f);

  if (t < 96){
    int n = t >> 5, row = t & 31;
    size_t gb = (size_t)gb0 + row;
    const float* st = stats + n * 40;
    const float* srow = s + ((size_t)n * BATCH + gb) * SD;
    const float* arow = a + ((size_t)n * BATCH + gb) * 2;
    #pragma unroll
    for (int c = 0; c < 32; ++c){
      float v = 0.f;
      if (c < 18) v = (srow[c] - st[c*2]) * st[c*2+1];
      else if (c < 20) v = (arow[c-18] - st[c*2]) * st[c*2+1];
      unsigned short hi = f2bf(v);
      int off = XN_O + n * 4096 + row * 64 + ((c * 2) ^ ((row & 3) << 4));
      *(unsigned short*)(sm + off) = hi;
      *(unsigned short*)(sm + off + 2048) = f2bf(v - bf2f(hi));
    }
  }
  __syncthreads();

  #pragma unroll 1
  for (int n = 0; n < NAG; ++n){
    const unsigned short* swh = wsu + OFF_SW(n);
    const unsigned short* swl = swh + 28672;
    {
      f32x4 v0 = binit(en_b[n*HD + col]), v1 = v0;
      gemmS(v0, v1, sm, XN_O + n*4096, swh, swl, 0 + col, lane);
      stTile(sm, EN_O, 0, lane, col, lrelu4(v0));
      stTile(sm, EN_O, 1, lane, col, lrelu4(v1));
    }
    __syncthreads();
    f32x4 sk0a = Z, sk0b = Z, sk1a = Z, sk1b = Z;
    gemmA(sk0a, sk0b, sm, EN_O, wsu + OFF_FT0, wsu + OFF_FT0 + 16384, 128, col, 0, lane);
    gemmA(sk1a, sk1b, sm, EN_O, wsu + OFF_FT1, wsu + OFF_FT1 + 16384, 128, col, 0, lane);

    f32x4 ov0a = Z, ov0b = Z;
    #pragma unroll 1
    for (int j = 0; j < 2; ++j){
      __syncthreads();
      f32x4 v0 = binit(oa_b[n*HD + col]), v1 = v0;
      gemmS(v0, v1, sm, XN_O + n*4096, swh, swl, 128*(1+j) + col, lane);
      stTile(sm, SLICE_O, 0, lane, col, lrelu4(v0));
      stTile(sm, SLICE_O, 1, lane, col, lrelu4(v1));
      __syncthreads();
      dotTile(sm, SLICE_O, sk0a, sk0b, lane, wave, col, PART_O);
      __syncthreads();
      if (t < TB){
        const float* part = (const float*)(sm + PART_O);
        float tot = 0.f;
        #pragma unroll
        for (int w2 = 0; w2 < 8; ++w2) tot += part[w2*32 + t];
        float e = __expf(tot * SCALE);
        ((float*)(sm + EP_O))[t] = e;
        float* es = (float*)(sm + ESUM_O);
        es[t] = (j == 0) ? e : es[t] + e;
      }
      __syncthreads();
      f32x4 w0 = binit(aval_b[col]), w1 = w0;
      gemmA(w0, w1, sm, SLICE_O, wsu + OFF_AV0, wsu + OFF_AV0 + 16384, 128, col, 0, lane);
      const float* eP = (const float*)(sm + EP_O);
      #pragma unroll
      for (int r = 0; r < 4; ++r){
        int row0 = ((lane >> 4) << 2) + r;
        ov0a[r] += eP[row0]      * lrelu(w0[r]);
        ov0b[r] += eP[row0 + 16] * lrelu(w1[r]);
      }
    }
    {
      const float* es = (const float*)(sm + ESUM_O);
      f32x4 o0, o1;
      #pragma unroll
      for (int r = 0; r < 4; ++r){
        int row0 = ((lane >> 4) << 2) + r;
        o0[r] = ov0a[r] / es[row0];
        o1[r] = ov0b[r] / es[row0 + 16];
      }
      stTile(sm, OV0_O, 0, lane, col, o0);
      stTile(sm, OV0_O, 1, lane, col, o1);
    }

    f32x4 ov1a = Z, ov1b = Z;
    #pragma unroll 1
    for (int j = 0; j < 3; ++j){
      __syncthreads();
      f32x4 v0 = binit(goal_b[n*HD + col]), v1 = v0;
      gemmS(v0, v1, sm, XN_O + n*4096, swh, swl, 128*(3+j) + col, lane);
      stTile(sm, SLICE_O, 0, lane, col, lrelu4(v0));
      stTile(sm, SLICE_O, 1, lane, col, lrelu4(v1));
      __syncthreads();
      dotTile(sm, SLICE_O, sk1a, sk1b, lane, wave, col, PART_O);
      __syncthreads();
      if (t < TB){
        const float* part = (const float*)(sm + PART_O);
        float tot = 0.f;
        #pragma unroll
        for (int w2 = 0; w2 < 8; ++w2) tot += part[w2*32 + t];
        float e = __expf(tot * SCALE);
        ((float*)(sm + EP_O))[t] = e;
        float* es = (float*)(sm + ESUM_O);
        es[t] = (j == 0) ? e : es[t] + e;
      }
      __syncthreads();
      f32x4 w0 = binit(aval_b[HD + col]), w1 = w0;
      gemmA(w0, w1, sm, SLICE_O, wsu + OFF_AV1, wsu + OFF_AV1 + 16384, 128, col, 0, lane);
      const float* eP = (const float*)(sm + EP_O);
      #pragma unroll
      for (int r = 0; r < 4; ++r){
        int row0 = ((lane >> 4) << 2) + r;
        ov1a[r] += eP[row0]      * lrelu(w0[r]);
        ov1b[r] += eP[row0 + 16] * lrelu(w1[r]);
      }
    }
    __syncthreads();
    {
      const float* es = (const float*)(sm + ESUM_O);
      f32x4 o0, o1;
      #pragma unroll
      for (int r = 0; r < 4; ++r){
        int row0 = ((lane >> 4) << 2) + r;
        o0[r] = ov1a[r] / es[row0];
        o1[r] = ov1b[r] / es[row0 + 16];
      }
      stTile(sm, SLICE_O, 0, lane, col, o0);
      stTile(sm, SLICE_O, 1, lane, col, o1);
    }
    __syncthreads();
    {
      const unsigned short* mh = wsu + OFF_MG(n);
      const unsigned short* ml = mh + 49152;
      f32x4 m0 = binit(merge_b[n*HD + col]), m1 = m0;
      gemmA(m0, m1, sm, EN_O,    mh, ml, 384, col, 0,   lane);
      gemmA(m0, m1, sm, OV0_O,   mh, ml, 384, col, 128, lane);
      gemmA(m0, m1, sm, SLICE_O, mh, ml, 384, col, 256, lane);
      stTile(sm, SA_O + n*16384, 0, lane, col, lrelu4(m0));
      stTile(sm, SA_O + n*16384, 1, lane, col, lrelu4(m1));
    }
    __syncthreads();
  }

  #pragma unroll 1
  for (int i = 0; i < NAG; ++i){
    const unsigned short* swh = wsu + OFF_SW(i);
    const unsigned short* swl = swh + 28672;
    f32x4 e0 = binit(senc_b[i*HD + col]), e1 = e0;
    gemmS(e0, e1, sm, XN_O + i*4096, swh, swl, 768 + col, lane);
    stTile(sm, EN_O, 0, lane, col, lrelu4(e0));
    stTile(sm, EN_O, 1, lane, col, lrelu4(e1));
    __syncthreads();
    f32x4 sm0 = Z, sm1 = Z;
    gemmA(sm0, sm1, sm, EN_O, wsu + OFF_MT, wsu + OFF_MT + 16384, 128, col, 0, lane);
    #pragma unroll 1
    for (int j = 0; j < NAG; ++j){
      if (j == i) continue;
      dotTile(sm, SA_O + j*16384, sm0, sm1, lane, wave, col, PART_O);
      __syncthreads();
      if (t < TB){
        const float* part = (const float*)(sm + PART_O);
        float tot = 0.f;
        #pragma unroll
        for (int w2 = 0; w2 < 8; ++w2) tot += part[w2*32 + t];
        ((float*)(sm + LW_O))[(i*3 + j)*32 + t] = tot;
      }
      __syncthreads();
    }
  }
  if (t < TB){
    float* LW = (float*)(sm + LW_O);
    #pragma unroll
    for (int i = 0; i < NAG; ++i){
      int j0 = (i == 0) ? 1 : 0;
      int j1 = (i == 2) ? 1 : 2;
      float l0 = LW[(i*3 + j0)*32 + t] * SCALE;
      float l1 = LW[(i*3 + j1)*32 + t] * SCALE;
      float q0 = __expf(l0), q1 = __expf(l1);
      float inv = 1.f / (q0 + q1);
      LW[(i*3 + j0)*32 + t] = q0 * inv;
      LW[(i*3 + j1)*32 + t] = q1 * inv;
    }
  }
  __syncthreads();
  f32x4 oc00 = Z, oc01 = Z, oc10 = Z, oc11 = Z, oc20 = Z, oc21 = Z;
  {
    const float* LW = (const float*)(sm + LW_O);
    #pragma unroll 1
    for (int j = 0; j < NAG; ++j){
      f32x4 v0 = binit(cval_b[col]), v1 = v0;
      gemmA(v0, v1, sm, SA_O + j*16384, wsu + OFF_CV, wsu + OFF_CV + 16384, 128, col, 0, lane);
      v0 = lrelu4(v0); v1 = lrelu4(v1);
      #pragma unroll
      for (int i = 0; i < NAG; ++i){
        if (i == j) continue;
        f32x4& o0 = (i == 0) ? oc00 : ((i == 1) ? oc10 : oc20);
        f32x4& o1 = (i == 0) ? oc01 : ((i == 1) ? oc11 : oc21);
        #pragma unroll
        for (int r = 0; r < 4; ++r){
          int row0 = ((lane >> 4) << 2) + r;
          o0[r] += LW[(i*3 + j)*32 + row0]      * v0[r];
          o1[r] += LW[(i*3 + j)*32 + row0 + 16] * v1[r];
        }
      }
    }
  }
  __syncthreads();
  #pragma unroll 1
  for (int i = 0; i < NAG; ++i){
    const unsigned short* swh = wsu + OFF_SW(i);
    const unsigned short* swl = swh + 28672;
    f32x4 se0 = binit(senc_b[i*HD + col]), se1 = se0;
    gemmS(se0, se1, sm, XN_O + i*4096, swh, swl, 768 + col, lane);
    stTile(sm, EN_O, 0, lane, col, lrelu4(se0));
    stTile(sm, EN_O, 1, lane, col, lrelu4(se1));
    {
      f32x4 o0 = (i == 0) ? oc00 : ((i == 1) ? oc10 : oc20);
      f32x4 o1 = (i == 0) ? oc01 : ((i == 1) ? oc11 : oc21);
      stTile(sm, OV0_O, 0, lane, col, o0);
      stTile(sm, OV0_O, 1, lane, col, o1);
    }
    __syncthreads();
    const unsigned short* c1h = wsu + OFF_C1(i);
    const unsigned short* c1l = c1h + 32768;
    f32x4 h0 = binit(cb1[i*HD + col]), h1 = h0;
    gemmA(h0, h1, sm, EN_O,  c1h, c1l, 256, col, 0,   lane);
    gemmA(h0, h1, sm, OV0_O, c1h, c1l, 256, col, 128, lane);
    stTile(sm, SLICE_O, 0, lane, col, lrelu4(h0));
    stTile(sm, SLICE_O, 1, lane, col, lrelu4(h1));
    __syncthreads();
    f32x4 q0 = Z, q1 = Z;
    gemmA(q0, q1, sm, SLICE_O, wsu + OFF_C2(i), wsu + OFF_C2(i) + 2048, 128, (lane & 15), 0, lane);
    if (wave == 0 && (lane & 15) < 2){
      int c2 = lane & 15;
      float bb = cb2[i*2 + c2];
      #pragma unroll
      for (int r = 0; r < 4; ++r){
        int row = ((lane >> 4) << 2) + r;
        out[((size_t)i*BATCH + gb0 + row)*2 + c2]      = q0[r] + bb;
        out[((size_t)i*BATCH + gb0 + row + 16)*2 + c2] = q1[r] + bb;
      }
    }
    __syncthreads();
  }
}

// ------------------------------------------------------------ launch -----
extern "C" void kernel_launch(void* const* d_in, const int* in_sizes, int n_in,
                              void* d_out, int out_size, void* d_ws, size_t ws_size,
                              hipStream_t stream) {
  const float* s       = (const float*)d_in[0];
  const float* a       = (const float*)d_in[1];
  const float* en_W    = (const float*)d_in[2];
  const float* en_b    = (const float*)d_in[3];
  const float* oa_W    = (const float*)d_in[4];
  const float* oa_b    = (const float*)d_in[5];
  const float* goal_W  = (const float*)d_in[6];
  const float* goal_b  = (const float*)d_in[7];
  const float* akey_W  = (const float*)d_in[8];
  const float* asel_W  = (const float*)d_in[9];
  const float* aval_W  = (const float*)d_in[10];
  const float* aval_b  = (const float*)d_in[11];
  const float* merge_W = (const float*)d_in[12];
  const float* merge_b = (const float*)d_in[13];
  const float* senc_W  = (const float*)d_in[14];
  const float* senc_b  = (const float*)d_in[15];
  const float* ckey_W  = (const float*)d_in[16];
  const float* csel_W  = (const float*)d_in[17];
  const float* cval_W  = (const float*)d_in[18];
  const float* cval_b  = (const float*)d_in[19];
  const float* cW1     = (const float*)d_in[20];
  const float* cb1     = (const float*)d_in[21];
  const float* cW2     = (const float*)d_in[22];
  const float* cb2     = (const float*)d_in[23];
  unsigned char* wsc = (unsigned char*)d_ws;
  float* F = (float*)(wsc + WSB_F);
  unsigned short* wsu = (unsigned short*)(wsc + WSB_W);
  float* out = (float*)d_out;

  hipMemsetAsync(wsc + WSB_ACCUM, 0, 480, stream);
  stats_partial_kernel<<<48, 256, 0, stream>>>(s, a, (float*)(wsc + WSB_ACCUM));
  stats_final_kernel<<<1, 64, 0, stream>>>((const float*)(wsc + WSB_ACCUM), (float*)(wsc + WSB_STATS));
  fuse_mats_kernel<<<dim3(HD, 3), HD, 0, stream>>>(asel_W, akey_W, csel_W, ckey_W, F);

  splitT_kernel<<<64, 256, 0, stream>>>(F,           wsu + OFF_FT0, wsu + OFF_FT0 + 16384, 128, 128, 128);
  splitT_kernel<<<64, 256, 0, stream>>>(F + 16384,   wsu + OFF_FT1, wsu + OFF_FT1 + 16384, 128, 128, 128);
  splitT_kernel<<<64, 256, 0, stream>>>(F + 32768,   wsu + OFF_MT,  wsu + OFF_MT  + 16384, 128, 128, 128);
  splitT_kernel<<<64, 256, 0, stream>>>(aval_W,          wsu + OFF_AV0, wsu + OFF_AV0 + 16384, 128, 128, 128);
  splitT_kernel<<<64, 256, 0, stream>>>(aval_W + 16384,  wsu + OFF_AV1, wsu + OFF_AV1 + 16384, 128, 128, 128);
  splitT_kernel<<<64, 256, 0, stream>>>(cval_W,          wsu + OFF_CV,  wsu + OFF_CV  + 16384, 128, 128, 128);
  for (int n = 0; n < 3; ++n){
    splitT_kernel<<<192, 256, 0, stream>>>(merge_W + (size_t)n*49152, wsu + OFF_MG(n), wsu + OFF_MG(n) + 49152, 384, 128, 128);
    splitT_kernel<<<128, 256, 0, stream>>>(cW1     + (size_t)n*32768, wsu + OFF_C1(n), wsu + OFF_C1(n) + 32768, 256, 128, 128);
    splitT_kernel<<<8,   256, 0, stream>>>(cW2     + (size_t)n*256,   wsu + OFF_C2(n), wsu + OFF_C2(n) + 2048,  128, 2, 16);
  }
  smallpack_kernel<<<336, 256, 0, stream>>>(en_W, oa_W, goal_W, senc_W, wsu);

  if (ws_size >= (size_t)WSB_SA + SA_BYTES){
    unsigned short* sa_g = (unsigned short*)(wsc + WSB_SA);
    actor_kernel<<<dim3(BATCH / TB, NAG), 512, 0, stream>>>(
        s, a, en_b, oa_b, goal_b, aval_b, merge_b,
        (const unsigned char*)wsc, sa_g);
    critic_kernel<<<dim3(BATCH / TB, NAG), 512, 0, stream>>>(
        s, a, senc_b, cval_b, cb1, cW2, cb2,
        (const unsigned char*)wsc, (const unsigned short*)sa_g, out);
  } else {
    fused_kernel<<<BATCH / TB, 512, 0, stream>>>(
        s, a, en_b, oa_b, goal_b, aval_b, merge_b, senc_b, cval_b, cb1, cb2,
        (const unsigned char*)wsc, out);
  }
}

// Round 6
// 366.951 us; speedup vs baseline: 2.8723x; 1.2039x over previous
//
#include <hip/hip_runtime.h>

#define NAG 3
#define BATCH 32768
#define HD 128
#define SD 18
#define TB 32
#define EPSV 1e-5f
#define SCALE 0.08838834764831845f

typedef __attribute__((ext_vector_type(8))) short short8;
typedef __attribute__((ext_vector_type(4))) float f32x4;

// ---------------- ws byte layout ----------------
#define WSB_STATS 0          // 480B f32  [3][20][2] mean,istd
#define WSB_ACCUM 512        // 480B f32  sum,sumsq
#define WSB_F     1024       // 3*16384 f32 scratch (F0,F1,M)
#define WSB_W     197632     // bf16 weight area (ushort units below)
#define OFF_FT0 0            // 16384, l +16384
#define OFF_FT1 32768
#define OFF_MT  65536
#define OFF_AV0 98304
#define OFF_AV1 131072
#define OFF_CV  163840
#define OFF_MG(n) (196608 + (n)*98304)   // 49152, l +49152
#define OFF_C1(n) (491520 + (n)*65536)   // 32768, l +32768
#define OFF_C2(n) (688128 + (n)*4096)    // 2048,  l +2048 (fallback only)
#define OFF_SW(n) (700416 + (n)*57344)   // 28672, l +28672
#define WSB_SA  2097152      // bf16 sa [3][32768][128] = 25165824 B (path A only)
#define SA_BYTES ((size_t)NAG * BATCH * HD * 2)

__device__ __forceinline__ float lrelu(float x){ return x >= 0.0f ? x : 0.01f * x; }
__device__ __forceinline__ f32x4 lrelu4(f32x4 v){
  f32x4 r; r[0]=lrelu(v[0]); r[1]=lrelu(v[1]); r[2]=lrelu(v[2]); r[3]=lrelu(v[3]); return r;
}
__device__ __forceinline__ f32x4 binit(float b){ f32x4 c; c[0]=b;c[1]=b;c[2]=b;c[3]=b; return c; }
__device__ __forceinline__ unsigned short f2bf(float f){
  unsigned int u = __float_as_uint(f);
  unsigned int r = (u + 0x7FFFu + ((u >> 16) & 1u)) >> 16;
  return (unsigned short)r;
}
__device__ __forceinline__ float bf2f(unsigned short h){
  return __uint_as_float(((unsigned int)h) << 16);
}

// ---------------- prep: batch stats ----------------
__global__ void stats_partial_kernel(const float* __restrict__ s,
                                     const float* __restrict__ a,
                                     float* __restrict__ accum){
  const int n = blockIdx.x >> 4;
  const int chunk = blockIdx.x & 15;
  const int t = threadIdx.x;
  const int rows = BATCH / 16;
  const int b0 = chunk * rows;
  float sum[20], sq[20];
  #pragma unroll
  for (int c = 0; c < 20; ++c){ sum[c] = 0.f; sq[c] = 0.f; }
  for (int b = b0 + t; b < b0 + rows; b += 256){
    const float* row = s + ((size_t)n * BATCH + b) * SD;
    #pragma unroll
    for (int c = 0; c < SD; ++c){ float v = row[c]; sum[c] += v; sq[c] += v * v; }
    const float* ra = a + ((size_t)n * BATCH + b) * 2;
    #pragma unroll
    for (int c = 0; c < 2; ++c){ float v = ra[c]; sum[SD + c] += v; sq[SD + c] += v * v; }
  }
  __shared__ float red[256];
  for (int c = 0; c < 20; ++c){
    red[t] = sum[c]; __syncthreads();
    for (int off = 128; off > 0; off >>= 1){ if (t < off) red[t] += red[t + off]; __syncthreads(); }
    if (t == 0) atomicAdd(&accum[(n * 20 + c) * 2 + 0], red[0]);
    __syncthreads();
    red[t] = sq[c]; __syncthreads();
    for (int off = 128; off > 0; off >>= 1){ if (t < off) red[t] += red[t + off]; __syncthreads(); }
    if (t == 0) atomicAdd(&accum[(n * 20 + c) * 2 + 1], red[0]);
    __syncthreads();
  }
}

// ---------------- prep: F_m = sel @ key^T (f32) + stats finalize ----------------
__global__ void fuse_mats_kernel(const float* __restrict__ asel, const float* __restrict__ akey,
                                 const float* __restrict__ csel, const float* __restrict__ ckey,
                                 float* __restrict__ F, const float* __restrict__ accum,
                                 float* __restrict__ stats){
  const int m  = blockIdx.y;
  if (m == 3){
    if (blockIdx.x == 0){
      int i = threadIdx.x;
      if (i < 60){
        float S = accum[i * 2 + 0], SQ = accum[i * 2 + 1];
        float mean = S / (float)BATCH;
        float var = SQ / (float)BATCH - mean * mean;
        stats[i * 2 + 0] = mean;
        stats[i * 2 + 1] = 1.0f / sqrtf(var + EPSV);
      }
    }
    return;
  }
  const int h1 = blockIdx.x;
  const int h2 = threadIdx.x;
  const float* A; const float* Bm;
  if (m == 0){ A = asel;            Bm = akey; }
  else if (m == 1){ A = asel + HD*HD; Bm = akey + HD*HD; }
  else { A = csel; Bm = ckey; }
  const float* arow = A + h1 * HD;
  const float* brow = Bm + h2 * HD;
  float acc = 0.f;
  #pragma unroll 4
  for (int d = 0; d < HD; ++d) acc = fmaf(arow[d], brow[d], acc);
  F[m * HD * HD + h1 * HD + h2] = acc;
}

// ---------------- prep: all weight splits + smallpack in ONE kernel ----------------
__global__ void prep_split_kernel(const float* __restrict__ F, const float* __restrict__ aval_W,
                                  const float* __restrict__ cval_W, const float* __restrict__ merge_W,
                                  const float* __restrict__ cW1, const float* __restrict__ cW2,
                                  const float* __restrict__ en_W, const float* __restrict__ oa_W,
                                  const float* __restrict__ goal_W, const float* __restrict__ senc_W,
                                  unsigned short* __restrict__ wsu){
  const int job = blockIdx.y;
  const int idx = blockIdx.x * 256 + threadIdx.x;
  if (job == 15){
    // smallpack: [896 cols][32 k] per agent
    if (idx >= 3 * 896 * 32) return;
    int k = idx & 31; int c = (idx >> 5) % 896; int n = idx / (896 * 32);
    int tt = c >> 7, cc = c & 127;
    float v = 0.f;
    if (tt == 0){
      if (k < 4) v = en_W[(size_t)(n*6 + k)*128 + cc];
      else if (k == 18 || k == 19) v = en_W[(size_t)(n*6 + 4 + (k-18))*128 + cc];
    } else if (tt <= 2){
      int j = tt - 1; int kk = k - (4 + 4*j);
      if (kk >= 0 && kk < 4) v = oa_W[(size_t)(n*4 + kk)*128 + cc];
    } else if (tt <= 5){
      int j = tt - 3; int kk = k - (12 + 2*j);
      if (kk >= 0 && kk < 2) v = goal_W[(size_t)(n*2 + kk)*128 + cc];
    } else {
      if (k < 18) v = senc_W[(size_t)(n*18 + k)*128 + cc];
    }
    unsigned short hi = f2bf(v); float lo = v - bf2f(hi);
    unsigned short* dh = wsu + OFF_SW(n);
    dh[c * 32 + k] = hi;
    dh[28672 + c * 32 + k] = f2bf(lo);
    return;
  }
  const float* src; unsigned short* dh; int K = 128, Csrc = 128, Cdst = 128, loff = 16384;
  switch (job){
    case 0: src = F;              dh = wsu + OFF_FT0; break;
    case 1: src = F + 16384;      dh = wsu + OFF_FT1; break;
    case 2: src = F + 32768;      dh = wsu + OFF_MT;  break;
    case 3: src = aval_W;         dh = wsu + OFF_AV0; break;
    case 4: src = aval_W + 16384; dh = wsu + OFF_AV1; break;
    case 5: src = cval_W;         dh = wsu + OFF_CV;  break;
    case 6: case 7: case 8: {
      int n = job - 6; src = merge_W + (size_t)n * 49152; dh = wsu + OFF_MG(n);
      K = 384; loff = 49152; } break;
    case 9: case 10: case 11: {
      int n = job - 9; src = cW1 + (size_t)n * 32768; dh = wsu + OFF_C1(n);
      K = 256; loff = 32768; } break;
    default: {
      int n = job - 12; src = cW2 + (size_t)n * 256; dh = wsu + OFF_C2(n);
      Csrc = 2; Cdst = 16; loff = 2048; } break;
  }
  if (idx >= K * Cdst) return;
  int k = idx / Cdst, c = idx - k * Cdst;
  float v = (c < Csrc) ? src[(size_t)k * Csrc + c] : 0.f;
  unsigned short hi = f2bf(v);
  dh[(size_t)c * K + k] = hi;
  dh[loff + (size_t)c * K + k] = f2bf(v - bf2f(hi));
}

// ---------------- MFMA helpers ----------------
__device__ __forceinline__ void ldA(const unsigned char* sm, int base, int mi, int ks, int lane,
                                    short8& h, short8& l){
  int row = mi * 16 + (lane & 15);
  int bc  = ks * 64 + ((lane >> 4) << 4);
  int off = base + row * 256 + (bc ^ ((row & 7) << 4));
  h = *(const short8*)(sm + off);
  l = *(const short8*)(sm + off + 8192);
}
__device__ __forceinline__ short8 ldAh(const unsigned char* sm, int base, int mi, int ks, int lane){
  int row = mi * 16 + (lane & 15);
  int bc  = ks * 64 + ((lane >> 4) << 4);
  return *(const short8*)(sm + base + row * 256 + (bc ^ ((row & 7) << 4)));
}
__device__ __forceinline__ void ldA32(const unsigned char* sm, int base, int mi, int lane,
                                      short8& h, short8& l){
  int row = mi * 16 + (lane & 15);
  int bc  = (lane >> 4) << 4;
  int off = base + row * 64 + (bc ^ ((row & 3) << 4));
  h = *(const short8*)(sm + off);
  l = *(const short8*)(sm + off + 2048);
}

#define MM3(acc, ah, al, bh, bl) \
  acc = __builtin_amdgcn_mfma_f32_16x16x32_bf16(ah, bh, acc, 0, 0, 0); \
  acc = __builtin_amdgcn_mfma_f32_16x16x32_bf16(ah, bl, acc, 0, 0, 0); \
  acc = __builtin_amdgcn_mfma_f32_16x16x32_bf16(al, bh, acc, 0, 0, 0);
#define MM2(acc, ah, bh, bl) \
  acc = __builtin_amdgcn_mfma_f32_16x16x32_bf16(ah, bh, acc, 0, 0, 0); \
  acc = __builtin_amdgcn_mfma_f32_16x16x32_bf16(ah, bl, acc, 0, 0, 0);

// split-A, split-B: 24 MFMA (fallback kernel)
__device__ __forceinline__ void gemmA(f32x4& c0, f32x4& c1, const unsigned char* sm, int abase,
                                      const unsigned short* wh, const unsigned short* wl,
                                      int K, int bcol, int kBaseB, int lane){
  const size_t bb = (size_t)bcol * K + kBaseB + ((lane >> 4) << 3);
  #pragma unroll
  for (int ks = 0; ks < 4; ++ks){
    short8 ah0, al0, ah1, al1;
    ldA(sm, abase, 0, ks, lane, ah0, al0);
    ldA(sm, abase, 1, ks, lane, ah1, al1);
    const short8 bh = *(const short8*)(wh + bb + ks * 32);
    const short8 bl = *(const short8*)(wl + bb + ks * 32);
    MM3(c0, ah0, al0, bh, bl);
    MM3(c1, ah1, al1, bh, bl);
  }
}
// hi-A, split-B: 16 MFMA, 8 LDS reads
__device__ __forceinline__ void gemmAh(f32x4& c0, f32x4& c1, const unsigned char* sm, int abase,
                                       const unsigned short* wh, const unsigned short* wl,
                                       int K, int bcol, int kBaseB, int lane){
  const size_t bb = (size_t)bcol * K + kBaseB + ((lane >> 4) << 3);
  #pragma unroll
  for (int ks = 0; ks < 4; ++ks){
    short8 ah0 = ldAh(sm, abase, 0, ks, lane);
    short8 ah1 = ldAh(sm, abase, 1, ks, lane);
    const short8 bh = *(const short8*)(wh + bb + ks * 32);
    const short8 bl = *(const short8*)(wl + bb + ks * 32);
    MM2(c0, ah0, bh, bl);
    MM2(c1, ah1, bh, bl);
  }
}
// hi-A shared across TWO split-B matrices: 32 MFMA, 8 LDS reads
__device__ __forceinline__ void gemmAW2(f32x4& c0, f32x4& c1, f32x4& d0, f32x4& d1,
                                        const unsigned char* sm, int abase,
                                        const unsigned short* wh0, const unsigned short* wl0,
                                        const unsigned short* wh1, const unsigned short* wl1,
                                        int K, int bcol, int lane){
  const size_t bb = (size_t)bcol * K + ((lane >> 4) << 3);
  #pragma unroll
  for (int ks = 0; ks < 4; ++ks){
    short8 ah0 = ldAh(sm, abase, 0, ks, lane);
    short8 ah1 = ldAh(sm, abase, 1, ks, lane);
    const short8 b0h = *(const short8*)(wh0 + bb + ks * 32);
    const short8 b0l = *(const short8*)(wl0 + bb + ks * 32);
    const short8 b1h = *(const short8*)(wh1 + bb + ks * 32);
    const short8 b1l = *(const short8*)(wl1 + bb + ks * 32);
    MM2(c0, ah0, b0h, b0l); MM2(c1, ah1, b0h, b0l);
    MM2(d0, ah0, b1h, b1l); MM2(d1, ah1, b1h, b1l);
  }
}
// TWO hi-A slices sharing ONE split-B: 32 MFMA, 16 LDS reads, 8 glb loads
__device__ __forceinline__ void gemmA2s(f32x4& c0, f32x4& c1, f32x4& d0, f32x4& d1,
                                        const unsigned char* sm, int a0, int a1,
                                        const unsigned short* wh, const unsigned short* wl,
                                        int bcol, int lane){
  const size_t bb = (size_t)bcol * 128 + ((lane >> 4) << 3);
  #pragma unroll
  for (int ks = 0; ks < 4; ++ks){
    const short8 bh = *(const short8*)(wh + bb + ks * 32);
    const short8 bl = *(const short8*)(wl + bb + ks * 32);
    short8 x0 = ldAh(sm, a0, 0, ks, lane);
    short8 x1 = ldAh(sm, a0, 1, ks, lane);
    MM2(c0, x0, bh, bl); MM2(c1, x1, bh, bl);
    short8 y0 = ldAh(sm, a1, 0, ks, lane);
    short8 y1 = ldAh(sm, a1, 1, ks, lane);
    MM2(d0, y0, bh, bl); MM2(d1, y1, bh, bl);
  }
}
// split-A (XN K=32), split-B: 6 MFMA
__device__ __forceinline__ void gemmS(f32x4& c0, f32x4& c1, const unsigned char* sm, int abase,
                                      const unsigned short* wh, const unsigned short* wl,
                                      int bcol, int lane){
  const size_t bb = (size_t)bcol * 32 + ((lane >> 4) << 3);
  short8 ah0, al0, ah1, al1;
  ldA32(sm, abase, 0, lane, ah0, al0);
  ldA32(sm, abase, 1, lane, ah1, al1);
  const short8 bh = *(const short8*)(wh + bb);
  const short8 bl = *(const short8*)(wl + bb);
  MM3(c0, ah0, al0, bh, bl);
  MM3(c1, ah1, al1, bh, bl);
}

// split store (16KB tile: hi + lo at +8192)
__device__ __forceinline__ void stTile(unsigned char* sm, int base, int mi, int lane, int col, f32x4 v){
  #pragma unroll
  for (int r = 0; r < 4; ++r){
    int row = mi * 16 + ((lane >> 4) << 2) + r;
    int bc  = col * 2;
    int off = base + row * 256 + (bc ^ ((row & 7) << 4));
    unsigned short hi = f2bf(v[r]);
    *(unsigned short*)(sm + off) = hi;
    *(unsigned short*)(sm + off + 8192) = f2bf(v[r] - bf2f(hi));
  }
}
// hi-only store (8KB tile)
__device__ __forceinline__ void stH(unsigned char* sm, int base, int mi, int lane, int col, f32x4 v){
  #pragma unroll
  for (int r = 0; r < 4; ++r){
    int row = mi * 16 + ((lane >> 4) << 2) + r;
    int off = base + row * 256 + ((col * 2) ^ ((row & 7) << 4));
    *(unsigned short*)(sm + off) = f2bf(v[r]);
  }
}
__device__ __forceinline__ void stSK(unsigned char* sm, int base, int mi, int lane, int col, f32x4 v){
  #pragma unroll
  for (int r = 0; r < 4; ++r){
    int row = mi * 16 + ((lane >> 4) << 2) + r;
    int off = base + row * 256 + ((col * 2) ^ ((row & 7) << 5));
    *(unsigned short*)(sm + off) = f2bf(v[r]);
  }
}
__device__ __forceinline__ float dot8(short8 x, short8 y){
  float acc = 0.f;
  #pragma unroll
  for (int e = 0; e < 8; ++e)
    acc = fmaf(bf2f((unsigned short)x[e]), bf2f((unsigned short)y[e]), acc);
  return acc;
}
#define RED16(p) { p += __shfl_xor(p, 1, 16); p += __shfl_xor(p, 2, 16); \
                   p += __shfl_xor(p, 4, 16); p += __shfl_xor(p, 8, 16); }

// fallback helper (path B)
__device__ __forceinline__ void dotTile(unsigned char* sm, int tbase, const f32x4 d0, const f32x4 d1,
                                        int lane, int wave, int col, int part_o){
  float* part = (float*)(sm + part_o);
  #pragma unroll
  for (int mi = 0; mi < 2; ++mi){
    #pragma unroll
    for (int r = 0; r < 4; ++r){
      int row = mi * 16 + ((lane >> 4) << 2) + r;
      int bc  = col * 2;
      int off = tbase + row * 256 + (bc ^ ((row & 7) << 4));
      float v = bf2f(*(const unsigned short*)(sm + off)) +
                bf2f(*(const unsigned short*)(sm + off + 8192));
      float p = (mi ? d1[r] : d0[r]) * v;
      RED16(p)
      if ((lane & 15) == 0) part[wave * 32 + row] = p;
    }
  }
}

// ======================================================================
// PATH A: actor kernel — grid (BATCH/TB, NAG), 512 threads, 53.6KB LDS
// ======================================================================
__global__ __launch_bounds__(512, 4) void actor_kernel(
    const float* __restrict__ s, const float* __restrict__ a,
    const float* __restrict__ en_b, const float* __restrict__ oa_b,
    const float* __restrict__ goal_b, const float* __restrict__ aval_b,
    const float* __restrict__ merge_b, const unsigned char* __restrict__ wsc,
    unsigned short* __restrict__ sa_g)
{
  __shared__ __align__(16) unsigned char SM[53632];
  const int AXN = 0, AEN = 4096, AOV = 12288, ASK = 20480, SLB0 = 36864, SLB1 = 45056;
  const int AEP = 53248, AES = 53504;
  const int t = threadIdx.x, lane = t & 63, wave = t >> 6;
  const int col = wave * 16 + (lane & 15);
  const int n = blockIdx.y;
  const int gb0 = blockIdx.x * TB;
  const float* stats = (const float*)(wsc + WSB_STATS);
  const unsigned short* wsu = (const unsigned short*)(wsc + WSB_W);
  const unsigned short* swh = wsu + OFF_SW(n);
  const unsigned short* swl = swh + 28672;
  float* eP0 = (float*)(SM + AEP);
  float* eP1 = eP0 + 32;
  float* esm = (float*)(SM + AES);
  const f32x4 Z = binit(0.f);
  const int drow = wave * 4 + (lane >> 4);        // dot row
  const int dcb  = (lane & 15) * 16;
  const int dsw5 = (drow & 7) << 5, dsw4 = (drow & 7) << 4;
  const int r0base = (lane >> 4) << 2;

  // stage normalized XN (split, K=32)
  if (t < TB){
    int row = t;
    size_t gb = (size_t)gb0 + row;
    const float* st = stats + n * 40;
    const float* srow = s + ((size_t)n * BATCH + gb) * SD;
    const float* arow = a + ((size_t)n * BATCH + gb) * 2;
    #pragma unroll
    for (int c = 0; c < 32; ++c){
      float v = 0.f;
      if (c < 18) v = (srow[c] - st[c*2]) * st[c*2+1];
      else if (c < 20) v = (arow[c-18] - st[c*2]) * st[c*2+1];
      unsigned short hi = f2bf(v);
      int off = AXN + row * 64 + ((c * 2) ^ ((row & 3) << 4));
      *(unsigned short*)(SM + off) = hi;
      *(unsigned short*)(SM + off + 2048) = f2bf(v - bf2f(hi));
    }
  }
  __syncthreads();
  // R0: en_enc -> AEN (hi)
  {
    f32x4 c0 = binit(en_b[n*HD + col]), c1 = c0;
    gemmS(c0, c1, SM, AXN, swh, swl, col, lane);
    stH(SM, AEN, 0, lane, col, lrelu4(c0));
    stH(SM, AEN, 1, lane, col, lrelu4(c1));
  }
  __syncthreads();
  // R1: selk0&selk1 -> ASK ; stage oa slices -> SLB0, SLB1
  {
    f32x4 k0 = Z, k1 = Z, m0 = Z, m1 = Z;
    gemmAW2(k0, k1, m0, m1, SM, AEN,
            wsu + OFF_FT0, wsu + OFF_FT0 + 16384,
            wsu + OFF_FT1, wsu + OFF_FT1 + 16384, 128, col, lane);
    stSK(SM, ASK, 0, lane, col, k0); stSK(SM, ASK, 1, lane, col, k1);
    stSK(SM, ASK + 8192, 0, lane, col, m0); stSK(SM, ASK + 8192, 1, lane, col, m1);
    const float bb = oa_b[n*HD + col];
    f32x4 c0 = binit(bb), c1 = c0;
    gemmS(c0, c1, SM, AXN, swh, swl, 128 + col, lane);
    stH(SM, SLB0, 0, lane, col, lrelu4(c0)); stH(SM, SLB0, 1, lane, col, lrelu4(c1));
    c0 = binit(bb); c1 = c0;
    gemmS(c0, c1, SM, AXN, swh, swl, 256 + col, lane);
    stH(SM, SLB1, 0, lane, col, lrelu4(c0)); stH(SM, SLB1, 1, lane, col, lrelu4(c1));
  }
  __syncthreads();
  // R2: oa vals (both slices, shared B) + logit dots + exp
  f32x4 v00a, v00b, v01a, v01b;
  {
    const float vb = aval_b[col];
    v00a = binit(vb); v00b = v00a; v01a = v00a; v01b = v00a;
    gemmA2s(v00a, v00b, v01a, v01b, SM, SLB0, SLB1,
            wsu + OFF_AV0, wsu + OFF_AV0 + 16384, col, lane);
    short8 kf = *(const short8*)(SM + ASK + drow * 256 + (dcb ^ dsw5));
    short8 e0f = *(const short8*)(SM + SLB0 + drow * 256 + (dcb ^ dsw4));
    short8 e1f = *(const short8*)(SM + SLB1 + drow * 256 + (dcb ^ dsw4));
    float p0 = dot8(kf, e0f), p1 = dot8(kf, e1f);
    RED16(p0) RED16(p1)
    if ((lane & 15) == 0){
      float e0 = __expf(p0 * SCALE), e1 = __expf(p1 * SCALE);
      eP0[drow] = e0; eP1[drow] = e1; esm[drow] = e0 + e1;
    }
  }
  __syncthreads();
  // R3: ov0 -> AOV ; stage goal slices g0,g1 -> SLB0, SLB1
  {
    f32x4 o0, o1;
    #pragma unroll
    for (int r = 0; r < 4; ++r){
      int r0 = r0base + r;
      o0[r] = (eP0[r0] * lrelu(v00a[r]) + eP1[r0] * lrelu(v01a[r])) / esm[r0];
      o1[r] = (eP0[r0+16] * lrelu(v00b[r]) + eP1[r0+16] * lrelu(v01b[r])) / esm[r0+16];
    }
    stH(SM, AOV, 0, lane, col, o0); stH(SM, AOV, 1, lane, col, o1);
    const float bb = goal_b[n*HD + col];
    f32x4 c0 = binit(bb), c1 = c0;
    gemmS(c0, c1, SM, AXN, swh, swl, 384 + col, lane);
    stH(SM, SLB0, 0, lane, col, lrelu4(c0)); stH(SM, SLB0, 1, lane, col, lrelu4(c1));
    c0 = binit(bb); c1 = c0;
    gemmS(c0, c1, SM, AXN, swh, swl, 512 + col, lane);
    stH(SM, SLB1, 0, lane, col, lrelu4(c0)); stH(SM, SLB1, 1, lane, col, lrelu4(c1));
  }
  __syncthreads();
  // R4: goal vals g0,g1 + dots (selk1)
  f32x4 w00a, w00b, w01a, w01b;
  {
    const float vb = aval_b[HD + col];
    w00a = binit(vb); w00b = w00a; w01a = w00a; w01b = w00a;
    gemmA2s(w00a, w00b, w01a, w01b, SM, SLB0, SLB1,
            wsu + OFF_AV1, wsu + OFF_AV1 + 16384, col, lane);
    short8 kf = *(const short8*)(SM + ASK + 8192 + drow * 256 + (dcb ^ dsw5));
    short8 e0f = *(const short8*)(SM + SLB0 + drow * 256 + (dcb ^ dsw4));
    short8 e1f = *(const short8*)(SM + SLB1 + drow * 256 + (dcb ^ dsw4));
    float p0 = dot8(kf, e0f), p1 = dot8(kf, e1f);
    RED16(p0) RED16(p1)
    if ((lane & 15) == 0){
      float e0 = __expf(p0 * SCALE), e1 = __expf(p1 * SCALE);
      eP0[drow] = e0; eP1[drow] = e1; esm[drow] = e0 + e1;
    }
  }
  __syncthreads();
  // R5: og init ; stage g2 -> SLB0
  f32x4 og0, og1;
  {
    #pragma unroll
    for (int r = 0; r < 4; ++r){
      int r0 = r0base + r;
      og0[r] = eP0[r0] * lrelu(w00a[r]) + eP1[r0] * lrelu(w01a[r]);
      og1[r] = eP0[r0+16] * lrelu(w00b[r]) + eP1[r0+16] * lrelu(w01b[r]);
    }
    f32x4 c0 = binit(goal_b[n*HD + col]), c1 = c0;
    gemmS(c0, c1, SM, AXN, swh, swl, 640 + col, lane);
    stH(SM, SLB0, 0, lane, col, lrelu4(c0)); stH(SM, SLB0, 1, lane, col, lrelu4(c1));
  }
  __syncthreads();
  // R6: g2 vals + dot
  f32x4 w2a, w2b;
  {
    w2a = binit(aval_b[HD + col]); w2b = w2a;
    gemmAh(w2a, w2b, SM, SLB0, wsu + OFF_AV1, wsu + OFF_AV1 + 16384, 128, col, 0, lane);
    short8 kf = *(const short8*)(SM + ASK + 8192 + drow * 256 + (dcb ^ dsw5));
    short8 ef = *(const short8*)(SM + SLB0 + drow * 256 + (dcb ^ dsw4));
    float p = dot8(kf, ef);
    RED16(p)
    if ((lane & 15) == 0){
      float e = __expf(p * SCALE);
      eP0[drow] = e; esm[drow] += e;
    }
  }
  __syncthreads();
  // R7: ov1 -> SLB1
  {
    f32x4 o0, o1;
    #pragma unroll
    for (int r = 0; r < 4; ++r){
      int r0 = r0base + r;
      o0[r] = (og0[r] + eP0[r0] * lrelu(w2a[r])) / esm[r0];
      o1[r] = (og1[r] + eP0[r0+16] * lrelu(w2b[r])) / esm[r0+16];
    }
    stH(SM, SLB1, 0, lane, col, o0); stH(SM, SLB1, 1, lane, col, o1);
  }
  __syncthreads();
  // R8: merge -> ASK (staging)
  {
    const unsigned short* mh = wsu + OFF_MG(n);
    const unsigned short* ml = mh + 49152;
    f32x4 c0 = binit(merge_b[n*HD + col]), c1 = c0;
    gemmAh(c0, c1, SM, AEN,  mh, ml, 384, col, 0,   lane);
    gemmAh(c0, c1, SM, AOV,  mh, ml, 384, col, 128, lane);
    gemmAh(c0, c1, SM, SLB1, mh, ml, 384, col, 256, lane);
    stH(SM, ASK, 0, lane, col, lrelu4(c0));
    stH(SM, ASK, 1, lane, col, lrelu4(c1));
  }
  __syncthreads();
  // R9: coalesced copy ASK -> sa_g
  {
    int row = t >> 4, ch = t & 15;
    short8 u = *(const short8*)(SM + ASK + row * 256 + ((ch * 16) ^ ((row & 7) << 4)));
    *(short8*)(sa_g + ((size_t)n * BATCH + gb0 + row) * HD + ch * 8) = u;
  }
}

// ======================================================================
// PATH A: critic kernel — grid (BATCH/TB, NAG=i), 512 threads, ~45KB LDS
// ======================================================================
__global__ __launch_bounds__(512, 4) void critic_kernel(
    const float* __restrict__ s, const float* __restrict__ a,
    const float* __restrict__ senc_b, const float* __restrict__ cval_b,
    const float* __restrict__ cb1, const float* __restrict__ cW2,
    const float* __restrict__ cb2, const unsigned char* __restrict__ wsc,
    const unsigned short* __restrict__ sa_g, float* __restrict__ out)
{
  __shared__ __align__(16) unsigned char SM[45312];
  const int CXN = 0, CEN = 4096, CSMo = 12288, CSA = 20480, COV = 36864, CH = 20480, CLW = 45056;
  const int t = threadIdx.x, lane = t & 63, wave = t >> 6;
  const int col = wave * 16 + (lane & 15);
  const int i = blockIdx.y;
  const int gb0 = blockIdx.x * TB;
  const int j0 = (i == 0) ? 1 : 0;
  const int j1 = (i == 2) ? 1 : 2;
  const float* stats = (const float*)(wsc + WSB_STATS);
  const unsigned short* wsu = (const unsigned short*)(wsc + WSB_W);
  const unsigned short* swh = wsu + OFF_SW(i);
  const unsigned short* swl = swh + 28672;
  const f32x4 Z = binit(0.f);

  // R0: stage XN_i (split) + copy sa_j0/j1 -> LDS (hi, 16B-swz)
  if (t < TB){
    int row = t;
    size_t gb = (size_t)gb0 + row;
    const float* st = stats + i * 40;
    const float* srow = s + ((size_t)i * BATCH + gb) * SD;
    const float* arow = a + ((size_t)i * BATCH + gb) * 2;
    #pragma unroll
    for (int c = 0; c < 32; ++c){
      float v = 0.f;
      if (c < 18) v = (srow[c] - st[c*2]) * st[c*2+1];
      else if (c < 20) v = (arow[c-18] - st[c*2]) * st[c*2+1];
      unsigned short hi = f2bf(v);
      int off = CXN + row * 64 + ((c * 2) ^ ((row & 3) << 4));
      *(unsigned short*)(SM + off) = hi;
      *(unsigned short*)(SM + off + 2048) = f2bf(v - bf2f(hi));
    }
  }
  {
    int r = t >> 4, ch = (t & 15) * 16;
    int sw = (r & 7) << 4;
    short8 u0 = *(const short8*)(sa_g + ((size_t)j0 * BATCH + gb0 + r) * HD + (ch >> 1));
    *(short8*)(SM + CSA + r * 256 + (ch ^ sw)) = u0;
    short8 u1 = *(const short8*)(sa_g + ((size_t)j1 * BATCH + gb0 + r) * HD + (ch >> 1));
    *(short8*)(SM + CSA + 8192 + r * 256 + (ch ^ sw)) = u1;
  }
  __syncthreads();
  // R1: s_enc -> CEN (hi)
  {
    f32x4 c0 = binit(senc_b[i*HD + col]), c1 = c0;
    gemmS(c0, c1, SM, CXN, swh, swl, 768 + col, lane);
    stH(SM, CEN, 0, lane, col, lrelu4(c0));
    stH(SM, CEN, 1, lane, col, lrelu4(c1));
  }
  __syncthreads();
  // R2: selsM = s_enc @ M -> CSM (bf16, 32B-swz)
  {
    f32x4 k0 = Z, k1 = Z;
    gemmAh(k0, k1, SM, CEN, wsu + OFF_MT, wsu + OFF_MT + 16384, 128, col, 0, lane);
    stSK(SM, CSMo, 0, lane, col, k0);
    stSK(SM, CSMo, 1, lane, col, k1);
  }
  __syncthreads();
  // R3: vals GEMMs (hi-A, shared B) + logit dots + 2-way softmax
  f32x4 v00, v01, v10, v11;
  {
    const float vb = cval_b[col];
    v00 = binit(vb); v01 = v00; v10 = v00; v11 = v00;
    gemmA2s(v00, v01, v10, v11, SM, CSA, CSA + 8192,
            wsu + OFF_CV, wsu + OFF_CV + 16384, col, lane);
    int row = wave * 4 + (lane >> 4);
    int cb = (lane & 15) * 16;
    int sw5 = (row & 7) << 5, sw4 = (row & 7) << 4;
    short8 m0 = *(const short8*)(SM + CSMo + row * 256 + (cb ^ sw5));
    short8 a0 = *(const short8*)(SM + CSA + row * 256 + (cb ^ sw4));
    short8 b0 = *(const short8*)(SM + CSA + 8192 + row * 256 + (cb ^ sw4));
    float p0 = dot8(m0, a0);
    float p1 = dot8(m0, b0);
    RED16(p0) RED16(p1)
    if ((lane & 15) == 0){
      float e0 = __expf(p0 * SCALE), e1 = __expf(p1 * SCALE);
      float inv = 1.f / (e0 + e1);
      ((float*)(SM + CLW))[row]      = e0 * inv;
      ((float*)(SM + CLW))[32 + row] = e1 * inv;
    }
  }
  __syncthreads();
  // R4: ov -> COV (hi)
  {
    const float* w0 = (const float*)(SM + CLW);
    const float* w1 = w0 + 32;
    f32x4 o0, o1;
    #pragma unroll
    for (int r = 0; r < 4; ++r){
      int r0 = ((lane >> 4) << 2) + r;
      o0[r] = w0[r0]      * lrelu(v00[r]) + w1[r0]      * lrelu(v10[r]);
      o1[r] = w0[r0 + 16] * lrelu(v01[r]) + w1[r0 + 16] * lrelu(v11[r]);
    }
    stH(SM, COV, 0, lane, col, o0);
    stH(SM, COV, 1, lane, col, o1);
  }
  __syncthreads();
  // R5: h = lrelu([s_enc|ov] @ cW1 + b) -> CH (split; overwrites CSA tiles)
  {
    const unsigned short* c1h = wsu + OFF_C1(i);
    const unsigned short* c1l = c1h + 32768;
    f32x4 h0 = binit(cb1[i*HD + col]), h1 = h0;
    gemmAh(h0, h1, SM, CEN, c1h, c1l, 256, col, 0,   lane);
    gemmAh(h0, h1, SM, COV, c1h, c1l, 256, col, 128, lane);
    stTile(SM, CH, 0, lane, col, lrelu4(h0));
    stTile(SM, CH, 1, lane, col, lrelu4(h1));
  }
  __syncthreads();
  // R6: q = h @ cW2 + cb2 (per-row dot, split h)
  {
    int row = wave * 4 + (lane >> 4);
    int cb = (lane & 15) * 16;
    int sw4 = (row & 7) << 4;
    const unsigned char* hb = SM + CH + row * 256;
    short8 h0 = *(const short8*)(hb + (cb ^ sw4));
    short8 l0 = *(const short8*)(hb + 8192 + (cb ^ sw4));
    float q0 = 0.f, q1 = 0.f;
    #pragma unroll
    for (int e = 0; e < 8; ++e){
      int d = (lane & 15) * 8 + e;
      float hv = bf2f((unsigned short)h0[e]) + bf2f((unsigned short)l0[e]);
      q0 = fmaf(hv, cW2[(i * HD + d) * 2 + 0], q0);
      q1 = fmaf(hv, cW2[(i * HD + d) * 2 + 1], q1);
    }
    RED16(q0) RED16(q1)
    if ((lane & 15) == 0){
      out[((size_t)i * BATCH + gb0 + row) * 2 + 0] = q0 + cb2[i * 2 + 0];
      out[((size_t)i * BATCH + gb0 + row) * 2 + 1] = q1 + cb2[i * 2 + 1];
    }
  }
}

// ======================================================================
// PATH B fallback: round-2 single fused kernel (proven)
// ======================================================================
#define XN_O    0
#define EN_O    12288
#define SLICE_O 28672
#define OV0_O   45056
#define SA_O    61440
#define PART_O  110592
#define EP_O    111616
#define ESUM_O  111744
#define LW_O    111872
#define SM_TOTAL 113024

__global__ __launch_bounds__(512, 2) void fused_kernel(
    const float* __restrict__ s, const float* __restrict__ a,
    const float* __restrict__ en_b, const float* __restrict__ oa_b,
    const float* __restrict__ goal_b, const float* __restrict__ aval_b,
    const float* __restrict__ merge_b, const float* __restrict__ senc_b,
    const float* __restrict__ cval_b, const float* __restrict__ cb1,
    const float* __restrict__ cb2, const unsigned char* __restrict__ wsc,
    float* __restrict__ out)
{
  __shared__ __align__(16) unsigned char SM[SM_TOTAL];
  unsigned char* sm = SM;
  const int t = threadIdx.x;
  const int lane = t & 63;
  const int wave = t >> 6;
  const int col = wave * 16 + (lane & 15);
  const int gb0 = blockIdx.x * TB;
  const float* stats = (const float*)(wsc + WSB_STATS);
  const unsigned short* wsu = (const unsigned short*)(wsc + WSB_W);
  const f32x4 Z = binit(0.f);

  if (t < 96){
    int n = t >> 5, row = t & 31;
    size_t gb = (size_t)gb0 + row;
    const float* st = stats + n * 40;
    const float* srow = s + ((size_t)n * BATCH + gb) * SD;
    const float* arow = a + ((size_t)n * BATCH + gb) * 2;
    #pragma unroll
    for (int c = 0; c < 32; ++c){
      float v = 0.f;
      if (c < 18) v = (srow[c] - st[c*2]) * st[c*2+1];
      else if (c < 20) v = (arow[c-18] - st[c*2]) * st[c*2+1];
      unsigned short hi = f2bf(v);
      int off = XN_O + n * 4096 + row * 64 + ((c * 2) ^ ((row & 3) << 4));
      *(unsigned short*)(sm + off) = hi;
      *(unsigned short*)(sm + off + 2048) = f2bf(v - bf2f(hi));
    }
  }
  __syncthreads();

  #pragma unroll 1
  for (int n = 0; n < NAG; ++n){
    const unsigned short* swh = wsu + OFF_SW(n);
    const unsigned short* swl = swh + 28672;
    {
      f32x4 v0 = binit(en_b[n*HD + col]), v1 = v0;
      gemmS(v0, v1, sm, XN_O + n*4096, swh, swl, 0 + col, lane);
      stTile(sm, EN_O, 0, lane, col, lrelu4(v0));
      stTile(sm, EN_O, 1, lane, col, lrelu4(v1));
    }
    __syncthreads();
    f32x4 sk0a = Z, sk0b = Z, sk1a = Z, sk1b = Z;
    gemmA(sk0a, sk0b, sm, EN_O, wsu + OFF_FT0, wsu + OFF_FT0 + 16384, 128, col, 0, lane);
    gemmA(sk1a, sk1b, sm, EN_O, wsu + OFF_FT1, wsu + OFF_FT1 + 16384, 128, col, 0, lane);

    f32x4 ov0a = Z, ov0b = Z;
    #pragma unroll 1
    for (int j = 0; j < 2; ++j){
      __syncthreads();
      f32x4 v0 = binit(oa_b[n*HD + col]), v1 = v0;
      gemmS(v0, v1, sm, XN_O + n*4096, swh, swl, 128*(1+j) + col, lane);
      stTile(sm, SLICE_O, 0, lane, col, lrelu4(v0));
      stTile(sm, SLICE_O, 1, lane, col, lrelu4(v1));
      __syncthreads();
      dotTile(sm, SLICE_O, sk0a, sk0b, lane, wave, col, PART_O);
      __syncthreads();
      if (t < TB){
        const float* part = (const float*)(sm + PART_O);
        float tot = 0.f;
        #pragma unroll
        for (int w2 = 0; w2 < 8; ++w2) tot += part[w2*32 + t];
        float e = __expf(tot * SCALE);
        ((float*)(sm + EP_O))[t] = e;
        float* es = (float*)(sm + ESUM_O);
        es[t] = (j == 0) ? e : es[t] + e;
      }
      __syncthreads();
      f32x4 w0 = binit(aval_b[col]), w1 = w0;
      gemmA(w0, w1, sm, SLICE_O, wsu + OFF_AV0, wsu + OFF_AV0 + 16384, 128, col, 0, lane);
      const float* eP = (const float*)(sm + EP_O);
      #pragma unroll
      for (int r = 0; r < 4; ++r){
        int row0 = ((lane >> 4) << 2) + r;
        ov0a[r] += eP[row0]      * lrelu(w0[r]);
        ov0b[r] += eP[row0 + 16] * lrelu(w1[r]);
      }
    }
    {
      const float* es = (const float*)(sm + ESUM_O);
      f32x4 o0, o1;
      #pragma unroll
      for (int r = 0; r < 4; ++r){
        int row0 = ((lane >> 4) << 2) + r;
        o0[r] = ov0a[r] / es[row0];
        o1[r] = ov0b[r] / es[row0 + 16];
      }
      stTile(sm, OV0_O, 0, lane, col, o0);
      stTile(sm, OV0_O, 1, lane, col, o1);
    }

    f32x4 ov1a = Z, ov1b = Z;
    #pragma unroll 1
    for (int j = 0; j < 3; ++j){
      __syncthreads();
      f32x4 v0 = binit(goal_b[n*HD + col]), v1 = v0;
      gemmS(v0, v1, sm, XN_O + n*4096, swh, swl, 128*(3+j) + col, lane);
      stTile(sm, SLICE_O, 0, lane, col, lrelu4(v0));
      stTile(sm, SLICE_O, 1, lane, col, lrelu4(v1));
      __syncthreads();
      dotTile(sm, SLICE_O, sk1a, sk1b, lane, wave, col, PART_O);
      __syncthreads();
      if (t < TB){
        const float* part = (const float*)(sm + PART_O);
        float tot = 0.f;
        #pragma unroll
        for (int w2 = 0; w2 < 8; ++w2) tot += part[w2*32 + t];
        float e = __expf(tot * SCALE);
        ((float*)(sm + EP_O))[t] = e;
        float* es = (float*)(sm + ESUM_O);
        es[t] = (j == 0) ? e : es[t] + e;
      }
      __syncthreads();
      f32x4 w0 = binit(aval_b[HD + col]), w1 = w0;
      gemmA(w0, w1, sm, SLICE_O, wsu + OFF_AV1, wsu + OFF_AV1 + 16384, 128, col, 0, lane);
      const float* eP = (const float*)(sm + EP_O);
      #pragma unroll
      for (int r = 0; r < 4; ++r){
        int row0 = ((lane >> 4) << 2) + r;
        ov1a[r] += eP[row0]      * lrelu(w0[r]);
        ov1b[r] += eP[row0 + 16] * lrelu(w1[r]);
      }
    }
    __syncthreads();
    {
      const float* es = (const float*)(sm + ESUM_O);
      f32x4 o0, o1;
      #pragma unroll
      for (int r = 0; r < 4; ++r){
        int row0 = ((lane >> 4) << 2) + r;
        o0[r] = ov1a[r] / es[row0];
        o1[r] = ov1b[r] / es[row0 + 16];
      }
      stTile(sm, SLICE_O, 0, lane, col, o0);
      stTile(sm, SLICE_O, 1, lane, col, o1);
    }
    __syncthreads();
    {
      const unsigned short* mh = wsu + OFF_MG(n);
      const unsigned short* ml = mh + 49152;
      f32x4 m0 = binit(merge_b[n*HD + col]), m1 = m0;
      gemmA(m0, m1, sm, EN_O,    mh, ml, 384, col, 0,   lane);
      gemmA(m0, m1, sm, OV0_O,   mh, ml, 384, col, 128, lane);
      gemmA(m0, m1, sm, SLICE_O, mh, ml, 384, col, 256, lane);
      stTile(sm, SA_O + n*16384, 0, lane, col, lrelu4(m0));
      stTile(sm, SA_O + n*16384, 1, lane, col, lrelu4(m1));
    }
    __syncthreads();
  }

  #pragma unroll 1
  for (int i = 0; i < NAG; ++i){
    const unsigned short* swh = wsu + OFF_SW(i);
    const unsigned short* swl = swh + 28672;
    f32x4 e0 = binit(senc_b[i*HD + col]), e1 = e0;
    gemmS(e0, e1, sm, XN_O + i*4096, swh, swl, 768 + col, lane);
    stTile(sm, EN_O, 0, lane, col, lrelu4(e0));
    stTile(sm, EN_O, 1, lane, col, lrelu4(e1));
    __syncthreads();
    f32x4 sm0 = Z, sm1 = Z;
    gemmA(sm0, sm1, sm, EN_O, wsu + OFF_MT, wsu + OFF_MT + 16384, 128, col, 0, lane);
    #pragma unroll 1
    for (int j = 0; j < NAG; ++j){
      if (j == i) continue;
      dotTile(sm, SA_O + j*16384, sm0, sm1, lane, wave, col, PART_O);
      __syncthreads();
      if (t < TB){
        const float* part = (const float*)(sm + PART_O);
        float tot = 0.f;
        #pragma unroll
        for (int w2 = 0; w2 < 8; ++w2) tot += part[w2*32 + t];
        ((float*)(sm + LW_O))[(i*3 + j)*32 + t] = tot;
      }
      __syncthreads();
    }
  }
  if (t < TB){
    float* LW = (float*)(sm + LW_O);
    #pragma unroll
    for (int i = 0; i < NAG; ++i){
      int j0 = (i == 0) ? 1 : 0;
      int j1 = (i == 2) ? 1 : 2;
      float l0 = LW[(i*3 + j0)*32 + t] * SCALE;
      float l1 = LW[(i*3 + j1)*32 + t] * SCALE;
      float q0 = __expf(l0), q1 = __expf(l1);
      float inv = 1.f / (q0 + q1);
      LW[(i*3 + j0)*32 + t] = q0 * inv;
      LW[(i*3 + j1)*32 + t] = q1 * inv;
    }
  }
  __syncthreads();
  f32x4 oc00 = Z, oc01 = Z, oc10 = Z, oc11 = Z, oc20 = Z, oc21 = Z;
  {
    const float* LW = (const float*)(sm + LW_O);
    #pragma unroll 1
    for (int j = 0; j < NAG; ++j){
      f32x4 v0 = binit(cval_b[col]), v1 = v0;
      gemmA(v0, v1, sm, SA_O + j*16384, wsu + OFF_CV, wsu + OFF_CV + 16384, 128, col, 0, lane);
      v0 = lrelu4(v0); v1 = lrelu4(v1);
      #pragma unroll
      for (int i = 0; i < NAG; ++i){
        if (i == j) continue;
        f32x4& o0 = (i == 0) ? oc00 : ((i == 1) ? oc10 : oc20);
        f32x4& o1 = (i == 0) ? oc01 : ((i == 1) ? oc11 : oc21);
        #pragma unroll
        for (int r = 0; r < 4; ++r){
          int row0 = ((lane >> 4) << 2) + r;
          o0[r] += LW[(i*3 + j)*32 + row0]      * v0[r];
          o1[r] += LW[(i*3 + j)*32 + row0 + 16] * v1[r];
        }
      }
    }
  }
  __syncthreads();
  #pragma unroll 1
  for (int i = 0; i < NAG; ++i){
    const unsigned short* swh = wsu + OFF_SW(i);
    const unsigned short* swl = swh + 28672;
    f32x4 se0 = binit(senc_b[i*HD + col]), se1 = se0;
    gemmS(se0, se1, sm, XN_O + i*4096, swh, swl, 768 + col, lane);
    stTile(sm, EN_O, 0, lane, col, lrelu4(se0));
    stTile(sm, EN_O, 1, lane, col, lrelu4(se1));
    {
      f32x4 o0 = (i == 0) ? oc00 : ((i == 1) ? oc10 : oc20);
      f32x4 o1 = (i == 0) ? oc01 : ((i == 1) ? oc11 : oc21);
      stTile(sm, OV0_O, 0, lane, col, o0);
      stTile(sm, OV0_O, 1, lane, col, o1);
    }
    __syncthreads();
    const unsigned short* c1h = wsu + OFF_C1(i);
    const unsigned short* c1l = c1h + 32768;
    f32x4 h0 = binit(cb1[i*HD + col]), h1 = h0;
    gemmA(h0, h1, sm, EN_O,  c1h, c1l, 256, col, 0,   lane);
    gemmA(h0, h1, sm, OV0_O, c1h, c1l, 256, col, 128, lane);
    stTile(sm, SLICE_O, 0, lane, col, lrelu4(h0));
    stTile(sm, SLICE_O, 1, lane, col, lrelu4(h1));
    __syncthreads();
    f32x4 q0 = Z, q1 = Z;
    gemmA(q0, q1, sm, SLICE_O, wsu + OFF_C2(i), wsu + OFF_C2(i) + 2048, 128, (lane & 15), 0, lane);
    if (wave == 0 && (lane & 15) < 2){
      int c2 = lane & 15;
      float bb = cb2[i*2 + c2];
      #pragma unroll
      for (int r = 0; r < 4; ++r){
        int row = ((lane >> 4) << 2) + r;
        out[((size_t)i*BATCH + gb0 + row)*2 + c2]      = q0[r] + bb;
        out[((size_t)i*BATCH + gb0 + row + 16)*2 + c2] = q1[r] + bb;
      }
    }
    __syncthreads();
  }
}

// ------------------------------------------------------------ launch -----
extern "C" void kernel_launch(void* const* d_in, const int* in_sizes, int n_in,
                              void* d_out, int out_size, void* d_ws, size_t ws_size,
                              hipStream_t stream) {
  const float* s       = (const float*)d_in[0];
  const float* a       = (const float*)d_in[1];
  const float* en_W    = (const float*)d_in[2];
  const float* en_b    = (const float*)d_in[3];
  const float* oa_W    = (const float*)d_in[4];
  const float* oa_b    = (const float*)d_in[5];
  const float* goal_W  = (const float*)d_in[6];
  const float* goal_b  = (const float*)d_in[7];
  const float* akey_W  = (const float*)d_in[8];
  const float* asel_W  = (const float*)d_in[9];
  const float* aval_W  = (const float*)d_in[10];
  const float* aval_b  = (const float*)d_in[11];
  const float* merge_W = (const float*)d_in[12];
  const float* merge_b = (const float*)d_in[13];
  const float* senc_W  = (const float*)d_in[14];
  const float* senc_b  = (const float*)d_in[15];
  const float* ckey_W  = (const float*)d_in[16];
  const float* csel_W  = (const float*)d_in[17];
  const float* cval_W  = (const float*)d_in[18];
  const float* cval_b  = (const float*)d_in[19];
  const float* cW1     = (const float*)d_in[20];
  const float* cb1     = (const float*)d_in[21];
  const float* cW2     = (const float*)d_in[22];
  const float* cb2     = (const float*)d_in[23];
  unsigned char* wsc = (unsigned char*)d_ws;
  float* F = (float*)(wsc + WSB_F);
  unsigned short* wsu = (unsigned short*)(wsc + WSB_W);
  float* out = (float*)d_out;

  hipMemsetAsync(wsc + WSB_ACCUM, 0, 480, stream);
  stats_partial_kernel<<<48, 256, 0, stream>>>(s, a, (float*)(wsc + WSB_ACCUM));
  fuse_mats_kernel<<<dim3(HD, 4), HD, 0, stream>>>(
      asel_W, akey_W, csel_W, ckey_W, F,
      (const float*)(wsc + WSB_ACCUM), (float*)(wsc + WSB_STATS));
  prep_split_kernel<<<dim3(336, 16), 256, 0, stream>>>(
      F, aval_W, cval_W, merge_W, cW1, cW2, en_W, oa_W, goal_W, senc_W, wsu);

  if (ws_size >= (size_t)WSB_SA + SA_BYTES){
    unsigned short* sa_g = (unsigned short*)(wsc + WSB_SA);
    actor_kernel<<<dim3(BATCH / TB, NAG), 512, 0, stream>>>(
        s, a, en_b, oa_b, goal_b, aval_b, merge_b,
        (const unsigned char*)wsc, sa_g);
    critic_kernel<<<dim3(BATCH / TB, NAG), 512, 0, stream>>>(
        s, a, senc_b, cval_b, cb1, cW2, cb2,
        (const unsigned char*)wsc, (const unsigned short*)sa_g, out);
  } else {
    fused_kernel<<<BATCH / TB, 512, 0, stream>>>(
        s, a, en_b, oa_b, goal_b, aval_b, merge_b, senc_b, cval_b, cb1, cb2,
        (const unsigned char*)wsc, out);
  }
}